// Round 1
// baseline (699.315 us; speedup 1.0000x reference)
//
#include <hip/hip_runtime.h>

// Problem constants (N=2048, L=512, K=16, DROP=2, DIM=1024)
#define NDIM 2048
#define LLEV 512
#define KDIM 16
#define HALF 1024

typedef __attribute__((ext_vector_type(8))) short bf16x8;   // 8 bf16 = 4 VGPRs
typedef __attribute__((ext_vector_type(4))) float f32x4;
typedef __attribute__((ext_vector_type(2))) float f32x2;

// ---------------------------------------------------------------------------
// bf16 split helpers: x ~= hi + lo, each RNE bf16 (~16-17 mantissa bits total)
// ---------------------------------------------------------------------------
__device__ inline unsigned short f2bf(float x) {
    unsigned u = __float_as_uint(x);
    u += 0x7fffu + ((u >> 16) & 1u);
    return (unsigned short)(u >> 16);
}
__device__ inline float bf2f(unsigned short b) {
    return __uint_as_float(((unsigned)b) << 16);
}
__device__ inline void split2(float x, unsigned short& h, unsigned short& l) {
    h = f2bf(x);
    l = f2bf(x - bf2f(h));
}

__device__ inline void gl2lds16(const void* g, void* l) {
    __builtin_amdgcn_global_load_lds(
        (const __attribute__((address_space(1))) void*)g,
        (__attribute__((address_space(3))) void*)l, 16, 0, 0);
}

// ---------------------------------------------------------------------------
// compose_kernel: pairwise level composition (validated R4/R5).
// 512 levels of 16 rows -> 256 composites of 32 rows.
// ---------------------------------------------------------------------------
__global__ __launch_bounds__(64) void compose_kernel(const float* __restrict__ O,
                                                     const int* __restrict__ idx,
                                                     int* __restrict__ Sarr,
                                                     float* __restrict__ Warr)
{
    __shared__ int s_S[32];
    __shared__ int s_pos[32];
    __shared__ float s_W[32][33];
    const int t = blockIdx.x;
    const int lane = threadIdx.x;
    const int* a = idx + (2 * t) * 16;
    const int* b = idx + (2 * t + 1) * 16;

    if (lane == 0) {
        int na = 0, i = 0, j = 0;
        while (i < 16 || j < 16) {
            int va = (i < 16) ? a[i] : 0x7fffffff;
            int vb = (j < 16) ? b[j] : 0x7fffffff;
            int v = va < vb ? va : vb;
            if (va == v) i++;
            if (vb == v) j++;
            s_S[na++] = v;
        }
        const int nm = na;
        int r = 0, p = 0;
        while (na < 32) {
            while (p < nm && s_S[p] < r) p++;
            if (p < nm && s_S[p] == r) { r++; continue; }
            s_S[na++] = r++;
        }
    }
    __syncthreads();
    if (lane < 32) {
        const int v = (lane < 16) ? a[lane] : b[lane - 16];
        int pp = 0;
        #pragma unroll
        for (int q = 0; q < 32; ++q) if (s_S[q] == v) pp = q;
        s_pos[lane] = pp;
        #pragma unroll
        for (int c = 0; c < 33; ++c) s_W[lane][c] = 0.f;
        s_W[lane][lane] = 1.f;
    }
    __syncthreads();
    const int j  = lane >> 2;
    const int cg = (lane & 3) * 8;
    #pragma unroll
    for (int step = 0; step < 2; ++step) {
        const float* Om = O + (size_t)(2 * t + step) * 256;
        float acc[8] = {};
        for (int k = 0; k < 16; ++k) {
            const float o = Om[j * 16 + k];
            const int p = s_pos[step * 16 + k];
            #pragma unroll
            for (int c = 0; c < 8; ++c) acc[c] += o * s_W[p][cg + c];
        }
        __syncthreads();
        const int pj = s_pos[step * 16 + j];
        #pragma unroll
        for (int c = 0; c < 8; ++c) s_W[pj][cg + c] = acc[c];
        __syncthreads();
    }
    if (lane < 32) Sarr[t * 32 + lane] = s_S[lane];
    {
        const int r = lane >> 1, h0 = (lane & 1) * 16;
        float* wp = Warr + (size_t)t * 1024 + r * 32 + h0;
        #pragma unroll
        for (int c = 0; c < 16; ++c) wp[c] = s_W[r][h0 + c];
    }
}

// ---------------------------------------------------------------------------
// compose2_kernel: pair 32-row composites -> 128 composites of 64 rows.
// Outputs row-major W2 (64x64), plain row list Sarr2, and packed u16 LDS
// byte offsets Spk (row*16 <= 32752 fits u16, 2 per u32) for scan4's gather.
// ---------------------------------------------------------------------------
__global__ __launch_bounds__(64) void compose2_kernel(const float* __restrict__ Warr,
                                                      const int* __restrict__ Sarr,
                                                      float* __restrict__ Warr2,
                                                      int* __restrict__ Sarr2,
                                                      unsigned int* __restrict__ Spk)
{
    __shared__ int s_S[64];
    __shared__ int s_pos[64];
    __shared__ unsigned s_map[64];
    __shared__ float s_W[64][68];   // stride 68 floats: 16B-aligned rows, bank-safe
    const int t = blockIdx.x;
    const int lane = threadIdx.x;
    const int* a = Sarr + (2 * t) * 32;
    const int* b = Sarr + (2 * t + 1) * 32;

    s_map[lane] = 0u;
    __syncthreads();
    if (lane == 0) {
        int na = 0;
        for (int k = 0; k < 32; ++k) {
            const int v = a[k];
            s_map[v >> 5] |= 1u << (v & 31);
            s_S[na++] = v;
        }
        for (int k = 0; k < 32; ++k) {
            const int v = b[k];
            if (!((s_map[v >> 5] >> (v & 31)) & 1u)) {
                s_map[v >> 5] |= 1u << (v & 31);
                s_S[na++] = v;
            }
        }
        int r = 0;
        while (na < 64) {
            if (!((s_map[r >> 5] >> (r & 31)) & 1u)) s_S[na++] = r;
            ++r;
        }
    }
    __syncthreads();
    {
        const int v = (lane < 32) ? a[lane] : b[lane - 32];
        int pp = 0;
        for (int q = 0; q < 64; ++q) if (s_S[q] == v) pp = q;
        s_pos[lane] = pp;
        #pragma unroll
        for (int c = 0; c < 68; ++c) s_W[lane][c] = 0.f;
        s_W[lane][lane] = 1.f;
    }
    __syncthreads();
    const int j  = lane >> 1;       // 0..31: source-local row of the step matrix
    const int cg = (lane & 1) * 32; // column half
    #pragma unroll
    for (int step = 0; step < 2; ++step) {
        const float* Om = Warr + (size_t)(2 * t + step) * 1024 + j * 32;
        float acc[32] = {};
        for (int k = 0; k < 32; ++k) {
            const float o = Om[k];
            const int p = s_pos[step * 32 + k];
            #pragma unroll
            for (int c4 = 0; c4 < 8; ++c4) {
                float4 v = *(const float4*)&s_W[p][cg + c4 * 4];
                acc[c4 * 4 + 0] += o * v.x;
                acc[c4 * 4 + 1] += o * v.y;
                acc[c4 * 4 + 2] += o * v.z;
                acc[c4 * 4 + 3] += o * v.w;
            }
        }
        __syncthreads();
        const int pj = s_pos[step * 32 + j];
        #pragma unroll
        for (int c4 = 0; c4 < 8; ++c4) {
            float4 v = make_float4(acc[c4 * 4 + 0], acc[c4 * 4 + 1],
                                   acc[c4 * 4 + 2], acc[c4 * 4 + 3]);
            *(float4*)&s_W[pj][cg + c4 * 4] = v;
        }
        __syncthreads();
    }
    Sarr2[t * 64 + lane] = s_S[lane];
    if (lane < 32)
        Spk[t * 32 + lane] = (unsigned)(s_S[2 * lane] << 4)
                           | ((unsigned)(s_S[2 * lane + 1] << 4) << 16);
    {
        float* wp = Warr2 + (size_t)t * 4096 + lane * 64;
        #pragma unroll
        for (int c = 0; c < 16; ++c)
            *(float4*)&wp[c * 4] = *(const float4*)&s_W[lane][c * 4];
    }
}

// ---------------------------------------------------------------------------
// scan4_kernel: 128-step scan over 64-row composites, 4 columns per block.
// One wave per block; each lane owns one full output row (64 coeffs in regs,
// double-buffered) -> no cross-lane reduce on the critical path. Gather
// addresses come pre-packed as u16 byte offsets (2 per u32). DS ops within a
// single wave are in-order, so no barriers are needed between steps.
// ---------------------------------------------------------------------------
__global__ __launch_bounds__(64) void scan4_kernel(const float* __restrict__ Warr2,
                                                   const int* __restrict__ Sarr2,
                                                   const unsigned int* __restrict__ Spk,
                                                   float* __restrict__ right)
{
    __shared__ float slab[NDIM * 4];
    const int lane = threadIdx.x;
    const int c0 = blockIdx.x * 4;

    for (int r = lane; r < NDIM; r += 64)
        *(float4*)&slab[r * 4] = make_float4(0.f, 0.f, 0.f, 0.f);
    if (lane < 4) slab[(c0 + lane) * 4 + lane] = 1.0f;

#define LOADSTEP(PK, CF, WB, tt)                                              \
    {                                                                         \
        const int4* sp_ = (const int4*)(Spk + (size_t)(tt) * 32);             \
        _Pragma("unroll")                                                     \
        for (int q = 0; q < 8; ++q) PK[q] = sp_[q];                           \
        const float4* wp_ = (const float4*)(Warr2 + (size_t)(tt) * 4096 + lane * 64); \
        _Pragma("unroll")                                                     \
        for (int q = 0; q < 16; ++q) *(float4*)&CF[q * 4] = wp_[q];           \
        WB = Sarr2[(size_t)(tt) * 64 + lane] << 4;                            \
    }

#define PROC(WORD, C0, C1)                                                    \
    {                                                                         \
        const unsigned w_ = (unsigned)(WORD);                                 \
        float4 v0_ = *(const float4*)((const char*)slab + (w_ & 0xffffu));    \
        float4 v1_ = *(const float4*)((const char*)slab + (w_ >> 16));        \
        const f32x2 cc0_ = {(C0), (C0)};                                      \
        const f32x2 cc1_ = {(C1), (C1)};                                      \
        a0 += ((f32x2){v0_.x, v0_.y}) * cc0_;                                 \
        a1 += ((f32x2){v0_.z, v0_.w}) * cc0_;                                 \
        a0 += ((f32x2){v1_.x, v1_.y}) * cc1_;                                 \
        a1 += ((f32x2){v1_.z, v1_.w}) * cc1_;                                 \
    }

#define COMPSTEP(PK, CF, WB)                                                  \
    {                                                                         \
        f32x2 a0 = {0.f, 0.f}, a1 = {0.f, 0.f};                              \
        _Pragma("unroll")                                                     \
        for (int q = 0; q < 8; ++q) {                                         \
            PROC(PK[q].x, CF[q * 8 + 0], CF[q * 8 + 1])                       \
            PROC(PK[q].y, CF[q * 8 + 2], CF[q * 8 + 3])                       \
            PROC(PK[q].z, CF[q * 8 + 4], CF[q * 8 + 5])                       \
            PROC(PK[q].w, CF[q * 8 + 6], CF[q * 8 + 7])                       \
        }                                                                     \
        float4 out_ = make_float4(a0.x, a0.y, a1.x, a1.y);                    \
        *(float4*)((char*)slab + (WB)) = out_;                                \
    }

    int4 pkA[8]; float cfA[64]; int wbA;
    int4 pkB[8]; float cfB[64]; int wbB;
    LOADSTEP(pkA, cfA, wbA, 0)
    for (int t = 0; t < 128; t += 2) {
        LOADSTEP(pkB, cfB, wbB, t + 1)
        COMPSTEP(pkA, cfA, wbA)
        if (t + 2 < 128) LOADSTEP(pkA, cfA, wbA, t + 2)
        COMPSTEP(pkB, cfB, wbB)
    }

#undef LOADSTEP
#undef PROC
#undef COMPSTEP

    #pragma unroll 4
    for (int i = 0; i < 32; ++i) {
        const int r = i * 64 + lane;
        *(float4*)(right + (size_t)r * NDIM + c0) = *(float4*)&slab[r * 4];
    }
}

// ---------------------------------------------------------------------------
// Old scan (fp32 fallback path only)
// ---------------------------------------------------------------------------
__global__ __launch_bounds__(64) void scan_kernel(const float* __restrict__ O,
                                                  const int* __restrict__ idx,
                                                  float* __restrict__ right)
{
    __shared__ float slab[NDIM * 8];
    const int lane = threadIdx.x;
    const int c0 = blockIdx.x * 8;
    const int k  = lane >> 2;
    const int c2 = (lane & 3) * 2;

    for (int r = lane; r < NDIM; r += 64) {
        *(float4*)&slab[r * 8]     = make_float4(0.f, 0.f, 0.f, 0.f);
        *(float4*)&slab[r * 8 + 4] = make_float4(0.f, 0.f, 0.f, 0.f);
    }
    if (lane < 8) slab[(c0 + lane) * 8 + lane] = 1.0f;

    int rows[16]; float a[16]; int wrow;
    #pragma unroll
    for (int j = 0; j < 16; ++j) rows[j] = idx[j];
    {
        const float4* p4 = (const float4*)(O + k * 16);
        #pragma unroll
        for (int q = 0; q < 4; ++q) *(float4*)&a[q * 4] = p4[q];
    }
    wrow = idx[k];

    for (int l = 0; l < LLEV; ++l) {
        int rr[16]; float aa[16];
        const int wr = wrow;
        #pragma unroll
        for (int j = 0; j < 16; ++j) { rr[j] = rows[j]; aa[j] = a[j]; }
        if (l + 1 < LLEV) {
            const int* ip = idx + (l + 1) * 16;
            #pragma unroll
            for (int j = 0; j < 16; ++j) rows[j] = ip[j];
            const float4* p4 = (const float4*)(O + (l + 1) * 256 + k * 16);
            #pragma unroll
            for (int q = 0; q < 4; ++q) *(float4*)&a[q * 4] = p4[q];
            wrow = ip[k];
        }
        float sx = 0.f, sy = 0.f;
        #pragma unroll
        for (int j = 0; j < 16; ++j) {
            float2 v = *(float2*)&slab[rr[j] * 8 + c2];
            sx += aa[j] * v.x;
            sy += aa[j] * v.y;
        }
        *(float2*)&slab[wr * 8 + c2] = make_float2(sx, sy);
    }

    for (int r0 = 0; r0 < NDIM; r0 += 32) {
        const int r = r0 + (lane >> 1);
        const int h = (lane & 1) * 4;
        *(float4*)(right + (size_t)r * NDIM + c0 + h) = *(float4*)&slab[r * 8 + h];
    }
}

// ---------------------------------------------------------------------------
// Split-bf16 MFMA NT gemm with SPLIT-K: blockIdx.z owns K-slice
// [z*K/ksplit, (z+1)*K/ksplit), writes partial to C + z*strideZ.
// 3-pass hi/lo, 128x128 tile, BK=64.
// ---------------------------------------------------------------------------
#define GBK 64
__global__ __launch_bounds__(256) void mfma_nt(const unsigned short* __restrict__ Ah,
                                               const unsigned short* __restrict__ Al,
                                               const unsigned short* __restrict__ Bh,
                                               const unsigned short* __restrict__ Bl,
                                               float* __restrict__ C,
                                               long strideZ,
                                               int M, int N, int K, int ksplit)
{
    __shared__ unsigned short sA_h[8 * 128 * 8];
    __shared__ unsigned short sA_l[8 * 128 * 8];
    __shared__ unsigned short sB_h[8 * 128 * 8];
    __shared__ unsigned short sB_l[8 * 128 * 8];

    const int tid  = threadIdx.x;
    const int wave = tid >> 6, lane = tid & 63;
    const int lm   = lane & 15, quad = lane >> 4;
    const int wm   = wave & 1,  wn   = wave >> 1;
    const int m0   = blockIdx.x * 128, n0 = blockIdx.y * 128;
    const int Kz   = K / ksplit;
    const int kbeg = Kz * blockIdx.z;
    C += (size_t)blockIdx.z * strideZ;

    const unsigned short* gbase;
    unsigned short* sbase;
    if      (wave == 0) { gbase = Ah + (size_t)m0 * K; sbase = sA_h; }
    else if (wave == 1) { gbase = Al + (size_t)m0 * K; sbase = sA_l; }
    else if (wave == 2) { gbase = Bh + (size_t)n0 * K; sbase = sB_h; }
    else                { gbase = Bl + (size_t)n0 * K; sbase = sB_l; }

    f32x4 acc[4][4];
    #pragma unroll
    for (int i = 0; i < 4; ++i)
        #pragma unroll
        for (int j = 0; j < 4; ++j) acc[i][j] = (f32x4){0.f, 0.f, 0.f, 0.f};

    for (int k0 = kbeg; k0 < kbeg + Kz; k0 += GBK) {
        #pragma unroll
        for (int h = 0; h < 2; ++h) {
            const unsigned short* gr = gbase + (size_t)(h * 64 + lane) * K + k0;
            unsigned short* sb = sbase + h * 512;
            #pragma unroll
            for (int c = 0; c < 8; ++c)
                gl2lds16(gr + c * 8, sb + c * 1024);
        }
        __syncthreads();
        #pragma unroll
        for (int sub = 0; sub < 2; ++sub) {
            const int co = (sub * 4 + quad) * 1024;
            bf16x8 ah[4], al[4], bh[4], bl[4];
            #pragma unroll
            for (int i = 0; i < 4; ++i) {
                const int m = wm * 64 + i * 16 + lm;
                ah[i] = *(const bf16x8*)&sA_h[co + m * 8];
                al[i] = *(const bf16x8*)&sA_l[co + m * 8];
            }
            #pragma unroll
            for (int j = 0; j < 4; ++j) {
                const int n = wn * 64 + j * 16 + lm;
                bh[j] = *(const bf16x8*)&sB_h[co + n * 8];
                bl[j] = *(const bf16x8*)&sB_l[co + n * 8];
            }
            #pragma unroll
            for (int i = 0; i < 4; ++i)
                #pragma unroll
                for (int j = 0; j < 4; ++j) {
                    acc[i][j] = __builtin_amdgcn_mfma_f32_16x16x32_bf16(ah[i], bh[j], acc[i][j], 0, 0, 0);
                    acc[i][j] = __builtin_amdgcn_mfma_f32_16x16x32_bf16(ah[i], bl[j], acc[i][j], 0, 0, 0);
                    acc[i][j] = __builtin_amdgcn_mfma_f32_16x16x32_bf16(al[i], bh[j], acc[i][j], 0, 0, 0);
                }
        }
        __syncthreads();
    }
    #pragma unroll
    for (int i = 0; i < 4; ++i) {
        const int mrow = m0 + wm * 64 + i * 16 + quad * 4;
        #pragma unroll
        for (int j = 0; j < 4; ++j) {
            float* cp = C + (size_t)mrow * N + n0 + wn * 64 + j * 16 + lm;
            #pragma unroll
            for (int r = 0; r < 4; ++r) cp[(size_t)r * N] = acc[i][j][r];
        }
    }
}

// ---------------------------------------------------------------------------
// reduce_k: dst[i] = sum_z parts[i + z*strideZ], float4 per thread.
// (dst may alias parts' z=0 slice — each thread owns its own i.)
// ---------------------------------------------------------------------------
__global__ __launch_bounds__(256) void reduce_k(float* __restrict__ dst,
                                                const float* __restrict__ parts,
                                                long strideZ, int nz, long n)
{
    const long i = ((long)blockIdx.x * 256 + threadIdx.x) * 4;
    if (i >= n) return;
    float4 s = *(const float4*)(parts + i);
    for (int z = 1; z < nz; ++z) {
        float4 v = *(const float4*)(parts + (size_t)z * strideZ + i);
        s.x += v.x; s.y += v.y; s.z += v.z; s.w += v.w;
    }
    *(float4*)(dst + i) = s;
}

// ---------------------------------------------------------------------------
// fp32 -> bf16 hi/lo conversion (optional row gather). 4 floats/thread.
// ---------------------------------------------------------------------------
__global__ __launch_bounds__(256) void conv_hl(const float* __restrict__ src,
                                               const int* __restrict__ gidx,
                                               int kshift,
                                               unsigned short* __restrict__ h,
                                               unsigned short* __restrict__ l)
{
    const long e = ((long)blockIdx.x * 256 + threadIdx.x) * 4;
    const float* s;
    if (gidx) {
        const long row = e >> kshift;
        const long col = e - (row << kshift);
        s = src + ((size_t)gidx[row] << kshift) + col;
    } else {
        s = src + e;
    }
    float4 v = *(const float4*)s;
    ushort4 hh, ll;
    split2(v.x, hh.x, ll.x); split2(v.y, hh.y, ll.y);
    split2(v.z, hh.z, ll.z); split2(v.w, hh.w, ll.w);
    *(ushort4*)(h + e) = hh;
    *(ushort4*)(l + e) = ll;
}

// ---------------------------------------------------------------------------
// Transposing fp32 -> bf16 hi/lo: dst[k][m] = src[m][k]. 64x64 LDS tile.
// ---------------------------------------------------------------------------
__global__ __launch_bounds__(256) void tconv_hl(const float* __restrict__ src,
                                                int Msrc, int Ksrc,
                                                unsigned short* __restrict__ h,
                                                unsigned short* __restrict__ l)
{
    __shared__ float t[64][65];
    const int bi = blockIdx.x, bj = blockIdx.y;
    const int tx = threadIdx.x & 15, ty = threadIdx.x >> 4;
    #pragma unroll
    for (int r = 0; r < 4; ++r) {
        const int row = bi * 64 + ty + r * 16;
        float4 v = *(const float4*)(src + (size_t)row * Ksrc + bj * 64 + tx * 4);
        t[ty + r * 16][tx * 4 + 0] = v.x; t[ty + r * 16][tx * 4 + 1] = v.y;
        t[ty + r * 16][tx * 4 + 2] = v.z; t[ty + r * 16][tx * 4 + 3] = v.w;
    }
    __syncthreads();
    #pragma unroll
    for (int r = 0; r < 4; ++r) {
        const int drow = bj * 64 + ty + r * 16;
        ushort4 hh, ll;
        split2(t[tx * 4 + 0][ty + r * 16], hh.x, ll.x);
        split2(t[tx * 4 + 1][ty + r * 16], hh.y, ll.y);
        split2(t[tx * 4 + 2][ty + r * 16], hh.z, ll.z);
        split2(t[tx * 4 + 3][ty + r * 16], hh.w, ll.w);
        *(ushort4*)(h + (size_t)drow * Msrc + bi * 64 + tx * 4) = hh;
        *(ushort4*)(l + (size_t)drow * Msrc + bi * 64 + tx * 4) = ll;
    }
}

// ---------------------------------------------------------------------------
// GT[n,r] = Gfull[r,n] transposed+converted, Gfull fused on the fly.
// ---------------------------------------------------------------------------
__global__ __launch_bounds__(256) void gt_build(const float* __restrict__ W1,
                                                const float* __restrict__ right,
                                                const int* __restrict__ inva,
                                                const float* __restrict__ dmrow,
                                                unsigned short* __restrict__ h,
                                                unsigned short* __restrict__ l)
{
    __shared__ float t[64][65];
    const int bi = blockIdx.x, bj = blockIdx.y;
    const int tx = threadIdx.x & 15, ty = threadIdx.x >> 4;
    #pragma unroll
    for (int rr = 0; rr < 4; ++rr) {
        const int r = bi * 64 + ty + rr * 16;
        const int ia = inva[r];
        float4 v;
        if (ia >= 0) {
            v = *(const float4*)(W1 + (size_t)ia * NDIM + bj * 64 + tx * 4);
        } else {
            v = *(const float4*)(right + (size_t)r * NDIM + bj * 64 + tx * 4);
            const float s = dmrow[r];
            v.x *= s; v.y *= s; v.z *= s; v.w *= s;
        }
        t[ty + rr * 16][tx * 4 + 0] = v.x; t[ty + rr * 16][tx * 4 + 1] = v.y;
        t[ty + rr * 16][tx * 4 + 2] = v.z; t[ty + rr * 16][tx * 4 + 3] = v.w;
    }
    __syncthreads();
    #pragma unroll
    for (int rr = 0; rr < 4; ++rr) {
        const int drow = bj * 64 + ty + rr * 16;
        ushort4 hh, ll;
        split2(t[tx * 4 + 0][ty + rr * 16], hh.x, ll.x);
        split2(t[tx * 4 + 1][ty + rr * 16], hh.y, ll.y);
        split2(t[tx * 4 + 2][ty + rr * 16], hh.z, ll.z);
        split2(t[tx * 4 + 3][ty + rr * 16], hh.w, ll.w);
        *(ushort4*)(h + (size_t)drow * NDIM + bi * 64 + tx * 4) = hh;
        *(ushort4*)(l + (size_t)drow * NDIM + bi * 64 + tx * 4) = ll;
    }
}

// ---------------------------------------------------------------------------
// Small helpers
// ---------------------------------------------------------------------------
__global__ __launch_bounds__(256) void diag_kernel(const float* __restrict__ P,
                                                   const float* __restrict__ R,
                                                   float* __restrict__ diag_all)
{
    __shared__ float red[256];
    const int i = blockIdx.x;
    const float4* p4 = (const float4*)(P + (size_t)i * NDIM);
    const float4* r4 = (const float4*)(R + (size_t)i * NDIM);
    float s = 0.f;
    for (int kq = threadIdx.x; kq < NDIM / 4; kq += 256) {
        float4 a = p4[kq], b = r4[kq];
        s += a.x * b.x + a.y * b.y + a.z * b.z + a.w * b.w;
    }
    red[threadIdx.x] = s;
    __syncthreads();
    for (int off = 128; off > 0; off >>= 1) {
        if (threadIdx.x < off) red[threadIdx.x] += red[threadIdx.x + off];
        __syncthreads();
    }
    if (threadIdx.x == 0) diag_all[i] = red[0];
}

__global__ void prep2_kernel(const int* __restrict__ act, const int* __restrict__ inact,
                             const float* __restrict__ diag_all,
                             int* __restrict__ inva, float* __restrict__ dm,
                             float* __restrict__ dmrow)
{
    const int t = threadIdx.x;
    inva[t] = -1;
    inva[t + HALF] = -1;
    __syncthreads();
    inva[act[t]] = t;
    const int ir = inact[t];
    const float dv = diag_all[ir];
    dm[t] = dv;
    dmrow[ir] = dv;
}

__global__ __launch_bounds__(256) void build_D(const float* __restrict__ Daa,
                                               const float* __restrict__ diag_all,
                                               const int* __restrict__ inva,
                                               float* __restrict__ D)
{
    const int e = blockIdx.x * 256 + threadIdx.x;
    const int i = e >> 11, j = e & (NDIM - 1);
    const int ii = inva[i], jj = inva[j];
    float v = 0.f;
    if (ii >= 0 && jj >= 0) v = Daa[ii * HALF + jj];
    if (i == j) v = diag_all[i];
    D[e] = v;
}

__global__ __launch_bounds__(256) void mc_kernel(const float* __restrict__ dm,
                                                 float* __restrict__ mc)
{
    const int e = blockIdx.x * 256 + threadIdx.x;
    const int t = e >> 10, s = e & (HALF - 1);
    mc[e] = (t == s) ? dm[t] : 0.f;
}

__global__ __launch_bounds__(512) void gather_rows(const float* __restrict__ R,
                                                   const int* __restrict__ ridx,
                                                   float* __restrict__ outp)
{
    const int r = blockIdx.x;
    const int c = threadIdx.x * 4;
    *(float4*)(outp + (size_t)r * NDIM + c) =
        *(const float4*)(R + (size_t)ridx[r] * NDIM + c);
}

// ---------------------------------------------------------------------------
// fp32 fallback gemms (only if ws_size too small for bf16 scratch)
// ---------------------------------------------------------------------------
__global__ __launch_bounds__(256) void gemm_nt64(const float* __restrict__ A, int lda,
                                                 const int* __restrict__ ridxA,
                                                 const float* __restrict__ B, int ldb,
                                                 const int* __restrict__ ridxB,
                                                 float* __restrict__ C, int ldc, int Kk)
{
    __shared__ float As[16][68];
    __shared__ float Bs[16][68];
    const int tid = threadIdx.x;
    const int tx = tid & 15, ty = tid >> 4;
    const int m0 = blockIdx.x * 64, n0 = blockIdx.y * 64;
    const int li = tid >> 2;
    const int lk = (tid & 3) * 4;
    int rowA = m0 + li; if (ridxA) rowA = ridxA[rowA];
    int rowB = n0 + li; if (ridxB) rowB = ridxB[rowB];
    const float* pA = A + (size_t)rowA * lda + lk;
    const float* pB = B + (size_t)rowB * ldb + lk;
    float acc[4][4] = {};
    for (int k0 = 0; k0 < Kk; k0 += 16) {
        float4 a4 = *(const float4*)(pA + k0);
        float4 b4 = *(const float4*)(pB + k0);
        As[lk + 0][li] = a4.x; As[lk + 1][li] = a4.y; As[lk + 2][li] = a4.z; As[lk + 3][li] = a4.w;
        Bs[lk + 0][li] = b4.x; Bs[lk + 1][li] = b4.y; Bs[lk + 2][li] = b4.z; Bs[lk + 3][li] = b4.w;
        __syncthreads();
        #pragma unroll
        for (int kk = 0; kk < 16; ++kk) {
            float4 av = *(const float4*)&As[kk][ty * 4];
            float4 bv = *(const float4*)&Bs[kk][tx * 4];
            float a[4] = {av.x, av.y, av.z, av.w};
            float b[4] = {bv.x, bv.y, bv.z, bv.w};
            #pragma unroll
            for (int i = 0; i < 4; ++i)
                #pragma unroll
                for (int j = 0; j < 4; ++j) acc[i][j] += a[i] * b[j];
        }
        __syncthreads();
    }
    #pragma unroll
    for (int i = 0; i < 4; ++i) {
        float4 v = make_float4(acc[i][0], acc[i][1], acc[i][2], acc[i][3]);
        *(float4*)(C + (size_t)(m0 + ty * 4 + i) * ldc + n0 + tx * 4) = v;
    }
}

__global__ __launch_bounds__(256) void gemm_nn64(const float* __restrict__ A, int lda,
                                                 const float* __restrict__ B, int ldb,
                                                 float* __restrict__ C, int ldc, int Kk)
{
    __shared__ float As[16][68];
    __shared__ float Bs[16][68];
    const int tid = threadIdx.x;
    const int tx = tid & 15, ty = tid >> 4;
    const int m0 = blockIdx.x * 64, n0 = blockIdx.y * 64;
    const int li = tid >> 2;
    const int lk = (tid & 3) * 4;
    const int bk = tid >> 4;
    const int bn = (tid & 15) * 4;
    const float* pA = A + (size_t)(m0 + li) * lda + lk;
    float acc[4][4] = {};
    for (int k0 = 0; k0 < Kk; k0 += 16) {
        float4 a4 = *(const float4*)(pA + k0);
        float4 b4 = *(const float4*)(B + (size_t)(k0 + bk) * ldb + n0 + bn);
        As[lk + 0][li] = a4.x; As[lk + 1][li] = a4.y; As[lk + 2][li] = a4.z; As[lk + 3][li] = a4.w;
        *(float4*)&Bs[bk][bn] = b4;
        __syncthreads();
        #pragma unroll
        for (int kk = 0; kk < 16; ++kk) {
            float4 av = *(const float4*)&As[kk][ty * 4];
            float4 bv = *(const float4*)&Bs[kk][tx * 4];
            float a[4] = {av.x, av.y, av.z, av.w};
            float b[4] = {bv.x, bv.y, bv.z, bv.w};
            #pragma unroll
            for (int i = 0; i < 4; ++i)
                #pragma unroll
                for (int j = 0; j < 4; ++j) acc[i][j] += a[i] * b[j];
        }
        __syncthreads();
    }
    #pragma unroll
    for (int i = 0; i < 4; ++i) {
        float4 v = make_float4(acc[i][0], acc[i][1], acc[i][2], acc[i][3]);
        *(float4*)(C + (size_t)(m0 + ty * 4 + i) * ldc + n0 + tx * 4) = v;
    }
}

__global__ __launch_bounds__(256) void arec64(const float* __restrict__ fw,
                                              const float* __restrict__ mw,
                                              const float* __restrict__ W1,
                                              const float* __restrict__ dm,
                                              float* __restrict__ C)
{
    __shared__ float As[16][68];
    __shared__ float Bs[16][68];
    const int tid = threadIdx.x;
    const int tx = tid & 15, ty = tid >> 4;
    const int m0 = blockIdx.x * 64, n0 = blockIdx.y * 64;
    const int bk = tid >> 4;
    const int bn = (tid & 15) * 4;
    float acc[4][4] = {};
    for (int t0 = 0; t0 < NDIM; t0 += 16) {
        const int t = t0 + bk;
        const float* Hrow; const float* Grow; float gs;
        if (t < HALF) { Hrow = fw + (size_t)t * NDIM; Grow = W1 + (size_t)t * NDIM; gs = 1.f; }
        else          { Hrow = mw + (size_t)(t - HALF) * NDIM; Grow = Hrow; gs = dm[t - HALF]; }
        float4 a4 = *(const float4*)(Hrow + m0 + bn);
        float4 b4 = *(const float4*)(Grow + n0 + bn);
        b4.x *= gs; b4.y *= gs; b4.z *= gs; b4.w *= gs;
        *(float4*)&As[bk][bn] = a4;
        *(float4*)&Bs[bk][bn] = b4;
        __syncthreads();
        #pragma unroll
        for (int kk = 0; kk < 16; ++kk) {
            float4 av = *(const float4*)&As[kk][ty * 4];
            float4 bv = *(const float4*)&Bs[kk][tx * 4];
            float a[4] = {av.x, av.y, av.z, av.w};
            float b[4] = {bv.x, bv.y, bv.z, bv.w};
            #pragma unroll
            for (int i = 0; i < 4; ++i)
                #pragma unroll
                for (int j = 0; j < 4; ++j) acc[i][j] += a[i] * b[j];
        }
        __syncthreads();
    }
    #pragma unroll
    for (int i = 0; i < 4; ++i) {
        float4 v = make_float4(acc[i][0], acc[i][1], acc[i][2], acc[i][3]);
        *(float4*)(C + (size_t)(m0 + ty * 4 + i) * NDIM + n0 + tx * 4) = v;
    }
}

// ---------------------------------------------------------------------------
extern "C" void kernel_launch(void* const* d_in, const int* in_sizes, int n_in,
                              void* d_out, int out_size, void* d_ws, size_t ws_size,
                              hipStream_t stream)
{
    (void)in_sizes; (void)n_in; (void)out_size;
    const float* A     = (const float*)d_in[0];
    const float* O     = (const float*)d_in[1];
    const int*   idx   = (const int*)d_in[2];
    const int*   act   = (const int*)d_in[3];
    const int*   inact = (const int*)d_in[4];

    float* out = (float*)d_out;
    const size_t NN = (size_t)NDIM * NDIM;
    float* A_rec = out;                       // scratch for P until final gemm
    float* right = out + NN;
    float* D     = out + 2 * NN;              // scratch: split-K partials / W1
    float* mc    = out + 3 * NN;
    float* fc    = mc + (size_t)HALF * HALF;  // Daa
    float* mw    = fc + (size_t)HALF * HALF;
    float* fw    = mw + (size_t)HALF * NDIM;

    char*  w        = (char*)d_ws;
    float* diag_all = (float*)w;              // 2048 f
    float* dm       = (float*)(w + 8192);     // 1024 f
    int*   inva     = (int*)(w + 12288);      // 2048 i
    float* dmrow    = (float*)(w + 20480);    // 2048 f

    const size_t MB = 1024 * 1024;
    const size_t WS_NEEDED = 65536 + 32 * MB;

    if (ws_size >= WS_NEEDED) {
        char* r1 = w + 65536;                 // 16 MB: (Warr/Sarr/Warr2/...) -> Rh/Rl -> RTh/RTl
        char* r2 = r1 + 16 * MB;              // 16 MB: Ah/Al -> Pa/F -> D/FT -> GT
        float* Warr  = (float*)r1;            // 1 MB   (consumed by compose2)
        int*   Sarr  = (int*)(r1 + MB);       // 32 KB
        float* Warr2 = (float*)(r1 + 2 * MB); // 2 MB   (consumed by scan4)
        int*   Sarr2 = (int*)(r1 + 4 * MB);   // 32 KB
        unsigned* Spk = (unsigned*)(r1 + 4 * MB + 32 * 1024); // 16 KB
        unsigned short* Rh  = (unsigned short*)r1;
        unsigned short* Rl  = (unsigned short*)(r1 + 8 * MB);
        unsigned short* RTh = Rh;
        unsigned short* RTl = Rl;
        unsigned short* Ah  = (unsigned short*)r2;
        unsigned short* Al  = (unsigned short*)(r2 + 8 * MB);
        unsigned short* Pah = (unsigned short*)r2;             // after P
        unsigned short* Pal = (unsigned short*)(r2 + 4 * MB);
        unsigned short* Fh  = (unsigned short*)(r2 + 8 * MB);
        unsigned short* Fl  = (unsigned short*)(r2 + 12 * MB);
        unsigned short* Dh  = (unsigned short*)r2;             // after Daa
        unsigned short* Dl  = (unsigned short*)(r2 + 2 * MB);
        unsigned short* FTh = (unsigned short*)(r2 + 4 * MB);
        unsigned short* FTl = (unsigned short*)(r2 + 8 * MB);
        unsigned short* GTh = (unsigned short*)r2;             // after W1
        unsigned short* GTl = (unsigned short*)(r2 + 8 * MB);

        // 1. two-stage level composition (512 -> 256 -> 128), then 128-step scan
        compose_kernel<<<256, 64, 0, stream>>>(O, idx, Sarr, Warr);
        compose2_kernel<<<128, 64, 0, stream>>>(Warr, Sarr, Warr2, Sarr2, Spk);
        scan4_kernel<<<512, 64, 0, stream>>>(Warr2, Sarr2, Spk, right);
        // 2. wavelets
        gather_rows<<<1024, 512, 0, stream>>>(right, act, fw);
        gather_rows<<<1024, 512, 0, stream>>>(right, inact, mw);
        // 3. convert R and A to bf16 hi/lo (overwrites compose scratch — consumed)
        conv_hl<<<4096, 256, 0, stream>>>(right, nullptr, 11, Rh, Rl);
        conv_hl<<<4096, 256, 0, stream>>>(A, nullptr, 11, Ah, Al);
        // 4. P = R @ A, split-K=2: z0 -> A_rec, z1 -> D slot; reduce into A_rec
        mfma_nt<<<dim3(16, 16, 2), 256, 0, stream>>>(Rh, Rl, Ah, Al, A_rec,
                                                     (long)2 * NN, NDIM, NDIM, NDIM, 2);
        reduce_k<<<4096, 256, 0, stream>>>(A_rec, A_rec, (long)2 * NN, 2, (long)NN);
        // 5. diag + prep
        diag_kernel<<<2048, 256, 0, stream>>>(A_rec, right, diag_all);
        prep2_kernel<<<1, 1024, 0, stream>>>(act, inact, diag_all, inva, dm, dmrow);
        // 7. Pa = P[act], F = fw in bf16
        conv_hl<<<2048, 256, 0, stream>>>(A_rec, act, 11, Pah, Pal);
        conv_hl<<<2048, 256, 0, stream>>>(fw, nullptr, 11, Fh, Fl);
        // 8. Daa = Pa . F^T, split-K=4: partials in D slot (4 x 4 MB); reduce -> fc
        mfma_nt<<<dim3(8, 8, 4), 256, 0, stream>>>(Pah, Pal, Fh, Fl, D,
                                                   (long)HALF * HALF, HALF, HALF, NDIM, 4);
        reduce_k<<<1024, 256, 0, stream>>>(fc, D, (long)HALF * HALF, 4, (long)HALF * HALF);
        // 9. Dh/Dl = conv(Daa); FT = fw^T
        conv_hl<<<1024, 256, 0, stream>>>(fc, nullptr, 10, Dh, Dl);
        tconv_hl<<<dim3(16, 32), 256, 0, stream>>>(fw, HALF, NDIM, FTh, FTl);
        // 10. W1 = Daa @ fw, split-K=2: z0 -> D (final home), z1 -> D+8MB; reduce
        mfma_nt<<<dim3(8, 16, 2), 256, 0, stream>>>(Dh, Dl, FTh, FTl, D,
                                                    (long)HALF * NDIM, HALF, NDIM, HALF, 2);
        reduce_k<<<2048, 256, 0, stream>>>(D, D, (long)HALF * NDIM, 2, (long)HALF * NDIM);
        // 11. RT = right^T
        tconv_hl<<<dim3(32, 32), 256, 0, stream>>>(right, NDIM, NDIM, RTh, RTl);
        // 12. GT from W1 / dm*right (consumes W1 in D slot)
        gt_build<<<dim3(32, 32), 256, 0, stream>>>(D, right, inva, dmrow, GTh, GTl);
        // 13. A_rec = RT . GT^T, split-K=2: z0 -> A_rec, z1 -> D slot; reduce
        mfma_nt<<<dim3(16, 16, 2), 256, 0, stream>>>(RTh, RTl, GTh, GTl, A_rec,
                                                     (long)2 * NN, NDIM, NDIM, NDIM, 2);
        reduce_k<<<4096, 256, 0, stream>>>(A_rec, A_rec, (long)2 * NN, 2, (long)NN);
        // 14. D output (overwrites partial scratch)
        build_D<<<16384, 256, 0, stream>>>(fc, diag_all, inva, D);
        // 15. mother_coefficients = diag(dm)
        mc_kernel<<<4096, 256, 0, stream>>>(dm, mc);
    } else {
        // fp32 fallback (R1 structure)
        scan_kernel<<<256, 64, 0, stream>>>(O, idx, right);
        gather_rows<<<1024, 512, 0, stream>>>(right, act, fw);
        gather_rows<<<1024, 512, 0, stream>>>(right, inact, mw);
        gemm_nt64<<<dim3(32, 32), 256, 0, stream>>>(right, NDIM, nullptr, A, NDIM, nullptr,
                                                    A_rec, NDIM, NDIM);
        diag_kernel<<<2048, 256, 0, stream>>>(A_rec, right, diag_all);
        prep2_kernel<<<1, 1024, 0, stream>>>(act, inact, diag_all, inva, dm, dmrow);
        gemm_nt64<<<dim3(16, 16), 256, 0, stream>>>(A_rec, NDIM, act, right, NDIM, act,
                                                    fc, HALF, NDIM);
        gemm_nn64<<<dim3(16, 32), 256, 0, stream>>>(fc, HALF, fw, NDIM, D, NDIM, HALF);
        arec64<<<dim3(32, 32), 256, 0, stream>>>(fw, mw, D, dm, A_rec);
        build_D<<<16384, 256, 0, stream>>>(fc, diag_all, inva, D);
        mc_kernel<<<4096, 256, 0, stream>>>(dm, mc);
    }
}

// Round 2
// 695.386 us; speedup vs baseline: 1.0057x; 1.0057x over previous
//
#include <hip/hip_runtime.h>

// Problem constants (N=2048, L=512, K=16, DROP=2, DIM=1024)
#define NDIM 2048
#define LLEV 512
#define KDIM 16
#define HALF 1024

typedef __attribute__((ext_vector_type(8))) short bf16x8;   // 8 bf16 = 4 VGPRs
typedef __attribute__((ext_vector_type(4))) float f32x4;

// ---------------------------------------------------------------------------
// bf16 split helpers: x ~= hi + lo, each RNE bf16 (~16-17 mantissa bits total)
// ---------------------------------------------------------------------------
__device__ inline unsigned short f2bf(float x) {
    unsigned u = __float_as_uint(x);
    u += 0x7fffu + ((u >> 16) & 1u);
    return (unsigned short)(u >> 16);
}
__device__ inline float bf2f(unsigned short b) {
    return __uint_as_float(((unsigned)b) << 16);
}
__device__ inline void split2(float x, unsigned short& h, unsigned short& l) {
    h = f2bf(x);
    l = f2bf(x - bf2f(h));
}

__device__ inline void gl2lds16(const void* g, void* l) {
    __builtin_amdgcn_global_load_lds(
        (const __attribute__((address_space(1))) void*)g,
        (__attribute__((address_space(3))) void*)l, 16, 0, 0);
}

// ---------------------------------------------------------------------------
// compose_kernel: pairwise level composition (validated R4/R5).
// 512 levels of 16 rows -> 256 composites of 32 rows.
// ---------------------------------------------------------------------------
__global__ __launch_bounds__(64) void compose_kernel(const float* __restrict__ O,
                                                     const int* __restrict__ idx,
                                                     int* __restrict__ Sarr,
                                                     float* __restrict__ Warr)
{
    __shared__ int s_S[32];
    __shared__ int s_pos[32];
    __shared__ float s_W[32][33];
    const int t = blockIdx.x;
    const int lane = threadIdx.x;
    const int* a = idx + (2 * t) * 16;
    const int* b = idx + (2 * t + 1) * 16;

    if (lane == 0) {
        int na = 0, i = 0, j = 0;
        while (i < 16 || j < 16) {
            int va = (i < 16) ? a[i] : 0x7fffffff;
            int vb = (j < 16) ? b[j] : 0x7fffffff;
            int v = va < vb ? va : vb;
            if (va == v) i++;
            if (vb == v) j++;
            s_S[na++] = v;
        }
        const int nm = na;
        int r = 0, p = 0;
        while (na < 32) {
            while (p < nm && s_S[p] < r) p++;
            if (p < nm && s_S[p] == r) { r++; continue; }
            s_S[na++] = r++;
        }
    }
    __syncthreads();
    if (lane < 32) {
        const int v = (lane < 16) ? a[lane] : b[lane - 16];
        int pp = 0;
        #pragma unroll
        for (int q = 0; q < 32; ++q) if (s_S[q] == v) pp = q;
        s_pos[lane] = pp;
        #pragma unroll
        for (int c = 0; c < 33; ++c) s_W[lane][c] = 0.f;
        s_W[lane][lane] = 1.f;
    }
    __syncthreads();
    const int j  = lane >> 2;
    const int cg = (lane & 3) * 8;
    #pragma unroll
    for (int step = 0; step < 2; ++step) {
        const float* Om = O + (size_t)(2 * t + step) * 256;
        float acc[8] = {};
        for (int k = 0; k < 16; ++k) {
            const float o = Om[j * 16 + k];
            const int p = s_pos[step * 16 + k];
            #pragma unroll
            for (int c = 0; c < 8; ++c) acc[c] += o * s_W[p][cg + c];
        }
        __syncthreads();
        const int pj = s_pos[step * 16 + j];
        #pragma unroll
        for (int c = 0; c < 8; ++c) s_W[pj][cg + c] = acc[c];
        __syncthreads();
    }
    if (lane < 32) Sarr[t * 32 + lane] = s_S[lane];
    {
        const int r = lane >> 1, h0 = (lane & 1) * 16;
        float* wp = Warr + (size_t)t * 1024 + r * 32 + h0;
        #pragma unroll
        for (int c = 0; c < 16; ++c) wp[c] = s_W[r][h0 + c];
    }
}

// ---------------------------------------------------------------------------
// compose2_kernel: pair 32-row composites -> 128 composites of 64 rows.
// Outputs row-major W2 (64x64), plain row list Sarr2, and packed u16 LDS
// byte offsets Spk (row*16 <= 32752 fits u16, 2 per u32) for scan4's gather.
// ---------------------------------------------------------------------------
__global__ __launch_bounds__(64) void compose2_kernel(const float* __restrict__ Warr,
                                                      const int* __restrict__ Sarr,
                                                      float* __restrict__ Warr2,
                                                      int* __restrict__ Sarr2,
                                                      unsigned int* __restrict__ Spk)
{
    __shared__ int s_S[64];
    __shared__ int s_pos[64];
    __shared__ unsigned s_map[64];
    __shared__ float s_W[64][68];   // stride 68 floats: 16B-aligned rows, bank-safe
    const int t = blockIdx.x;
    const int lane = threadIdx.x;
    const int* a = Sarr + (2 * t) * 32;
    const int* b = Sarr + (2 * t + 1) * 32;

    s_map[lane] = 0u;
    __syncthreads();
    if (lane == 0) {
        int na = 0;
        for (int k = 0; k < 32; ++k) {
            const int v = a[k];
            s_map[v >> 5] |= 1u << (v & 31);
            s_S[na++] = v;
        }
        for (int k = 0; k < 32; ++k) {
            const int v = b[k];
            if (!((s_map[v >> 5] >> (v & 31)) & 1u)) {
                s_map[v >> 5] |= 1u << (v & 31);
                s_S[na++] = v;
            }
        }
        int r = 0;
        while (na < 64) {
            if (!((s_map[r >> 5] >> (r & 31)) & 1u)) s_S[na++] = r;
            ++r;
        }
    }
    __syncthreads();
    {
        const int v = (lane < 32) ? a[lane] : b[lane - 32];
        int pp = 0;
        for (int q = 0; q < 64; ++q) if (s_S[q] == v) pp = q;
        s_pos[lane] = pp;
        #pragma unroll
        for (int c = 0; c < 68; ++c) s_W[lane][c] = 0.f;
        s_W[lane][lane] = 1.f;
    }
    __syncthreads();
    const int j  = lane >> 1;       // 0..31: source-local row of the step matrix
    const int cg = (lane & 1) * 32; // column half
    #pragma unroll
    for (int step = 0; step < 2; ++step) {
        const float* Om = Warr + (size_t)(2 * t + step) * 1024 + j * 32;
        float acc[32] = {};
        for (int k = 0; k < 32; ++k) {
            const float o = Om[k];
            const int p = s_pos[step * 32 + k];
            #pragma unroll
            for (int c4 = 0; c4 < 8; ++c4) {
                float4 v = *(const float4*)&s_W[p][cg + c4 * 4];
                acc[c4 * 4 + 0] += o * v.x;
                acc[c4 * 4 + 1] += o * v.y;
                acc[c4 * 4 + 2] += o * v.z;
                acc[c4 * 4 + 3] += o * v.w;
            }
        }
        __syncthreads();
        const int pj = s_pos[step * 32 + j];
        #pragma unroll
        for (int c4 = 0; c4 < 8; ++c4) {
            float4 v = make_float4(acc[c4 * 4 + 0], acc[c4 * 4 + 1],
                                   acc[c4 * 4 + 2], acc[c4 * 4 + 3]);
            *(float4*)&s_W[pj][cg + c4 * 4] = v;
        }
        __syncthreads();
    }
    Sarr2[t * 64 + lane] = s_S[lane];
    if (lane < 32)
        Spk[t * 32 + lane] = (unsigned)(s_S[2 * lane] << 4)
                           | ((unsigned)(s_S[2 * lane + 1] << 4) << 16);
    {
        float* wp = Warr2 + (size_t)t * 4096 + lane * 64;
        #pragma unroll
        for (int c = 0; c < 16; ++c)
            *(float4*)&wp[c * 4] = *(const float4*)&s_W[lane][c * 4];
    }
}

// ---------------------------------------------------------------------------
// scan4_kernel: 128-step scan over 64-row composites, 4 columns per block.
// One wave per block; each lane owns one full output row (64 coeffs held in
// NAMED f32x4 registers, double-buffered) -> no cross-lane reduce, no scratch.
// R1 post-mortem: float[64] arrays accessed via float4* punning defeated SROA
// and spilled both buffers to scratch (VGPR_Count 88, 240us). All state is now
// named vector variables with compile-time component access only.
// ---------------------------------------------------------------------------
__global__ __launch_bounds__(64, 1) void scan4_kernel(const float* __restrict__ Warr2,
                                                      const int* __restrict__ Sarr2,
                                                      const unsigned int* __restrict__ Spk,
                                                      float* __restrict__ right)
{
    __shared__ float slab[NDIM * 4];
    const int lane = threadIdx.x;
    const int c0 = blockIdx.x * 4;

    for (int r = lane; r < NDIM; r += 64)
        *(f32x4*)&slab[r * 4] = (f32x4){0.f, 0.f, 0.f, 0.f};
    if (lane < 4) slab[(c0 + lane) * 4 + lane] = 1.0f;

    // Per-buffer state: 16 named f32x4 (the lane's 64-coeff row), 8 named int4
    // (32 packed u16 byte-offset pairs), 1 write byte-offset.
    int4 pA0, pA1, pA2, pA3, pA4, pA5, pA6, pA7;
    int4 pB0, pB1, pB2, pB3, pB4, pB5, pB6, pB7;
    f32x4 cA0, cA1, cA2, cA3, cA4, cA5, cA6, cA7;
    f32x4 cA8, cA9, cA10, cA11, cA12, cA13, cA14, cA15;
    f32x4 cB0, cB1, cB2, cB3, cB4, cB5, cB6, cB7;
    f32x4 cB8, cB9, cB10, cB11, cB12, cB13, cB14, cB15;
    int wbA, wbB;

#define LOADSTEP(S, tt)                                                       \
    {                                                                         \
        const int4* sp_ = (const int4*)(Spk + (size_t)(tt) * 32);             \
        p##S##0 = sp_[0]; p##S##1 = sp_[1]; p##S##2 = sp_[2]; p##S##3 = sp_[3]; \
        p##S##4 = sp_[4]; p##S##5 = sp_[5]; p##S##6 = sp_[6]; p##S##7 = sp_[7]; \
        const f32x4* wp_ = (const f32x4*)(Warr2 + (size_t)(tt) * 4096 + lane * 64); \
        c##S##0  = wp_[0];  c##S##1  = wp_[1];  c##S##2  = wp_[2];  c##S##3  = wp_[3];  \
        c##S##4  = wp_[4];  c##S##5  = wp_[5];  c##S##6  = wp_[6];  c##S##7  = wp_[7];  \
        c##S##8  = wp_[8];  c##S##9  = wp_[9];  c##S##10 = wp_[10]; c##S##11 = wp_[11]; \
        c##S##12 = wp_[12]; c##S##13 = wp_[13]; c##S##14 = wp_[14]; c##S##15 = wp_[15]; \
        wb##S = Sarr2[(size_t)(tt) * 64 + lane] << 4;                         \
    }

    // PAIR: one packed u32 -> two broadcast b128 slab reads + 2 vector FMAs.
#define PAIR(W, C0, C1, ACC)                                                  \
    {                                                                         \
        const unsigned w_ = (unsigned)(W);                                    \
        const f32x4 v0_ = *(const f32x4*)((const char*)slab + (w_ & 0xffffu)); \
        const f32x4 v1_ = *(const f32x4*)((const char*)slab + (w_ >> 16));    \
        ACC += v0_ * (C0);                                                    \
        ACC += v1_ * (C1);                                                    \
    }

    // QUAD: one int4 (8 source rows) against two coeff f32x4s.
#define QUAD(P, CLO, CHI, A0, A1)                                             \
    PAIR((P).x, (CLO).x, (CLO).y, A0)                                         \
    PAIR((P).y, (CLO).z, (CLO).w, A1)                                         \
    PAIR((P).z, (CHI).x, (CHI).y, A0)                                         \
    PAIR((P).w, (CHI).z, (CHI).w, A1)

#define COMPSTEP(S)                                                           \
    {                                                                         \
        f32x4 ac0 = {0.f,0.f,0.f,0.f}, ac1 = {0.f,0.f,0.f,0.f};               \
        f32x4 ac2 = {0.f,0.f,0.f,0.f}, ac3 = {0.f,0.f,0.f,0.f};               \
        QUAD(p##S##0, c##S##0,  c##S##1,  ac0, ac1)                           \
        QUAD(p##S##1, c##S##2,  c##S##3,  ac2, ac3)                           \
        QUAD(p##S##2, c##S##4,  c##S##5,  ac0, ac1)                           \
        QUAD(p##S##3, c##S##6,  c##S##7,  ac2, ac3)                           \
        QUAD(p##S##4, c##S##8,  c##S##9,  ac0, ac1)                           \
        QUAD(p##S##5, c##S##10, c##S##11, ac2, ac3)                           \
        QUAD(p##S##6, c##S##12, c##S##13, ac0, ac1)                           \
        QUAD(p##S##7, c##S##14, c##S##15, ac2, ac3)                           \
        const f32x4 o_ = (ac0 + ac1) + (ac2 + ac3);                           \
        *(f32x4*)((char*)slab + wb##S) = o_;                                  \
    }

    LOADSTEP(A, 0)
    for (int t = 0; t < 128; t += 2) {
        LOADSTEP(B, t + 1)
        COMPSTEP(A)
        if (t + 2 < 128) LOADSTEP(A, t + 2)
        COMPSTEP(B)
    }

#undef LOADSTEP
#undef PAIR
#undef QUAD
#undef COMPSTEP

    #pragma unroll 4
    for (int i = 0; i < 32; ++i) {
        const int r = i * 64 + lane;
        *(float4*)(right + (size_t)r * NDIM + c0) = *(float4*)&slab[r * 4];
    }
}

// ---------------------------------------------------------------------------
// Old scan (fp32 fallback path only)
// ---------------------------------------------------------------------------
__global__ __launch_bounds__(64) void scan_kernel(const float* __restrict__ O,
                                                  const int* __restrict__ idx,
                                                  float* __restrict__ right)
{
    __shared__ float slab[NDIM * 8];
    const int lane = threadIdx.x;
    const int c0 = blockIdx.x * 8;
    const int k  = lane >> 2;
    const int c2 = (lane & 3) * 2;

    for (int r = lane; r < NDIM; r += 64) {
        *(float4*)&slab[r * 8]     = make_float4(0.f, 0.f, 0.f, 0.f);
        *(float4*)&slab[r * 8 + 4] = make_float4(0.f, 0.f, 0.f, 0.f);
    }
    if (lane < 8) slab[(c0 + lane) * 8 + lane] = 1.0f;

    int rows[16]; float a[16]; int wrow;
    #pragma unroll
    for (int j = 0; j < 16; ++j) rows[j] = idx[j];
    {
        const float4* p4 = (const float4*)(O + k * 16);
        #pragma unroll
        for (int q = 0; q < 4; ++q) *(float4*)&a[q * 4] = p4[q];
    }
    wrow = idx[k];

    for (int l = 0; l < LLEV; ++l) {
        int rr[16]; float aa[16];
        const int wr = wrow;
        #pragma unroll
        for (int j = 0; j < 16; ++j) { rr[j] = rows[j]; aa[j] = a[j]; }
        if (l + 1 < LLEV) {
            const int* ip = idx + (l + 1) * 16;
            #pragma unroll
            for (int j = 0; j < 16; ++j) rows[j] = ip[j];
            const float4* p4 = (const float4*)(O + (l + 1) * 256 + k * 16);
            #pragma unroll
            for (int q = 0; q < 4; ++q) *(float4*)&a[q * 4] = p4[q];
            wrow = ip[k];
        }
        float sx = 0.f, sy = 0.f;
        #pragma unroll
        for (int j = 0; j < 16; ++j) {
            float2 v = *(float2*)&slab[rr[j] * 8 + c2];
            sx += aa[j] * v.x;
            sy += aa[j] * v.y;
        }
        *(float2*)&slab[wr * 8 + c2] = make_float2(sx, sy);
    }

    for (int r0 = 0; r0 < NDIM; r0 += 32) {
        const int r = r0 + (lane >> 1);
        const int h = (lane & 1) * 4;
        *(float4*)(right + (size_t)r * NDIM + c0 + h) = *(float4*)&slab[r * 8 + h];
    }
}

// ---------------------------------------------------------------------------
// Split-bf16 MFMA NT gemm with SPLIT-K: blockIdx.z owns K-slice
// [z*K/ksplit, (z+1)*K/ksplit), writes partial to C + z*strideZ.
// 3-pass hi/lo, 128x128 tile, BK=64.
// ---------------------------------------------------------------------------
#define GBK 64
__global__ __launch_bounds__(256) void mfma_nt(const unsigned short* __restrict__ Ah,
                                               const unsigned short* __restrict__ Al,
                                               const unsigned short* __restrict__ Bh,
                                               const unsigned short* __restrict__ Bl,
                                               float* __restrict__ C,
                                               long strideZ,
                                               int M, int N, int K, int ksplit)
{
    __shared__ unsigned short sA_h[8 * 128 * 8];
    __shared__ unsigned short sA_l[8 * 128 * 8];
    __shared__ unsigned short sB_h[8 * 128 * 8];
    __shared__ unsigned short sB_l[8 * 128 * 8];

    const int tid  = threadIdx.x;
    const int wave = tid >> 6, lane = tid & 63;
    const int lm   = lane & 15, quad = lane >> 4;
    const int wm   = wave & 1,  wn   = wave >> 1;
    const int m0   = blockIdx.x * 128, n0 = blockIdx.y * 128;
    const int Kz   = K / ksplit;
    const int kbeg = Kz * blockIdx.z;
    C += (size_t)blockIdx.z * strideZ;

    const unsigned short* gbase;
    unsigned short* sbase;
    if      (wave == 0) { gbase = Ah + (size_t)m0 * K; sbase = sA_h; }
    else if (wave == 1) { gbase = Al + (size_t)m0 * K; sbase = sA_l; }
    else if (wave == 2) { gbase = Bh + (size_t)n0 * K; sbase = sB_h; }
    else                { gbase = Bl + (size_t)n0 * K; sbase = sB_l; }

    f32x4 acc[4][4];
    #pragma unroll
    for (int i = 0; i < 4; ++i)
        #pragma unroll
        for (int j = 0; j < 4; ++j) acc[i][j] = (f32x4){0.f, 0.f, 0.f, 0.f};

    for (int k0 = kbeg; k0 < kbeg + Kz; k0 += GBK) {
        #pragma unroll
        for (int h = 0; h < 2; ++h) {
            const unsigned short* gr = gbase + (size_t)(h * 64 + lane) * K + k0;
            unsigned short* sb = sbase + h * 512;
            #pragma unroll
            for (int c = 0; c < 8; ++c)
                gl2lds16(gr + c * 8, sb + c * 1024);
        }
        __syncthreads();
        #pragma unroll
        for (int sub = 0; sub < 2; ++sub) {
            const int co = (sub * 4 + quad) * 1024;
            bf16x8 ah[4], al[4], bh[4], bl[4];
            #pragma unroll
            for (int i = 0; i < 4; ++i) {
                const int m = wm * 64 + i * 16 + lm;
                ah[i] = *(const bf16x8*)&sA_h[co + m * 8];
                al[i] = *(const bf16x8*)&sA_l[co + m * 8];
            }
            #pragma unroll
            for (int j = 0; j < 4; ++j) {
                const int n = wn * 64 + j * 16 + lm;
                bh[j] = *(const bf16x8*)&sB_h[co + n * 8];
                bl[j] = *(const bf16x8*)&sB_l[co + n * 8];
            }
            #pragma unroll
            for (int i = 0; i < 4; ++i)
                #pragma unroll
                for (int j = 0; j < 4; ++j) {
                    acc[i][j] = __builtin_amdgcn_mfma_f32_16x16x32_bf16(ah[i], bh[j], acc[i][j], 0, 0, 0);
                    acc[i][j] = __builtin_amdgcn_mfma_f32_16x16x32_bf16(ah[i], bl[j], acc[i][j], 0, 0, 0);
                    acc[i][j] = __builtin_amdgcn_mfma_f32_16x16x32_bf16(al[i], bh[j], acc[i][j], 0, 0, 0);
                }
        }
        __syncthreads();
    }
    #pragma unroll
    for (int i = 0; i < 4; ++i) {
        const int mrow = m0 + wm * 64 + i * 16 + quad * 4;
        #pragma unroll
        for (int j = 0; j < 4; ++j) {
            float* cp = C + (size_t)mrow * N + n0 + wn * 64 + j * 16 + lm;
            #pragma unroll
            for (int r = 0; r < 4; ++r) cp[(size_t)r * N] = acc[i][j][r];
        }
    }
}

// ---------------------------------------------------------------------------
// reduce_k: dst[i] = sum_z parts[i + z*strideZ], float4 per thread.
// (dst may alias parts' z=0 slice — each thread owns its own i.)
// ---------------------------------------------------------------------------
__global__ __launch_bounds__(256) void reduce_k(float* __restrict__ dst,
                                                const float* __restrict__ parts,
                                                long strideZ, int nz, long n)
{
    const long i = ((long)blockIdx.x * 256 + threadIdx.x) * 4;
    if (i >= n) return;
    float4 s = *(const float4*)(parts + i);
    for (int z = 1; z < nz; ++z) {
        float4 v = *(const float4*)(parts + (size_t)z * strideZ + i);
        s.x += v.x; s.y += v.y; s.z += v.z; s.w += v.w;
    }
    *(float4*)(dst + i) = s;
}

// ---------------------------------------------------------------------------
// fp32 -> bf16 hi/lo conversion (optional row gather). 4 floats/thread.
// ---------------------------------------------------------------------------
__global__ __launch_bounds__(256) void conv_hl(const float* __restrict__ src,
                                               const int* __restrict__ gidx,
                                               int kshift,
                                               unsigned short* __restrict__ h,
                                               unsigned short* __restrict__ l)
{
    const long e = ((long)blockIdx.x * 256 + threadIdx.x) * 4;
    const float* s;
    if (gidx) {
        const long row = e >> kshift;
        const long col = e - (row << kshift);
        s = src + ((size_t)gidx[row] << kshift) + col;
    } else {
        s = src + e;
    }
    float4 v = *(const float4*)s;
    ushort4 hh, ll;
    split2(v.x, hh.x, ll.x); split2(v.y, hh.y, ll.y);
    split2(v.z, hh.z, ll.z); split2(v.w, hh.w, ll.w);
    *(ushort4*)(h + e) = hh;
    *(ushort4*)(l + e) = ll;
}

// ---------------------------------------------------------------------------
// Transposing fp32 -> bf16 hi/lo: dst[k][m] = src[m][k]. 64x64 LDS tile.
// ---------------------------------------------------------------------------
__global__ __launch_bounds__(256) void tconv_hl(const float* __restrict__ src,
                                                int Msrc, int Ksrc,
                                                unsigned short* __restrict__ h,
                                                unsigned short* __restrict__ l)
{
    __shared__ float t[64][65];
    const int bi = blockIdx.x, bj = blockIdx.y;
    const int tx = threadIdx.x & 15, ty = threadIdx.x >> 4;
    #pragma unroll
    for (int r = 0; r < 4; ++r) {
        const int row = bi * 64 + ty + r * 16;
        float4 v = *(const float4*)(src + (size_t)row * Ksrc + bj * 64 + tx * 4);
        t[ty + r * 16][tx * 4 + 0] = v.x; t[ty + r * 16][tx * 4 + 1] = v.y;
        t[ty + r * 16][tx * 4 + 2] = v.z; t[ty + r * 16][tx * 4 + 3] = v.w;
    }
    __syncthreads();
    #pragma unroll
    for (int r = 0; r < 4; ++r) {
        const int drow = bj * 64 + ty + r * 16;
        ushort4 hh, ll;
        split2(t[tx * 4 + 0][ty + r * 16], hh.x, ll.x);
        split2(t[tx * 4 + 1][ty + r * 16], hh.y, ll.y);
        split2(t[tx * 4 + 2][ty + r * 16], hh.z, ll.z);
        split2(t[tx * 4 + 3][ty + r * 16], hh.w, ll.w);
        *(ushort4*)(h + (size_t)drow * Msrc + bi * 64 + tx * 4) = hh;
        *(ushort4*)(l + (size_t)drow * Msrc + bi * 64 + tx * 4) = ll;
    }
}

// ---------------------------------------------------------------------------
// GT[n,r] = Gfull[r,n] transposed+converted, Gfull fused on the fly.
// ---------------------------------------------------------------------------
__global__ __launch_bounds__(256) void gt_build(const float* __restrict__ W1,
                                                const float* __restrict__ right,
                                                const int* __restrict__ inva,
                                                const float* __restrict__ dmrow,
                                                unsigned short* __restrict__ h,
                                                unsigned short* __restrict__ l)
{
    __shared__ float t[64][65];
    const int bi = blockIdx.x, bj = blockIdx.y;
    const int tx = threadIdx.x & 15, ty = threadIdx.x >> 4;
    #pragma unroll
    for (int rr = 0; rr < 4; ++rr) {
        const int r = bi * 64 + ty + rr * 16;
        const int ia = inva[r];
        float4 v;
        if (ia >= 0) {
            v = *(const float4*)(W1 + (size_t)ia * NDIM + bj * 64 + tx * 4);
        } else {
            v = *(const float4*)(right + (size_t)r * NDIM + bj * 64 + tx * 4);
            const float s = dmrow[r];
            v.x *= s; v.y *= s; v.z *= s; v.w *= s;
        }
        t[ty + rr * 16][tx * 4 + 0] = v.x; t[ty + rr * 16][tx * 4 + 1] = v.y;
        t[ty + rr * 16][tx * 4 + 2] = v.z; t[ty + rr * 16][tx * 4 + 3] = v.w;
    }
    __syncthreads();
    #pragma unroll
    for (int rr = 0; rr < 4; ++rr) {
        const int drow = bj * 64 + ty + rr * 16;
        ushort4 hh, ll;
        split2(t[tx * 4 + 0][ty + rr * 16], hh.x, ll.x);
        split2(t[tx * 4 + 1][ty + rr * 16], hh.y, ll.y);
        split2(t[tx * 4 + 2][ty + rr * 16], hh.z, ll.z);
        split2(t[tx * 4 + 3][ty + rr * 16], hh.w, ll.w);
        *(ushort4*)(h + (size_t)drow * NDIM + bi * 64 + tx * 4) = hh;
        *(ushort4*)(l + (size_t)drow * NDIM + bi * 64 + tx * 4) = ll;
    }
}

// ---------------------------------------------------------------------------
// Small helpers
// ---------------------------------------------------------------------------
__global__ __launch_bounds__(256) void diag_kernel(const float* __restrict__ P,
                                                   const float* __restrict__ R,
                                                   float* __restrict__ diag_all)
{
    __shared__ float red[256];
    const int i = blockIdx.x;
    const float4* p4 = (const float4*)(P + (size_t)i * NDIM);
    const float4* r4 = (const float4*)(R + (size_t)i * NDIM);
    float s = 0.f;
    for (int kq = threadIdx.x; kq < NDIM / 4; kq += 256) {
        float4 a = p4[kq], b = r4[kq];
        s += a.x * b.x + a.y * b.y + a.z * b.z + a.w * b.w;
    }
    red[threadIdx.x] = s;
    __syncthreads();
    for (int off = 128; off > 0; off >>= 1) {
        if (threadIdx.x < off) red[threadIdx.x] += red[threadIdx.x + off];
        __syncthreads();
    }
    if (threadIdx.x == 0) diag_all[i] = red[0];
}

__global__ void prep2_kernel(const int* __restrict__ act, const int* __restrict__ inact,
                             const float* __restrict__ diag_all,
                             int* __restrict__ inva, float* __restrict__ dm,
                             float* __restrict__ dmrow)
{
    const int t = threadIdx.x;
    inva[t] = -1;
    inva[t + HALF] = -1;
    __syncthreads();
    inva[act[t]] = t;
    const int ir = inact[t];
    const float dv = diag_all[ir];
    dm[t] = dv;
    dmrow[ir] = dv;
}

__global__ __launch_bounds__(256) void build_D(const float* __restrict__ Daa,
                                               const float* __restrict__ diag_all,
                                               const int* __restrict__ inva,
                                               float* __restrict__ D)
{
    const int e = blockIdx.x * 256 + threadIdx.x;
    const int i = e >> 11, j = e & (NDIM - 1);
    const int ii = inva[i], jj = inva[j];
    float v = 0.f;
    if (ii >= 0 && jj >= 0) v = Daa[ii * HALF + jj];
    if (i == j) v = diag_all[i];
    D[e] = v;
}

__global__ __launch_bounds__(256) void mc_kernel(const float* __restrict__ dm,
                                                 float* __restrict__ mc)
{
    const int e = blockIdx.x * 256 + threadIdx.x;
    const int t = e >> 10, s = e & (HALF - 1);
    mc[e] = (t == s) ? dm[t] : 0.f;
}

__global__ __launch_bounds__(512) void gather_rows(const float* __restrict__ R,
                                                   const int* __restrict__ ridx,
                                                   float* __restrict__ outp)
{
    const int r = blockIdx.x;
    const int c = threadIdx.x * 4;
    *(float4*)(outp + (size_t)r * NDIM + c) =
        *(const float4*)(R + (size_t)ridx[r] * NDIM + c);
}

// ---------------------------------------------------------------------------
// fp32 fallback gemms (only if ws_size too small for bf16 scratch)
// ---------------------------------------------------------------------------
__global__ __launch_bounds__(256) void gemm_nt64(const float* __restrict__ A, int lda,
                                                 const int* __restrict__ ridxA,
                                                 const float* __restrict__ B, int ldb,
                                                 const int* __restrict__ ridxB,
                                                 float* __restrict__ C, int ldc, int Kk)
{
    __shared__ float As[16][68];
    __shared__ float Bs[16][68];
    const int tid = threadIdx.x;
    const int tx = tid & 15, ty = tid >> 4;
    const int m0 = blockIdx.x * 64, n0 = blockIdx.y * 64;
    const int li = tid >> 2;
    const int lk = (tid & 3) * 4;
    int rowA = m0 + li; if (ridxA) rowA = ridxA[rowA];
    int rowB = n0 + li; if (ridxB) rowB = ridxB[rowB];
    const float* pA = A + (size_t)rowA * lda + lk;
    const float* pB = B + (size_t)rowB * ldb + lk;
    float acc[4][4] = {};
    for (int k0 = 0; k0 < Kk; k0 += 16) {
        float4 a4 = *(const float4*)(pA + k0);
        float4 b4 = *(const float4*)(pB + k0);
        As[lk + 0][li] = a4.x; As[lk + 1][li] = a4.y; As[lk + 2][li] = a4.z; As[lk + 3][li] = a4.w;
        Bs[lk + 0][li] = b4.x; Bs[lk + 1][li] = b4.y; Bs[lk + 2][li] = b4.z; Bs[lk + 3][li] = b4.w;
        __syncthreads();
        #pragma unroll
        for (int kk = 0; kk < 16; ++kk) {
            float4 av = *(const float4*)&As[kk][ty * 4];
            float4 bv = *(const float4*)&Bs[kk][tx * 4];
            float a[4] = {av.x, av.y, av.z, av.w};
            float b[4] = {bv.x, bv.y, bv.z, bv.w};
            #pragma unroll
            for (int i = 0; i < 4; ++i)
                #pragma unroll
                for (int j = 0; j < 4; ++j) acc[i][j] += a[i] * b[j];
        }
        __syncthreads();
    }
    #pragma unroll
    for (int i = 0; i < 4; ++i) {
        float4 v = make_float4(acc[i][0], acc[i][1], acc[i][2], acc[i][3]);
        *(float4*)(C + (size_t)(m0 + ty * 4 + i) * ldc + n0 + tx * 4) = v;
    }
}

__global__ __launch_bounds__(256) void gemm_nn64(const float* __restrict__ A, int lda,
                                                 const float* __restrict__ B, int ldb,
                                                 float* __restrict__ C, int ldc, int Kk)
{
    __shared__ float As[16][68];
    __shared__ float Bs[16][68];
    const int tid = threadIdx.x;
    const int tx = tid & 15, ty = tid >> 4;
    const int m0 = blockIdx.x * 64, n0 = blockIdx.y * 64;
    const int li = tid >> 2;
    const int lk = (tid & 3) * 4;
    const int bk = tid >> 4;
    const int bn = (tid & 15) * 4;
    const float* pA = A + (size_t)(m0 + li) * lda + lk;
    float acc[4][4] = {};
    for (int k0 = 0; k0 < Kk; k0 += 16) {
        float4 a4 = *(const float4*)(pA + k0);
        float4 b4 = *(const float4*)(B + (size_t)(k0 + bk) * ldb + n0 + bn);
        As[lk + 0][li] = a4.x; As[lk + 1][li] = a4.y; As[lk + 2][li] = a4.z; As[lk + 3][li] = a4.w;
        *(float4*)&Bs[bk][bn] = b4;
        __syncthreads();
        #pragma unroll
        for (int kk = 0; kk < 16; ++kk) {
            float4 av = *(const float4*)&As[kk][ty * 4];
            float4 bv = *(const float4*)&Bs[kk][tx * 4];
            float a[4] = {av.x, av.y, av.z, av.w};
            float b[4] = {bv.x, bv.y, bv.z, bv.w};
            #pragma unroll
            for (int i = 0; i < 4; ++i)
                #pragma unroll
                for (int j = 0; j < 4; ++j) acc[i][j] += a[i] * b[j];
        }
        __syncthreads();
    }
    #pragma unroll
    for (int i = 0; i < 4; ++i) {
        float4 v = make_float4(acc[i][0], acc[i][1], acc[i][2], acc[i][3]);
        *(float4*)(C + (size_t)(m0 + ty * 4 + i) * ldc + n0 + tx * 4) = v;
    }
}

__global__ __launch_bounds__(256) void arec64(const float* __restrict__ fw,
                                              const float* __restrict__ mw,
                                              const float* __restrict__ W1,
                                              const float* __restrict__ dm,
                                              float* __restrict__ C)
{
    __shared__ float As[16][68];
    __shared__ float Bs[16][68];
    const int tid = threadIdx.x;
    const int tx = tid & 15, ty = tid >> 4;
    const int m0 = blockIdx.x * 64, n0 = blockIdx.y * 64;
    const int bk = tid >> 4;
    const int bn = (tid & 15) * 4;
    float acc[4][4] = {};
    for (int t0 = 0; t0 < NDIM; t0 += 16) {
        const int t = t0 + bk;
        const float* Hrow; const float* Grow; float gs;
        if (t < HALF) { Hrow = fw + (size_t)t * NDIM; Grow = W1 + (size_t)t * NDIM; gs = 1.f; }
        else          { Hrow = mw + (size_t)(t - HALF) * NDIM; Grow = Hrow; gs = dm[t - HALF]; }
        float4 a4 = *(const float4*)(Hrow + m0 + bn);
        float4 b4 = *(const float4*)(Grow + n0 + bn);
        b4.x *= gs; b4.y *= gs; b4.z *= gs; b4.w *= gs;
        *(float4*)&As[bk][bn] = a4;
        *(float4*)&Bs[bk][bn] = b4;
        __syncthreads();
        #pragma unroll
        for (int kk = 0; kk < 16; ++kk) {
            float4 av = *(const float4*)&As[kk][ty * 4];
            float4 bv = *(const float4*)&Bs[kk][tx * 4];
            float a[4] = {av.x, av.y, av.z, av.w};
            float b[4] = {bv.x, bv.y, bv.z, bv.w};
            #pragma unroll
            for (int i = 0; i < 4; ++i)
                #pragma unroll
                for (int j = 0; j < 4; ++j) acc[i][j] += a[i] * b[j];
        }
        __syncthreads();
    }
    #pragma unroll
    for (int i = 0; i < 4; ++i) {
        float4 v = make_float4(acc[i][0], acc[i][1], acc[i][2], acc[i][3]);
        *(float4*)(C + (size_t)(m0 + ty * 4 + i) * NDIM + n0 + tx * 4) = v;
    }
}

// ---------------------------------------------------------------------------
extern "C" void kernel_launch(void* const* d_in, const int* in_sizes, int n_in,
                              void* d_out, int out_size, void* d_ws, size_t ws_size,
                              hipStream_t stream)
{
    (void)in_sizes; (void)n_in; (void)out_size;
    const float* A     = (const float*)d_in[0];
    const float* O     = (const float*)d_in[1];
    const int*   idx   = (const int*)d_in[2];
    const int*   act   = (const int*)d_in[3];
    const int*   inact = (const int*)d_in[4];

    float* out = (float*)d_out;
    const size_t NN = (size_t)NDIM * NDIM;
    float* A_rec = out;                       // scratch for P until final gemm
    float* right = out + NN;
    float* D     = out + 2 * NN;              // scratch: split-K partials / W1
    float* mc    = out + 3 * NN;
    float* fc    = mc + (size_t)HALF * HALF;  // Daa
    float* mw    = fc + (size_t)HALF * HALF;
    float* fw    = mw + (size_t)HALF * NDIM;

    char*  w        = (char*)d_ws;
    float* diag_all = (float*)w;              // 2048 f
    float* dm       = (float*)(w + 8192);     // 1024 f
    int*   inva     = (int*)(w + 12288);      // 2048 i
    float* dmrow    = (float*)(w + 20480);    // 2048 f

    const size_t MB = 1024 * 1024;
    const size_t WS_NEEDED = 65536 + 32 * MB;

    if (ws_size >= WS_NEEDED) {
        char* r1 = w + 65536;                 // 16 MB: (Warr/Sarr/Warr2/...) -> Rh/Rl -> RTh/RTl
        char* r2 = r1 + 16 * MB;              // 16 MB: Ah/Al -> Pa/F -> D/FT -> GT
        float* Warr  = (float*)r1;            // 1 MB   (consumed by compose2)
        int*   Sarr  = (int*)(r1 + MB);       // 32 KB
        float* Warr2 = (float*)(r1 + 2 * MB); // 2 MB   (consumed by scan4)
        int*   Sarr2 = (int*)(r1 + 4 * MB);   // 32 KB
        unsigned* Spk = (unsigned*)(r1 + 4 * MB + 32 * 1024); // 16 KB
        unsigned short* Rh  = (unsigned short*)r1;
        unsigned short* Rl  = (unsigned short*)(r1 + 8 * MB);
        unsigned short* RTh = Rh;
        unsigned short* RTl = Rl;
        unsigned short* Ah  = (unsigned short*)r2;
        unsigned short* Al  = (unsigned short*)(r2 + 8 * MB);
        unsigned short* Pah = (unsigned short*)r2;             // after P
        unsigned short* Pal = (unsigned short*)(r2 + 4 * MB);
        unsigned short* Fh  = (unsigned short*)(r2 + 8 * MB);
        unsigned short* Fl  = (unsigned short*)(r2 + 12 * MB);
        unsigned short* Dh  = (unsigned short*)r2;             // after Daa
        unsigned short* Dl  = (unsigned short*)(r2 + 2 * MB);
        unsigned short* FTh = (unsigned short*)(r2 + 4 * MB);
        unsigned short* FTl = (unsigned short*)(r2 + 8 * MB);
        unsigned short* GTh = (unsigned short*)r2;             // after W1
        unsigned short* GTl = (unsigned short*)(r2 + 8 * MB);

        // 1. two-stage level composition (512 -> 256 -> 128), then 128-step scan
        compose_kernel<<<256, 64, 0, stream>>>(O, idx, Sarr, Warr);
        compose2_kernel<<<128, 64, 0, stream>>>(Warr, Sarr, Warr2, Sarr2, Spk);
        scan4_kernel<<<512, 64, 0, stream>>>(Warr2, Sarr2, Spk, right);
        // 2. wavelets
        gather_rows<<<1024, 512, 0, stream>>>(right, act, fw);
        gather_rows<<<1024, 512, 0, stream>>>(right, inact, mw);
        // 3. convert R and A to bf16 hi/lo (overwrites compose scratch — consumed)
        conv_hl<<<4096, 256, 0, stream>>>(right, nullptr, 11, Rh, Rl);
        conv_hl<<<4096, 256, 0, stream>>>(A, nullptr, 11, Ah, Al);
        // 4. P = R @ A, split-K=2: z0 -> A_rec, z1 -> D slot; reduce into A_rec
        mfma_nt<<<dim3(16, 16, 2), 256, 0, stream>>>(Rh, Rl, Ah, Al, A_rec,
                                                     (long)2 * NN, NDIM, NDIM, NDIM, 2);
        reduce_k<<<4096, 256, 0, stream>>>(A_rec, A_rec, (long)2 * NN, 2, (long)NN);
        // 5. diag + prep
        diag_kernel<<<2048, 256, 0, stream>>>(A_rec, right, diag_all);
        prep2_kernel<<<1, 1024, 0, stream>>>(act, inact, diag_all, inva, dm, dmrow);
        // 7. Pa = P[act], F = fw in bf16
        conv_hl<<<2048, 256, 0, stream>>>(A_rec, act, 11, Pah, Pal);
        conv_hl<<<2048, 256, 0, stream>>>(fw, nullptr, 11, Fh, Fl);
        // 8. Daa = Pa . F^T, split-K=4: partials in D slot (4 x 4 MB); reduce -> fc
        mfma_nt<<<dim3(8, 8, 4), 256, 0, stream>>>(Pah, Pal, Fh, Fl, D,
                                                   (long)HALF * HALF, HALF, HALF, NDIM, 4);
        reduce_k<<<1024, 256, 0, stream>>>(fc, D, (long)HALF * HALF, 4, (long)HALF * HALF);
        // 9. Dh/Dl = conv(Daa); FT = fw^T
        conv_hl<<<1024, 256, 0, stream>>>(fc, nullptr, 10, Dh, Dl);
        tconv_hl<<<dim3(16, 32), 256, 0, stream>>>(fw, HALF, NDIM, FTh, FTl);
        // 10. W1 = Daa @ fw, split-K=2: z0 -> D (final home), z1 -> D+8MB; reduce
        mfma_nt<<<dim3(8, 16, 2), 256, 0, stream>>>(Dh, Dl, FTh, FTl, D,
                                                    (long)HALF * NDIM, HALF, NDIM, HALF, 2);
        reduce_k<<<2048, 256, 0, stream>>>(D, D, (long)HALF * NDIM, 2, (long)HALF * NDIM);
        // 11. RT = right^T
        tconv_hl<<<dim3(32, 32), 256, 0, stream>>>(right, NDIM, NDIM, RTh, RTl);
        // 12. GT from W1 / dm*right (consumes W1 in D slot)
        gt_build<<<dim3(32, 32), 256, 0, stream>>>(D, right, inva, dmrow, GTh, GTl);
        // 13. A_rec = RT . GT^T, split-K=2: z0 -> A_rec, z1 -> D slot; reduce
        mfma_nt<<<dim3(16, 16, 2), 256, 0, stream>>>(RTh, RTl, GTh, GTl, A_rec,
                                                     (long)2 * NN, NDIM, NDIM, NDIM, 2);
        reduce_k<<<4096, 256, 0, stream>>>(A_rec, A_rec, (long)2 * NN, 2, (long)NN);
        // 14. D output (overwrites partial scratch)
        build_D<<<16384, 256, 0, stream>>>(fc, diag_all, inva, D);
        // 15. mother_coefficients = diag(dm)
        mc_kernel<<<4096, 256, 0, stream>>>(dm, mc);
    } else {
        // fp32 fallback (R1 structure)
        scan_kernel<<<256, 64, 0, stream>>>(O, idx, right);
        gather_rows<<<1024, 512, 0, stream>>>(right, act, fw);
        gather_rows<<<1024, 512, 0, stream>>>(right, inact, mw);
        gemm_nt64<<<dim3(32, 32), 256, 0, stream>>>(right, NDIM, nullptr, A, NDIM, nullptr,
                                                    A_rec, NDIM, NDIM);
        diag_kernel<<<2048, 256, 0, stream>>>(A_rec, right, diag_all);
        prep2_kernel<<<1, 1024, 0, stream>>>(act, inact, diag_all, inva, dm, dmrow);
        gemm_nt64<<<dim3(16, 16), 256, 0, stream>>>(A_rec, NDIM, act, right, NDIM, act,
                                                    fc, HALF, NDIM);
        gemm_nn64<<<dim3(16, 32), 256, 0, stream>>>(fc, HALF, fw, NDIM, D, NDIM, HALF);
        arec64<<<dim3(32, 32), 256, 0, stream>>>(fw, mw, D, dm, A_rec);
        build_D<<<16384, 256, 0, stream>>>(fc, diag_all, inva, D);
        mc_kernel<<<4096, 256, 0, stream>>>(dm, mc);
    }
}

// Round 3
// 659.593 us; speedup vs baseline: 1.0602x; 1.0543x over previous
//
#include <hip/hip_runtime.h>

// Problem constants (N=2048, L=512, K=16, DROP=2, DIM=1024)
#define NDIM 2048
#define LLEV 512
#define KDIM 16
#define HALF 1024

typedef __attribute__((ext_vector_type(8))) short bf16x8;   // 8 bf16 = 4 VGPRs
typedef __attribute__((ext_vector_type(4))) float f32x4;

// ---------------------------------------------------------------------------
// bf16 split helpers: x ~= hi + lo, each RNE bf16 (~16-17 mantissa bits total)
// ---------------------------------------------------------------------------
__device__ inline unsigned short f2bf(float x) {
    unsigned u = __float_as_uint(x);
    u += 0x7fffu + ((u >> 16) & 1u);
    return (unsigned short)(u >> 16);
}
__device__ inline float bf2f(unsigned short b) {
    return __uint_as_float(((unsigned)b) << 16);
}
__device__ inline void split2(float x, unsigned short& h, unsigned short& l) {
    h = f2bf(x);
    l = f2bf(x - bf2f(h));
}

__device__ inline void gl2lds16(const void* g, void* l) {
    __builtin_amdgcn_global_load_lds(
        (const __attribute__((address_space(1))) void*)g,
        (__attribute__((address_space(3))) void*)l, 16, 0, 0);
}

// ---------------------------------------------------------------------------
// compose_kernel: pairwise level composition (validated R4/R5).
// 512 levels of 16 rows -> 256 composites of 32 rows.
// ---------------------------------------------------------------------------
__global__ __launch_bounds__(64) void compose_kernel(const float* __restrict__ O,
                                                     const int* __restrict__ idx,
                                                     int* __restrict__ Sarr,
                                                     float* __restrict__ Warr)
{
    __shared__ int s_S[32];
    __shared__ int s_pos[32];
    __shared__ float s_W[32][33];
    const int t = blockIdx.x;
    const int lane = threadIdx.x;
    const int* a = idx + (2 * t) * 16;
    const int* b = idx + (2 * t + 1) * 16;

    if (lane == 0) {
        int na = 0, i = 0, j = 0;
        while (i < 16 || j < 16) {
            int va = (i < 16) ? a[i] : 0x7fffffff;
            int vb = (j < 16) ? b[j] : 0x7fffffff;
            int v = va < vb ? va : vb;
            if (va == v) i++;
            if (vb == v) j++;
            s_S[na++] = v;
        }
        const int nm = na;
        int r = 0, p = 0;
        while (na < 32) {
            while (p < nm && s_S[p] < r) p++;
            if (p < nm && s_S[p] == r) { r++; continue; }
            s_S[na++] = r++;
        }
    }
    __syncthreads();
    if (lane < 32) {
        const int v = (lane < 16) ? a[lane] : b[lane - 16];
        int pp = 0;
        #pragma unroll
        for (int q = 0; q < 32; ++q) if (s_S[q] == v) pp = q;
        s_pos[lane] = pp;
        #pragma unroll
        for (int c = 0; c < 33; ++c) s_W[lane][c] = 0.f;
        s_W[lane][lane] = 1.f;
    }
    __syncthreads();
    const int j  = lane >> 2;
    const int cg = (lane & 3) * 8;
    #pragma unroll
    for (int step = 0; step < 2; ++step) {
        const float* Om = O + (size_t)(2 * t + step) * 256;
        float acc[8] = {};
        for (int k = 0; k < 16; ++k) {
            const float o = Om[j * 16 + k];
            const int p = s_pos[step * 16 + k];
            #pragma unroll
            for (int c = 0; c < 8; ++c) acc[c] += o * s_W[p][cg + c];
        }
        __syncthreads();
        const int pj = s_pos[step * 16 + j];
        #pragma unroll
        for (int c = 0; c < 8; ++c) s_W[pj][cg + c] = acc[c];
        __syncthreads();
    }
    if (lane < 32) Sarr[t * 32 + lane] = s_S[lane];
    {
        const int r = lane >> 1, h0 = (lane & 1) * 16;
        float* wp = Warr + (size_t)t * 1024 + r * 32 + h0;
        #pragma unroll
        for (int c = 0; c < 16; ++c) wp[c] = s_W[r][h0 + c];
    }
}

// ---------------------------------------------------------------------------
// compose2_kernel: pair 32-row composites -> 128 composites of 64 rows.
// Outputs row-major W2 (64x64), plain row list Sarr2, and packed u16 LDS
// byte offsets Spk (row*16 <= 32752 fits u16, 2 per u32) for scan4's gather.
// ---------------------------------------------------------------------------
__global__ __launch_bounds__(64) void compose2_kernel(const float* __restrict__ Warr,
                                                      const int* __restrict__ Sarr,
                                                      float* __restrict__ Warr2,
                                                      int* __restrict__ Sarr2,
                                                      unsigned int* __restrict__ Spk)
{
    __shared__ int s_S[64];
    __shared__ int s_pos[64];
    __shared__ unsigned s_map[64];
    __shared__ float s_W[64][68];   // stride 68 floats: 16B-aligned rows, bank-safe
    const int t = blockIdx.x;
    const int lane = threadIdx.x;
    const int* a = Sarr + (2 * t) * 32;
    const int* b = Sarr + (2 * t + 1) * 32;

    s_map[lane] = 0u;
    __syncthreads();
    if (lane == 0) {
        int na = 0;
        for (int k = 0; k < 32; ++k) {
            const int v = a[k];
            s_map[v >> 5] |= 1u << (v & 31);
            s_S[na++] = v;
        }
        for (int k = 0; k < 32; ++k) {
            const int v = b[k];
            if (!((s_map[v >> 5] >> (v & 31)) & 1u)) {
                s_map[v >> 5] |= 1u << (v & 31);
                s_S[na++] = v;
            }
        }
        int r = 0;
        while (na < 64) {
            if (!((s_map[r >> 5] >> (r & 31)) & 1u)) s_S[na++] = r;
            ++r;
        }
    }
    __syncthreads();
    {
        const int v = (lane < 32) ? a[lane] : b[lane - 32];
        int pp = 0;
        for (int q = 0; q < 64; ++q) if (s_S[q] == v) pp = q;
        s_pos[lane] = pp;
        #pragma unroll
        for (int c = 0; c < 68; ++c) s_W[lane][c] = 0.f;
        s_W[lane][lane] = 1.f;
    }
    __syncthreads();
    const int j  = lane >> 1;       // 0..31: source-local row of the step matrix
    const int cg = (lane & 1) * 32; // column half
    #pragma unroll
    for (int step = 0; step < 2; ++step) {
        const float* Om = Warr + (size_t)(2 * t + step) * 1024 + j * 32;
        float acc[32] = {};
        for (int k = 0; k < 32; ++k) {
            const float o = Om[k];
            const int p = s_pos[step * 32 + k];
            #pragma unroll
            for (int c4 = 0; c4 < 8; ++c4) {
                float4 v = *(const float4*)&s_W[p][cg + c4 * 4];
                acc[c4 * 4 + 0] += o * v.x;
                acc[c4 * 4 + 1] += o * v.y;
                acc[c4 * 4 + 2] += o * v.z;
                acc[c4 * 4 + 3] += o * v.w;
            }
        }
        __syncthreads();
        const int pj = s_pos[step * 32 + j];
        #pragma unroll
        for (int c4 = 0; c4 < 8; ++c4) {
            float4 v = make_float4(acc[c4 * 4 + 0], acc[c4 * 4 + 1],
                                   acc[c4 * 4 + 2], acc[c4 * 4 + 3]);
            *(float4*)&s_W[pj][cg + c4 * 4] = v;
        }
        __syncthreads();
    }
    Sarr2[t * 64 + lane] = s_S[lane];
    if (lane < 32)
        Spk[t * 32 + lane] = (unsigned)(s_S[2 * lane] << 4)
                           | ((unsigned)(s_S[2 * lane + 1] << 4) << 16);
    {
        float* wp = Warr2 + (size_t)t * 4096 + lane * 64;
        #pragma unroll
        for (int c = 0; c < 16; ++c)
            *(float4*)&wp[c * 4] = *(const float4*)&s_W[lane][c * 4];
    }
}

// ---------------------------------------------------------------------------
// scan4_kernel: 128-step scan over 64-row composites, 4 columns per block.
// One wave per block; each lane owns one full output row.
// R2 post-mortem: plain C++ coefficient loads get SUNK to their (single) use
// by the scheduler -> no double-buffer ever exists (VGPR stuck at 88, 240us).
// Fix: issue the 16 dwordx4 coefficient loads as one asm volatile block
// (pinned at issue site), compute the OTHER buffer's step to hide L2 latency,
// then `s_waitcnt vmcnt(0)` + sched_barrier(0) before consuming (rule #18:
// without the sched_barrier, VALU users of asm-defined regs hoist above the
// waitcnt). pk words / write-row stay as C++ loads from wave-uniform
// addresses (SMEM, compiler-managed lgkmcnt).
// ---------------------------------------------------------------------------
__global__ __launch_bounds__(64, 1) void scan4_kernel(const float* __restrict__ Warr2,
                                                      const int* __restrict__ Sarr2,
                                                      const unsigned int* __restrict__ Spk,
                                                      float* __restrict__ right)
{
    __shared__ float slab[NDIM * 4];
    const int lane = threadIdx.x;
    const int c0 = blockIdx.x * 4;

    for (int r = lane; r < NDIM; r += 64)
        *(f32x4*)&slab[r * 4] = (f32x4){0.f, 0.f, 0.f, 0.f};
    if (lane < 4) slab[(c0 + lane) * 4 + lane] = 1.0f;

    int4 pA0, pA1, pA2, pA3, pA4, pA5, pA6, pA7;
    int4 pB0, pB1, pB2, pB3, pB4, pB5, pB6, pB7;
    f32x4 cA0, cA1, cA2, cA3, cA4, cA5, cA6, cA7;
    f32x4 cA8, cA9, cA10, cA11, cA12, cA13, cA14, cA15;
    f32x4 cB0, cB1, cB2, cB3, cB4, cB5, cB6, cB7;
    f32x4 cB8, cB9, cB10, cB11, cB12, cB13, cB14, cB15;
    int wbA, wbB;

    // Issue-pinned coefficient prefetch: 16x global_load_dwordx4 in one
    // volatile asm block (cannot sink). Per-lane address = row `lane` of the
    // 64x64 step matrix (256 B).
#define ASMLOAD(S, tt)                                                        \
    {                                                                         \
        const int4* sp_ = (const int4*)(Spk + (size_t)(tt) * 32);             \
        p##S##0 = sp_[0]; p##S##1 = sp_[1]; p##S##2 = sp_[2]; p##S##3 = sp_[3]; \
        p##S##4 = sp_[4]; p##S##5 = sp_[5]; p##S##6 = sp_[6]; p##S##7 = sp_[7]; \
        wb##S = Sarr2[(size_t)(tt) * 64 + lane] << 4;                         \
        const char* ap_ = (const char*)Warr2 + (size_t)(tt) * 16384 + lane * 256; \
        asm volatile(                                                         \
            "global_load_dwordx4 %0, %16, off\n\t"                            \
            "global_load_dwordx4 %1, %16, off offset:16\n\t"                  \
            "global_load_dwordx4 %2, %16, off offset:32\n\t"                  \
            "global_load_dwordx4 %3, %16, off offset:48\n\t"                  \
            "global_load_dwordx4 %4, %16, off offset:64\n\t"                  \
            "global_load_dwordx4 %5, %16, off offset:80\n\t"                  \
            "global_load_dwordx4 %6, %16, off offset:96\n\t"                  \
            "global_load_dwordx4 %7, %16, off offset:112\n\t"                 \
            "global_load_dwordx4 %8, %16, off offset:128\n\t"                 \
            "global_load_dwordx4 %9, %16, off offset:144\n\t"                 \
            "global_load_dwordx4 %10, %16, off offset:160\n\t"                \
            "global_load_dwordx4 %11, %16, off offset:176\n\t"                \
            "global_load_dwordx4 %12, %16, off offset:192\n\t"                \
            "global_load_dwordx4 %13, %16, off offset:208\n\t"                \
            "global_load_dwordx4 %14, %16, off offset:224\n\t"                \
            "global_load_dwordx4 %15, %16, off offset:240"                    \
            : "=&v"(c##S##0),  "=&v"(c##S##1),  "=&v"(c##S##2),  "=&v"(c##S##3),  \
              "=&v"(c##S##4),  "=&v"(c##S##5),  "=&v"(c##S##6),  "=&v"(c##S##7),  \
              "=&v"(c##S##8),  "=&v"(c##S##9),  "=&v"(c##S##10), "=&v"(c##S##11), \
              "=&v"(c##S##12), "=&v"(c##S##13), "=&v"(c##S##14), "=&v"(c##S##15)  \
            : "v"(ap_));                                                      \
    }

    // Drain the asm loads; sched_barrier stops register-only consumers from
    // hoisting above the waitcnt (guide rule #18).
#define WAITV                                                                 \
    asm volatile("s_waitcnt vmcnt(0)" ::: "memory");                          \
    __builtin_amdgcn_sched_barrier(0);

    // PAIR: one packed u32 -> two broadcast b128 slab reads + 2 vector FMAs.
#define PAIR(W, C0, C1, ACC)                                                  \
    {                                                                         \
        const unsigned w_ = (unsigned)(W);                                    \
        const f32x4 v0_ = *(const f32x4*)((const char*)slab + (w_ & 0xffffu)); \
        const f32x4 v1_ = *(const f32x4*)((const char*)slab + (w_ >> 16));    \
        ACC += v0_ * (C0);                                                    \
        ACC += v1_ * (C1);                                                    \
    }

    // QUAD: one int4 (8 source rows) against two coeff f32x4s.
#define QUAD(P, CLO, CHI, A0, A1)                                             \
    PAIR((P).x, (CLO).x, (CLO).y, A0)                                         \
    PAIR((P).y, (CLO).z, (CLO).w, A1)                                         \
    PAIR((P).z, (CHI).x, (CHI).y, A0)                                         \
    PAIR((P).w, (CHI).z, (CHI).w, A1)

#define COMPSTEP(S)                                                           \
    {                                                                         \
        f32x4 ac0 = {0.f,0.f,0.f,0.f}, ac1 = {0.f,0.f,0.f,0.f};               \
        f32x4 ac2 = {0.f,0.f,0.f,0.f}, ac3 = {0.f,0.f,0.f,0.f};               \
        QUAD(p##S##0, c##S##0,  c##S##1,  ac0, ac1)                           \
        QUAD(p##S##1, c##S##2,  c##S##3,  ac2, ac3)                           \
        QUAD(p##S##2, c##S##4,  c##S##5,  ac0, ac1)                           \
        QUAD(p##S##3, c##S##6,  c##S##7,  ac2, ac3)                           \
        QUAD(p##S##4, c##S##8,  c##S##9,  ac0, ac1)                           \
        QUAD(p##S##5, c##S##10, c##S##11, ac2, ac3)                           \
        QUAD(p##S##6, c##S##12, c##S##13, ac0, ac1)                           \
        QUAD(p##S##7, c##S##14, c##S##15, ac2, ac3)                           \
        const f32x4 o_ = (ac0 + ac1) + (ac2 + ac3);                           \
        *(f32x4*)((char*)slab + wb##S) = o_;                                  \
    }

    ASMLOAD(A, 0)
    WAITV
    for (int t = 0; t < 128; t += 2) {
        ASMLOAD(B, t + 1)      // issue B's loads...
        COMPSTEP(A)            // ...hide their latency under step t
        WAITV                  // B complete
        if (t + 2 < 128) ASMLOAD(A, t + 2)
        COMPSTEP(B)            // step t+1 hides A's next loads
        WAITV                  // A complete
    }

#undef ASMLOAD
#undef WAITV
#undef PAIR
#undef QUAD
#undef COMPSTEP

    #pragma unroll 4
    for (int i = 0; i < 32; ++i) {
        const int r = i * 64 + lane;
        *(float4*)(right + (size_t)r * NDIM + c0) = *(float4*)&slab[r * 4];
    }
}

// ---------------------------------------------------------------------------
// Old scan (fp32 fallback path only)
// ---------------------------------------------------------------------------
__global__ __launch_bounds__(64) void scan_kernel(const float* __restrict__ O,
                                                  const int* __restrict__ idx,
                                                  float* __restrict__ right)
{
    __shared__ float slab[NDIM * 8];
    const int lane = threadIdx.x;
    const int c0 = blockIdx.x * 8;
    const int k  = lane >> 2;
    const int c2 = (lane & 3) * 2;

    for (int r = lane; r < NDIM; r += 64) {
        *(float4*)&slab[r * 8]     = make_float4(0.f, 0.f, 0.f, 0.f);
        *(float4*)&slab[r * 8 + 4] = make_float4(0.f, 0.f, 0.f, 0.f);
    }
    if (lane < 8) slab[(c0 + lane) * 8 + lane] = 1.0f;

    int rows[16]; float a[16]; int wrow;
    #pragma unroll
    for (int j = 0; j < 16; ++j) rows[j] = idx[j];
    {
        const float4* p4 = (const float4*)(O + k * 16);
        #pragma unroll
        for (int q = 0; q < 4; ++q) *(float4*)&a[q * 4] = p4[q];
    }
    wrow = idx[k];

    for (int l = 0; l < LLEV; ++l) {
        int rr[16]; float aa[16];
        const int wr = wrow;
        #pragma unroll
        for (int j = 0; j < 16; ++j) { rr[j] = rows[j]; aa[j] = a[j]; }
        if (l + 1 < LLEV) {
            const int* ip = idx + (l + 1) * 16;
            #pragma unroll
            for (int j = 0; j < 16; ++j) rows[j] = ip[j];
            const float4* p4 = (const float4*)(O + (l + 1) * 256 + k * 16);
            #pragma unroll
            for (int q = 0; q < 4; ++q) *(float4*)&a[q * 4] = p4[q];
            wrow = ip[k];
        }
        float sx = 0.f, sy = 0.f;
        #pragma unroll
        for (int j = 0; j < 16; ++j) {
            float2 v = *(float2*)&slab[rr[j] * 8 + c2];
            sx += aa[j] * v.x;
            sy += aa[j] * v.y;
        }
        *(float2*)&slab[wr * 8 + c2] = make_float2(sx, sy);
    }

    for (int r0 = 0; r0 < NDIM; r0 += 32) {
        const int r = r0 + (lane >> 1);
        const int h = (lane & 1) * 4;
        *(float4*)(right + (size_t)r * NDIM + c0 + h) = *(float4*)&slab[r * 8 + h];
    }
}

// ---------------------------------------------------------------------------
// Split-bf16 MFMA NT gemm with SPLIT-K: blockIdx.z owns K-slice
// [z*K/ksplit, (z+1)*K/ksplit), writes partial to C + z*strideZ.
// 3-pass hi/lo, 128x128 tile, BK=64.
// ---------------------------------------------------------------------------
#define GBK 64
__global__ __launch_bounds__(256) void mfma_nt(const unsigned short* __restrict__ Ah,
                                               const unsigned short* __restrict__ Al,
                                               const unsigned short* __restrict__ Bh,
                                               const unsigned short* __restrict__ Bl,
                                               float* __restrict__ C,
                                               long strideZ,
                                               int M, int N, int K, int ksplit)
{
    __shared__ unsigned short sA_h[8 * 128 * 8];
    __shared__ unsigned short sA_l[8 * 128 * 8];
    __shared__ unsigned short sB_h[8 * 128 * 8];
    __shared__ unsigned short sB_l[8 * 128 * 8];

    const int tid  = threadIdx.x;
    const int wave = tid >> 6, lane = tid & 63;
    const int lm   = lane & 15, quad = lane >> 4;
    const int wm   = wave & 1,  wn   = wave >> 1;
    const int m0   = blockIdx.x * 128, n0 = blockIdx.y * 128;
    const int Kz   = K / ksplit;
    const int kbeg = Kz * blockIdx.z;
    C += (size_t)blockIdx.z * strideZ;

    const unsigned short* gbase;
    unsigned short* sbase;
    if      (wave == 0) { gbase = Ah + (size_t)m0 * K; sbase = sA_h; }
    else if (wave == 1) { gbase = Al + (size_t)m0 * K; sbase = sA_l; }
    else if (wave == 2) { gbase = Bh + (size_t)n0 * K; sbase = sB_h; }
    else                { gbase = Bl + (size_t)n0 * K; sbase = sB_l; }

    f32x4 acc[4][4];
    #pragma unroll
    for (int i = 0; i < 4; ++i)
        #pragma unroll
        for (int j = 0; j < 4; ++j) acc[i][j] = (f32x4){0.f, 0.f, 0.f, 0.f};

    for (int k0 = kbeg; k0 < kbeg + Kz; k0 += GBK) {
        #pragma unroll
        for (int h = 0; h < 2; ++h) {
            const unsigned short* gr = gbase + (size_t)(h * 64 + lane) * K + k0;
            unsigned short* sb = sbase + h * 512;
            #pragma unroll
            for (int c = 0; c < 8; ++c)
                gl2lds16(gr + c * 8, sb + c * 1024);
        }
        __syncthreads();
        #pragma unroll
        for (int sub = 0; sub < 2; ++sub) {
            const int co = (sub * 4 + quad) * 1024;
            bf16x8 ah[4], al[4], bh[4], bl[4];
            #pragma unroll
            for (int i = 0; i < 4; ++i) {
                const int m = wm * 64 + i * 16 + lm;
                ah[i] = *(const bf16x8*)&sA_h[co + m * 8];
                al[i] = *(const bf16x8*)&sA_l[co + m * 8];
            }
            #pragma unroll
            for (int j = 0; j < 4; ++j) {
                const int n = wn * 64 + j * 16 + lm;
                bh[j] = *(const bf16x8*)&sB_h[co + n * 8];
                bl[j] = *(const bf16x8*)&sB_l[co + n * 8];
            }
            #pragma unroll
            for (int i = 0; i < 4; ++i)
                #pragma unroll
                for (int j = 0; j < 4; ++j) {
                    acc[i][j] = __builtin_amdgcn_mfma_f32_16x16x32_bf16(ah[i], bh[j], acc[i][j], 0, 0, 0);
                    acc[i][j] = __builtin_amdgcn_mfma_f32_16x16x32_bf16(ah[i], bl[j], acc[i][j], 0, 0, 0);
                    acc[i][j] = __builtin_amdgcn_mfma_f32_16x16x32_bf16(al[i], bh[j], acc[i][j], 0, 0, 0);
                }
        }
        __syncthreads();
    }
    #pragma unroll
    for (int i = 0; i < 4; ++i) {
        const int mrow = m0 + wm * 64 + i * 16 + quad * 4;
        #pragma unroll
        for (int j = 0; j < 4; ++j) {
            float* cp = C + (size_t)mrow * N + n0 + wn * 64 + j * 16 + lm;
            #pragma unroll
            for (int r = 0; r < 4; ++r) cp[(size_t)r * N] = acc[i][j][r];
        }
    }
}

// ---------------------------------------------------------------------------
// reduce_k: dst[i] = sum_z parts[i + z*strideZ], float4 per thread.
// (dst may alias parts' z=0 slice — each thread owns its own i.)
// ---------------------------------------------------------------------------
__global__ __launch_bounds__(256) void reduce_k(float* __restrict__ dst,
                                                const float* __restrict__ parts,
                                                long strideZ, int nz, long n)
{
    const long i = ((long)blockIdx.x * 256 + threadIdx.x) * 4;
    if (i >= n) return;
    float4 s = *(const float4*)(parts + i);
    for (int z = 1; z < nz; ++z) {
        float4 v = *(const float4*)(parts + (size_t)z * strideZ + i);
        s.x += v.x; s.y += v.y; s.z += v.z; s.w += v.w;
    }
    *(float4*)(dst + i) = s;
}

// ---------------------------------------------------------------------------
// fp32 -> bf16 hi/lo conversion (optional row gather). 4 floats/thread.
// ---------------------------------------------------------------------------
__global__ __launch_bounds__(256) void conv_hl(const float* __restrict__ src,
                                               const int* __restrict__ gidx,
                                               int kshift,
                                               unsigned short* __restrict__ h,
                                               unsigned short* __restrict__ l)
{
    const long e = ((long)blockIdx.x * 256 + threadIdx.x) * 4;
    const float* s;
    if (gidx) {
        const long row = e >> kshift;
        const long col = e - (row << kshift);
        s = src + ((size_t)gidx[row] << kshift) + col;
    } else {
        s = src + e;
    }
    float4 v = *(const float4*)s;
    ushort4 hh, ll;
    split2(v.x, hh.x, ll.x); split2(v.y, hh.y, ll.y);
    split2(v.z, hh.z, ll.z); split2(v.w, hh.w, ll.w);
    *(ushort4*)(h + e) = hh;
    *(ushort4*)(l + e) = ll;
}

// ---------------------------------------------------------------------------
// Transposing fp32 -> bf16 hi/lo: dst[k][m] = src[m][k]. 64x64 LDS tile.
// ---------------------------------------------------------------------------
__global__ __launch_bounds__(256) void tconv_hl(const float* __restrict__ src,
                                                int Msrc, int Ksrc,
                                                unsigned short* __restrict__ h,
                                                unsigned short* __restrict__ l)
{
    __shared__ float t[64][65];
    const int bi = blockIdx.x, bj = blockIdx.y;
    const int tx = threadIdx.x & 15, ty = threadIdx.x >> 4;
    #pragma unroll
    for (int r = 0; r < 4; ++r) {
        const int row = bi * 64 + ty + r * 16;
        float4 v = *(const float4*)(src + (size_t)row * Ksrc + bj * 64 + tx * 4);
        t[ty + r * 16][tx * 4 + 0] = v.x; t[ty + r * 16][tx * 4 + 1] = v.y;
        t[ty + r * 16][tx * 4 + 2] = v.z; t[ty + r * 16][tx * 4 + 3] = v.w;
    }
    __syncthreads();
    #pragma unroll
    for (int r = 0; r < 4; ++r) {
        const int drow = bj * 64 + ty + r * 16;
        ushort4 hh, ll;
        split2(t[tx * 4 + 0][ty + r * 16], hh.x, ll.x);
        split2(t[tx * 4 + 1][ty + r * 16], hh.y, ll.y);
        split2(t[tx * 4 + 2][ty + r * 16], hh.z, ll.z);
        split2(t[tx * 4 + 3][ty + r * 16], hh.w, ll.w);
        *(ushort4*)(h + (size_t)drow * Msrc + bi * 64 + tx * 4) = hh;
        *(ushort4*)(l + (size_t)drow * Msrc + bi * 64 + tx * 4) = ll;
    }
}

// ---------------------------------------------------------------------------
// GT[n,r] = Gfull[r,n] transposed+converted, Gfull fused on the fly.
// ---------------------------------------------------------------------------
__global__ __launch_bounds__(256) void gt_build(const float* __restrict__ W1,
                                                const float* __restrict__ right,
                                                const int* __restrict__ inva,
                                                const float* __restrict__ dmrow,
                                                unsigned short* __restrict__ h,
                                                unsigned short* __restrict__ l)
{
    __shared__ float t[64][65];
    const int bi = blockIdx.x, bj = blockIdx.y;
    const int tx = threadIdx.x & 15, ty = threadIdx.x >> 4;
    #pragma unroll
    for (int rr = 0; rr < 4; ++rr) {
        const int r = bi * 64 + ty + rr * 16;
        const int ia = inva[r];
        float4 v;
        if (ia >= 0) {
            v = *(const float4*)(W1 + (size_t)ia * NDIM + bj * 64 + tx * 4);
        } else {
            v = *(const float4*)(right + (size_t)r * NDIM + bj * 64 + tx * 4);
            const float s = dmrow[r];
            v.x *= s; v.y *= s; v.z *= s; v.w *= s;
        }
        t[ty + rr * 16][tx * 4 + 0] = v.x; t[ty + rr * 16][tx * 4 + 1] = v.y;
        t[ty + rr * 16][tx * 4 + 2] = v.z; t[ty + rr * 16][tx * 4 + 3] = v.w;
    }
    __syncthreads();
    #pragma unroll
    for (int rr = 0; rr < 4; ++rr) {
        const int drow = bj * 64 + ty + rr * 16;
        ushort4 hh, ll;
        split2(t[tx * 4 + 0][ty + rr * 16], hh.x, ll.x);
        split2(t[tx * 4 + 1][ty + rr * 16], hh.y, ll.y);
        split2(t[tx * 4 + 2][ty + rr * 16], hh.z, ll.z);
        split2(t[tx * 4 + 3][ty + rr * 16], hh.w, ll.w);
        *(ushort4*)(h + (size_t)drow * NDIM + bi * 64 + tx * 4) = hh;
        *(ushort4*)(l + (size_t)drow * NDIM + bi * 64 + tx * 4) = ll;
    }
}

// ---------------------------------------------------------------------------
// Small helpers
// ---------------------------------------------------------------------------
__global__ __launch_bounds__(256) void diag_kernel(const float* __restrict__ P,
                                                   const float* __restrict__ R,
                                                   float* __restrict__ diag_all)
{
    __shared__ float red[256];
    const int i = blockIdx.x;
    const float4* p4 = (const float4*)(P + (size_t)i * NDIM);
    const float4* r4 = (const float4*)(R + (size_t)i * NDIM);
    float s = 0.f;
    for (int kq = threadIdx.x; kq < NDIM / 4; kq += 256) {
        float4 a = p4[kq], b = r4[kq];
        s += a.x * b.x + a.y * b.y + a.z * b.z + a.w * b.w;
    }
    red[threadIdx.x] = s;
    __syncthreads();
    for (int off = 128; off > 0; off >>= 1) {
        if (threadIdx.x < off) red[threadIdx.x] += red[threadIdx.x + off];
        __syncthreads();
    }
    if (threadIdx.x == 0) diag_all[i] = red[0];
}

__global__ void prep2_kernel(const int* __restrict__ act, const int* __restrict__ inact,
                             const float* __restrict__ diag_all,
                             int* __restrict__ inva, float* __restrict__ dm,
                             float* __restrict__ dmrow)
{
    const int t = threadIdx.x;
    inva[t] = -1;
    inva[t + HALF] = -1;
    __syncthreads();
    inva[act[t]] = t;
    const int ir = inact[t];
    const float dv = diag_all[ir];
    dm[t] = dv;
    dmrow[ir] = dv;
}

__global__ __launch_bounds__(256) void build_D(const float* __restrict__ Daa,
                                               const float* __restrict__ diag_all,
                                               const int* __restrict__ inva,
                                               float* __restrict__ D)
{
    const int e = blockIdx.x * 256 + threadIdx.x;
    const int i = e >> 11, j = e & (NDIM - 1);
    const int ii = inva[i], jj = inva[j];
    float v = 0.f;
    if (ii >= 0 && jj >= 0) v = Daa[ii * HALF + jj];
    if (i == j) v = diag_all[i];
    D[e] = v;
}

__global__ __launch_bounds__(256) void mc_kernel(const float* __restrict__ dm,
                                                 float* __restrict__ mc)
{
    const int e = blockIdx.x * 256 + threadIdx.x;
    const int t = e >> 10, s = e & (HALF - 1);
    mc[e] = (t == s) ? dm[t] : 0.f;
}

__global__ __launch_bounds__(512) void gather_rows(const float* __restrict__ R,
                                                   const int* __restrict__ ridx,
                                                   float* __restrict__ outp)
{
    const int r = blockIdx.x;
    const int c = threadIdx.x * 4;
    *(float4*)(outp + (size_t)r * NDIM + c) =
        *(const float4*)(R + (size_t)ridx[r] * NDIM + c);
}

// ---------------------------------------------------------------------------
// fp32 fallback gemms (only if ws_size too small for bf16 scratch)
// ---------------------------------------------------------------------------
__global__ __launch_bounds__(256) void gemm_nt64(const float* __restrict__ A, int lda,
                                                 const int* __restrict__ ridxA,
                                                 const float* __restrict__ B, int ldb,
                                                 const int* __restrict__ ridxB,
                                                 float* __restrict__ C, int ldc, int Kk)
{
    __shared__ float As[16][68];
    __shared__ float Bs[16][68];
    const int tid = threadIdx.x;
    const int tx = tid & 15, ty = tid >> 4;
    const int m0 = blockIdx.x * 64, n0 = blockIdx.y * 64;
    const int li = tid >> 2;
    const int lk = (tid & 3) * 4;
    int rowA = m0 + li; if (ridxA) rowA = ridxA[rowA];
    int rowB = n0 + li; if (ridxB) rowB = ridxB[rowB];
    const float* pA = A + (size_t)rowA * lda + lk;
    const float* pB = B + (size_t)rowB * ldb + lk;
    float acc[4][4] = {};
    for (int k0 = 0; k0 < Kk; k0 += 16) {
        float4 a4 = *(const float4*)(pA + k0);
        float4 b4 = *(const float4*)(pB + k0);
        As[lk + 0][li] = a4.x; As[lk + 1][li] = a4.y; As[lk + 2][li] = a4.z; As[lk + 3][li] = a4.w;
        Bs[lk + 0][li] = b4.x; Bs[lk + 1][li] = b4.y; Bs[lk + 2][li] = b4.z; Bs[lk + 3][li] = b4.w;
        __syncthreads();
        #pragma unroll
        for (int kk = 0; kk < 16; ++kk) {
            float4 av = *(const float4*)&As[kk][ty * 4];
            float4 bv = *(const float4*)&Bs[kk][tx * 4];
            float a[4] = {av.x, av.y, av.z, av.w};
            float b[4] = {bv.x, bv.y, bv.z, bv.w};
            #pragma unroll
            for (int i = 0; i < 4; ++i)
                #pragma unroll
                for (int j = 0; j < 4; ++j) acc[i][j] += a[i] * b[j];
        }
        __syncthreads();
    }
    #pragma unroll
    for (int i = 0; i < 4; ++i) {
        float4 v = make_float4(acc[i][0], acc[i][1], acc[i][2], acc[i][3]);
        *(float4*)(C + (size_t)(m0 + ty * 4 + i) * ldc + n0 + tx * 4) = v;
    }
}

__global__ __launch_bounds__(256) void gemm_nn64(const float* __restrict__ A, int lda,
                                                 const float* __restrict__ B, int ldb,
                                                 float* __restrict__ C, int ldc, int Kk)
{
    __shared__ float As[16][68];
    __shared__ float Bs[16][68];
    const int tid = threadIdx.x;
    const int tx = tid & 15, ty = tid >> 4;
    const int m0 = blockIdx.x * 64, n0 = blockIdx.y * 64;
    const int li = tid >> 2;
    const int lk = (tid & 3) * 4;
    const int bk = tid >> 4;
    const int bn = (tid & 15) * 4;
    const float* pA = A + (size_t)(m0 + li) * lda + lk;
    float acc[4][4] = {};
    for (int k0 = 0; k0 < Kk; k0 += 16) {
        float4 a4 = *(const float4*)(pA + k0);
        float4 b4 = *(const float4*)(B + (size_t)(k0 + bk) * ldb + n0 + bn);
        As[lk + 0][li] = a4.x; As[lk + 1][li] = a4.y; As[lk + 2][li] = a4.z; As[lk + 3][li] = a4.w;
        *(float4*)&Bs[bk][bn] = b4;
        __syncthreads();
        #pragma unroll
        for (int kk = 0; kk < 16; ++kk) {
            float4 av = *(const float4*)&As[kk][ty * 4];
            float4 bv = *(const float4*)&Bs[kk][tx * 4];
            float a[4] = {av.x, av.y, av.z, av.w};
            float b[4] = {bv.x, bv.y, bv.z, bv.w};
            #pragma unroll
            for (int i = 0; i < 4; ++i)
                #pragma unroll
                for (int j = 0; j < 4; ++j) acc[i][j] += a[i] * b[j];
        }
        __syncthreads();
    }
    #pragma unroll
    for (int i = 0; i < 4; ++i) {
        float4 v = make_float4(acc[i][0], acc[i][1], acc[i][2], acc[i][3]);
        *(float4*)(C + (size_t)(m0 + ty * 4 + i) * ldc + n0 + tx * 4) = v;
    }
}

__global__ __launch_bounds__(256) void arec64(const float* __restrict__ fw,
                                              const float* __restrict__ mw,
                                              const float* __restrict__ W1,
                                              const float* __restrict__ dm,
                                              float* __restrict__ C)
{
    __shared__ float As[16][68];
    __shared__ float Bs[16][68];
    const int tid = threadIdx.x;
    const int tx = tid & 15, ty = tid >> 4;
    const int m0 = blockIdx.x * 64, n0 = blockIdx.y * 64;
    const int bk = tid >> 4;
    const int bn = (tid & 15) * 4;
    float acc[4][4] = {};
    for (int t0 = 0; t0 < NDIM; t0 += 16) {
        const int t = t0 + bk;
        const float* Hrow; const float* Grow; float gs;
        if (t < HALF) { Hrow = fw + (size_t)t * NDIM; Grow = W1 + (size_t)t * NDIM; gs = 1.f; }
        else          { Hrow = mw + (size_t)(t - HALF) * NDIM; Grow = Hrow; gs = dm[t - HALF]; }
        float4 a4 = *(const float4*)(Hrow + m0 + bn);
        float4 b4 = *(const float4*)(Grow + n0 + bn);
        b4.x *= gs; b4.y *= gs; b4.z *= gs; b4.w *= gs;
        *(float4*)&As[bk][bn] = a4;
        *(float4*)&Bs[bk][bn] = b4;
        __syncthreads();
        #pragma unroll
        for (int kk = 0; kk < 16; ++kk) {
            float4 av = *(const float4*)&As[kk][ty * 4];
            float4 bv = *(const float4*)&Bs[kk][tx * 4];
            float a[4] = {av.x, av.y, av.z, av.w};
            float b[4] = {bv.x, bv.y, bv.z, bv.w};
            #pragma unroll
            for (int i = 0; i < 4; ++i)
                #pragma unroll
                for (int j = 0; j < 4; ++j) acc[i][j] += a[i] * b[j];
        }
        __syncthreads();
    }
    #pragma unroll
    for (int i = 0; i < 4; ++i) {
        float4 v = make_float4(acc[i][0], acc[i][1], acc[i][2], acc[i][3]);
        *(float4*)(C + (size_t)(m0 + ty * 4 + i) * NDIM + n0 + tx * 4) = v;
    }
}

// ---------------------------------------------------------------------------
extern "C" void kernel_launch(void* const* d_in, const int* in_sizes, int n_in,
                              void* d_out, int out_size, void* d_ws, size_t ws_size,
                              hipStream_t stream)
{
    (void)in_sizes; (void)n_in; (void)out_size;
    const float* A     = (const float*)d_in[0];
    const float* O     = (const float*)d_in[1];
    const int*   idx   = (const int*)d_in[2];
    const int*   act   = (const int*)d_in[3];
    const int*   inact = (const int*)d_in[4];

    float* out = (float*)d_out;
    const size_t NN = (size_t)NDIM * NDIM;
    float* A_rec = out;                       // scratch for P until final gemm
    float* right = out + NN;
    float* D     = out + 2 * NN;              // scratch: split-K partials / W1
    float* mc    = out + 3 * NN;
    float* fc    = mc + (size_t)HALF * HALF;  // Daa
    float* mw    = fc + (size_t)HALF * HALF;
    float* fw    = mw + (size_t)HALF * NDIM;

    char*  w        = (char*)d_ws;
    float* diag_all = (float*)w;              // 2048 f
    float* dm       = (float*)(w + 8192);     // 1024 f
    int*   inva     = (int*)(w + 12288);      // 2048 i
    float* dmrow    = (float*)(w + 20480);    // 2048 f

    const size_t MB = 1024 * 1024;
    const size_t WS_NEEDED = 65536 + 32 * MB;

    if (ws_size >= WS_NEEDED) {
        char* r1 = w + 65536;                 // 16 MB: (Warr/Sarr/Warr2/...) -> Rh/Rl -> RTh/RTl
        char* r2 = r1 + 16 * MB;              // 16 MB: Ah/Al -> Pa/F -> D/FT -> GT
        float* Warr  = (float*)r1;            // 1 MB   (consumed by compose2)
        int*   Sarr  = (int*)(r1 + MB);       // 32 KB
        float* Warr2 = (float*)(r1 + 2 * MB); // 2 MB   (consumed by scan4)
        int*   Sarr2 = (int*)(r1 + 4 * MB);   // 32 KB
        unsigned* Spk = (unsigned*)(r1 + 4 * MB + 32 * 1024); // 16 KB
        unsigned short* Rh  = (unsigned short*)r1;
        unsigned short* Rl  = (unsigned short*)(r1 + 8 * MB);
        unsigned short* RTh = Rh;
        unsigned short* RTl = Rl;
        unsigned short* Ah  = (unsigned short*)r2;
        unsigned short* Al  = (unsigned short*)(r2 + 8 * MB);
        unsigned short* Pah = (unsigned short*)r2;             // after P
        unsigned short* Pal = (unsigned short*)(r2 + 4 * MB);
        unsigned short* Fh  = (unsigned short*)(r2 + 8 * MB);
        unsigned short* Fl  = (unsigned short*)(r2 + 12 * MB);
        unsigned short* Dh  = (unsigned short*)r2;             // after Daa
        unsigned short* Dl  = (unsigned short*)(r2 + 2 * MB);
        unsigned short* FTh = (unsigned short*)(r2 + 4 * MB);
        unsigned short* FTl = (unsigned short*)(r2 + 8 * MB);
        unsigned short* GTh = (unsigned short*)r2;             // after W1
        unsigned short* GTl = (unsigned short*)(r2 + 8 * MB);

        // 1. two-stage level composition (512 -> 256 -> 128), then 128-step scan
        compose_kernel<<<256, 64, 0, stream>>>(O, idx, Sarr, Warr);
        compose2_kernel<<<128, 64, 0, stream>>>(Warr, Sarr, Warr2, Sarr2, Spk);
        scan4_kernel<<<512, 64, 0, stream>>>(Warr2, Sarr2, Spk, right);
        // 2. wavelets
        gather_rows<<<1024, 512, 0, stream>>>(right, act, fw);
        gather_rows<<<1024, 512, 0, stream>>>(right, inact, mw);
        // 3. convert R and A to bf16 hi/lo (overwrites compose scratch — consumed)
        conv_hl<<<4096, 256, 0, stream>>>(right, nullptr, 11, Rh, Rl);
        conv_hl<<<4096, 256, 0, stream>>>(A, nullptr, 11, Ah, Al);
        // 4. P = R @ A, split-K=2: z0 -> A_rec, z1 -> D slot; reduce into A_rec
        mfma_nt<<<dim3(16, 16, 2), 256, 0, stream>>>(Rh, Rl, Ah, Al, A_rec,
                                                     (long)2 * NN, NDIM, NDIM, NDIM, 2);
        reduce_k<<<4096, 256, 0, stream>>>(A_rec, A_rec, (long)2 * NN, 2, (long)NN);
        // 5. diag + prep
        diag_kernel<<<2048, 256, 0, stream>>>(A_rec, right, diag_all);
        prep2_kernel<<<1, 1024, 0, stream>>>(act, inact, diag_all, inva, dm, dmrow);
        // 7. Pa = P[act], F = fw in bf16
        conv_hl<<<2048, 256, 0, stream>>>(A_rec, act, 11, Pah, Pal);
        conv_hl<<<2048, 256, 0, stream>>>(fw, nullptr, 11, Fh, Fl);
        // 8. Daa = Pa . F^T, split-K=4: partials in D slot (4 x 4 MB); reduce -> fc
        mfma_nt<<<dim3(8, 8, 4), 256, 0, stream>>>(Pah, Pal, Fh, Fl, D,
                                                   (long)HALF * HALF, HALF, HALF, NDIM, 4);
        reduce_k<<<1024, 256, 0, stream>>>(fc, D, (long)HALF * HALF, 4, (long)HALF * HALF);
        // 9. Dh/Dl = conv(Daa); FT = fw^T
        conv_hl<<<1024, 256, 0, stream>>>(fc, nullptr, 10, Dh, Dl);
        tconv_hl<<<dim3(16, 32), 256, 0, stream>>>(fw, HALF, NDIM, FTh, FTl);
        // 10. W1 = Daa @ fw, split-K=2: z0 -> D (final home), z1 -> D+8MB; reduce
        mfma_nt<<<dim3(8, 16, 2), 256, 0, stream>>>(Dh, Dl, FTh, FTl, D,
                                                    (long)HALF * NDIM, HALF, NDIM, HALF, 2);
        reduce_k<<<2048, 256, 0, stream>>>(D, D, (long)HALF * NDIM, 2, (long)HALF * NDIM);
        // 11. RT = right^T
        tconv_hl<<<dim3(32, 32), 256, 0, stream>>>(right, NDIM, NDIM, RTh, RTl);
        // 12. GT from W1 / dm*right (consumes W1 in D slot)
        gt_build<<<dim3(32, 32), 256, 0, stream>>>(D, right, inva, dmrow, GTh, GTl);
        // 13. A_rec = RT . GT^T, split-K=2: z0 -> A_rec, z1 -> D slot; reduce
        mfma_nt<<<dim3(16, 16, 2), 256, 0, stream>>>(RTh, RTl, GTh, GTl, A_rec,
                                                     (long)2 * NN, NDIM, NDIM, NDIM, 2);
        reduce_k<<<4096, 256, 0, stream>>>(A_rec, A_rec, (long)2 * NN, 2, (long)NN);
        // 14. D output (overwrites partial scratch)
        build_D<<<16384, 256, 0, stream>>>(fc, diag_all, inva, D);
        // 15. mother_coefficients = diag(dm)
        mc_kernel<<<4096, 256, 0, stream>>>(dm, mc);
    } else {
        // fp32 fallback (R1 structure)
        scan_kernel<<<256, 64, 0, stream>>>(O, idx, right);
        gather_rows<<<1024, 512, 0, stream>>>(right, act, fw);
        gather_rows<<<1024, 512, 0, stream>>>(right, inact, mw);
        gemm_nt64<<<dim3(32, 32), 256, 0, stream>>>(right, NDIM, nullptr, A, NDIM, nullptr,
                                                    A_rec, NDIM, NDIM);
        diag_kernel<<<2048, 256, 0, stream>>>(A_rec, right, diag_all);
        prep2_kernel<<<1, 1024, 0, stream>>>(act, inact, diag_all, inva, dm, dmrow);
        gemm_nt64<<<dim3(16, 16), 256, 0, stream>>>(A_rec, NDIM, act, right, NDIM, act,
                                                    fc, HALF, NDIM);
        gemm_nn64<<<dim3(16, 32), 256, 0, stream>>>(fc, HALF, fw, NDIM, D, NDIM, HALF);
        arec64<<<dim3(32, 32), 256, 0, stream>>>(fw, mw, D, dm, A_rec);
        build_D<<<16384, 256, 0, stream>>>(fc, diag_all, inva, D);
        mc_kernel<<<4096, 256, 0, stream>>>(dm, mc);
    }
}

// Round 4
// 559.045 us; speedup vs baseline: 1.2509x; 1.1799x over previous
//
#include <hip/hip_runtime.h>

// Problem constants (N=2048, L=512, K=16, DROP=2, DIM=1024)
#define NDIM 2048
#define LLEV 512
#define KDIM 16
#define HALF 1024

typedef __attribute__((ext_vector_type(8))) short bf16x8;   // 8 bf16 = 4 VGPRs
typedef __attribute__((ext_vector_type(4))) float f32x4;

// ---------------------------------------------------------------------------
// bf16 split helpers: x ~= hi + lo, each RNE bf16 (~16-17 mantissa bits total)
// ---------------------------------------------------------------------------
__device__ inline unsigned short f2bf(float x) {
    unsigned u = __float_as_uint(x);
    u += 0x7fffu + ((u >> 16) & 1u);
    return (unsigned short)(u >> 16);
}
__device__ inline float bf2f(unsigned short b) {
    return __uint_as_float(((unsigned)b) << 16);
}
__device__ inline void split2(float x, unsigned short& h, unsigned short& l) {
    h = f2bf(x);
    l = f2bf(x - bf2f(h));
}

__device__ inline void gl2lds16(const void* g, void* l) {
    __builtin_amdgcn_global_load_lds(
        (const __attribute__((address_space(1))) void*)g,
        (__attribute__((address_space(3))) void*)l, 16, 0, 0);
}

// ---------------------------------------------------------------------------
// compose_kernel: pairwise level composition (validated R4/R5).
// 512 levels of 16 rows -> 256 composites of 32 rows.
// ---------------------------------------------------------------------------
__global__ __launch_bounds__(64) void compose_kernel(const float* __restrict__ O,
                                                     const int* __restrict__ idx,
                                                     int* __restrict__ Sarr,
                                                     float* __restrict__ Warr)
{
    __shared__ int s_S[32];
    __shared__ int s_pos[32];
    __shared__ float s_W[32][33];
    const int t = blockIdx.x;
    const int lane = threadIdx.x;
    const int* a = idx + (2 * t) * 16;
    const int* b = idx + (2 * t + 1) * 16;

    if (lane == 0) {
        int na = 0, i = 0, j = 0;
        while (i < 16 || j < 16) {
            int va = (i < 16) ? a[i] : 0x7fffffff;
            int vb = (j < 16) ? b[j] : 0x7fffffff;
            int v = va < vb ? va : vb;
            if (va == v) i++;
            if (vb == v) j++;
            s_S[na++] = v;
        }
        const int nm = na;
        int r = 0, p = 0;
        while (na < 32) {
            while (p < nm && s_S[p] < r) p++;
            if (p < nm && s_S[p] == r) { r++; continue; }
            s_S[na++] = r++;
        }
    }
    __syncthreads();
    if (lane < 32) {
        const int v = (lane < 16) ? a[lane] : b[lane - 16];
        int pp = 0;
        #pragma unroll
        for (int q = 0; q < 32; ++q) if (s_S[q] == v) pp = q;
        s_pos[lane] = pp;
        #pragma unroll
        for (int c = 0; c < 33; ++c) s_W[lane][c] = 0.f;
        s_W[lane][lane] = 1.f;
    }
    __syncthreads();
    const int j  = lane >> 2;
    const int cg = (lane & 3) * 8;
    #pragma unroll
    for (int step = 0; step < 2; ++step) {
        const float* Om = O + (size_t)(2 * t + step) * 256;
        float acc[8] = {};
        for (int k = 0; k < 16; ++k) {
            const float o = Om[j * 16 + k];
            const int p = s_pos[step * 16 + k];
            #pragma unroll
            for (int c = 0; c < 8; ++c) acc[c] += o * s_W[p][cg + c];
        }
        __syncthreads();
        const int pj = s_pos[step * 16 + j];
        #pragma unroll
        for (int c = 0; c < 8; ++c) s_W[pj][cg + c] = acc[c];
        __syncthreads();
    }
    if (lane < 32) Sarr[t * 32 + lane] = s_S[lane];
    {
        const int r = lane >> 1, h0 = (lane & 1) * 16;
        float* wp = Warr + (size_t)t * 1024 + r * 32 + h0;
        #pragma unroll
        for (int c = 0; c < 16; ++c) wp[c] = s_W[r][h0 + c];
    }
}

// ---------------------------------------------------------------------------
// scan3_kernel: batch-2 scan with k-split lanes (validated R5; the proven
// 128us scan). R1-R3 fat-step variants all regressed — reverted.
// ---------------------------------------------------------------------------
__global__ __launch_bounds__(64) void scan3_kernel(const float* __restrict__ Warr,
                                                   const int* __restrict__ Sarr,
                                                   float* __restrict__ right)
{
    __shared__ float slab[NDIM * 4];
    const int lane = threadIdx.x;
    const int c0 = blockIdx.x * 4;
    const int rr = lane & 31;
    const int ks = lane >> 5;

    for (int r = lane; r < NDIM; r += 64)
        *(float4*)&slab[r * 4] = make_float4(0.f, 0.f, 0.f, 0.f);
    if (lane < 4) slab[(c0 + lane) * 4 + lane] = 1.0f;

    int rows[16]; float cf[16]; int wrow;
    {
        const int4* sp = (const int4*)(Sarr + ks * 16);
        #pragma unroll
        for (int q = 0; q < 4; ++q) *(int4*)&rows[q * 4] = sp[q];
        const float4* wp = (const float4*)(Warr + rr * 32 + ks * 16);
        #pragma unroll
        for (int q = 0; q < 4; ++q) *(float4*)&cf[q * 4] = wp[q];
        wrow = Sarr[rr];
    }

    for (int t = 0; t < 256; ++t) {
        int cr[16]; float cc[16];
        const int wr = wrow;
        #pragma unroll
        for (int q = 0; q < 16; ++q) { cr[q] = rows[q]; cc[q] = cf[q]; }
        if (t + 1 < 256) {
            const int4* sp = (const int4*)(Sarr + (t + 1) * 32 + ks * 16);
            #pragma unroll
            for (int q = 0; q < 4; ++q) *(int4*)&rows[q * 4] = sp[q];
            const float4* wp = (const float4*)(Warr + (size_t)(t + 1) * 1024 + rr * 32 + ks * 16);
            #pragma unroll
            for (int q = 0; q < 4; ++q) *(float4*)&cf[q * 4] = wp[q];
            wrow = Sarr[(t + 1) * 32 + rr];
        }
        float4 acc = make_float4(0.f, 0.f, 0.f, 0.f);
        #pragma unroll
        for (int j = 0; j < 16; ++j) {
            float4 v = *(const float4*)&slab[cr[j] * 4];
            acc.x += cc[j] * v.x; acc.y += cc[j] * v.y;
            acc.z += cc[j] * v.z; acc.w += cc[j] * v.w;
        }
        acc.x += __shfl_xor(acc.x, 32, 64);
        acc.y += __shfl_xor(acc.y, 32, 64);
        acc.z += __shfl_xor(acc.z, 32, 64);
        acc.w += __shfl_xor(acc.w, 32, 64);
        if (lane < 32)
            *(float4*)&slab[wr * 4] = acc;
    }

    #pragma unroll 4
    for (int i = 0; i < 32; ++i) {
        const int r = i * 64 + lane;
        *(float4*)(right + (size_t)r * NDIM + c0) = *(float4*)&slab[r * 4];
    }
}

// ---------------------------------------------------------------------------
// Old scan (fp32 fallback path only)
// ---------------------------------------------------------------------------
__global__ __launch_bounds__(64) void scan_kernel(const float* __restrict__ O,
                                                  const int* __restrict__ idx,
                                                  float* __restrict__ right)
{
    __shared__ float slab[NDIM * 8];
    const int lane = threadIdx.x;
    const int c0 = blockIdx.x * 8;
    const int k  = lane >> 2;
    const int c2 = (lane & 3) * 2;

    for (int r = lane; r < NDIM; r += 64) {
        *(float4*)&slab[r * 8]     = make_float4(0.f, 0.f, 0.f, 0.f);
        *(float4*)&slab[r * 8 + 4] = make_float4(0.f, 0.f, 0.f, 0.f);
    }
    if (lane < 8) slab[(c0 + lane) * 8 + lane] = 1.0f;

    int rows[16]; float a[16]; int wrow;
    #pragma unroll
    for (int j = 0; j < 16; ++j) rows[j] = idx[j];
    {
        const float4* p4 = (const float4*)(O + k * 16);
        #pragma unroll
        for (int q = 0; q < 4; ++q) *(float4*)&a[q * 4] = p4[q];
    }
    wrow = idx[k];

    for (int l = 0; l < LLEV; ++l) {
        int rr[16]; float aa[16];
        const int wr = wrow;
        #pragma unroll
        for (int j = 0; j < 16; ++j) { rr[j] = rows[j]; aa[j] = a[j]; }
        if (l + 1 < LLEV) {
            const int* ip = idx + (l + 1) * 16;
            #pragma unroll
            for (int j = 0; j < 16; ++j) rows[j] = ip[j];
            const float4* p4 = (const float4*)(O + (l + 1) * 256 + k * 16);
            #pragma unroll
            for (int q = 0; q < 4; ++q) *(float4*)&a[q * 4] = p4[q];
            wrow = ip[k];
        }
        float sx = 0.f, sy = 0.f;
        #pragma unroll
        for (int j = 0; j < 16; ++j) {
            float2 v = *(float2*)&slab[rr[j] * 8 + c2];
            sx += aa[j] * v.x;
            sy += aa[j] * v.y;
        }
        *(float2*)&slab[wr * 8 + c2] = make_float2(sx, sy);
    }

    for (int r0 = 0; r0 < NDIM; r0 += 32) {
        const int r = r0 + (lane >> 1);
        const int h = (lane & 1) * 4;
        *(float4*)(right + (size_t)r * NDIM + c0 + h) = *(float4*)&slab[r * 8 + h];
    }
}

// ---------------------------------------------------------------------------
// Split-bf16 MFMA NT gemm with SPLIT-K: blockIdx.z owns K-slice
// [z*K/ksplit, (z+1)*K/ksplit), writes partial to C + z*strideZ.
// 3-pass hi/lo, 128x128 tile, BK=64.
// ---------------------------------------------------------------------------
#define GBK 64
__global__ __launch_bounds__(256) void mfma_nt(const unsigned short* __restrict__ Ah,
                                               const unsigned short* __restrict__ Al,
                                               const unsigned short* __restrict__ Bh,
                                               const unsigned short* __restrict__ Bl,
                                               float* __restrict__ C,
                                               long strideZ,
                                               int M, int N, int K, int ksplit)
{
    __shared__ unsigned short sA_h[8 * 128 * 8];
    __shared__ unsigned short sA_l[8 * 128 * 8];
    __shared__ unsigned short sB_h[8 * 128 * 8];
    __shared__ unsigned short sB_l[8 * 128 * 8];

    const int tid  = threadIdx.x;
    const int wave = tid >> 6, lane = tid & 63;
    const int lm   = lane & 15, quad = lane >> 4;
    const int wm   = wave & 1,  wn   = wave >> 1;
    const int m0   = blockIdx.x * 128, n0 = blockIdx.y * 128;
    const int Kz   = K / ksplit;
    const int kbeg = Kz * blockIdx.z;
    C += (size_t)blockIdx.z * strideZ;

    const unsigned short* gbase;
    unsigned short* sbase;
    if      (wave == 0) { gbase = Ah + (size_t)m0 * K; sbase = sA_h; }
    else if (wave == 1) { gbase = Al + (size_t)m0 * K; sbase = sA_l; }
    else if (wave == 2) { gbase = Bh + (size_t)n0 * K; sbase = sB_h; }
    else                { gbase = Bl + (size_t)n0 * K; sbase = sB_l; }

    f32x4 acc[4][4];
    #pragma unroll
    for (int i = 0; i < 4; ++i)
        #pragma unroll
        for (int j = 0; j < 4; ++j) acc[i][j] = (f32x4){0.f, 0.f, 0.f, 0.f};

    for (int k0 = kbeg; k0 < kbeg + Kz; k0 += GBK) {
        #pragma unroll
        for (int h = 0; h < 2; ++h) {
            const unsigned short* gr = gbase + (size_t)(h * 64 + lane) * K + k0;
            unsigned short* sb = sbase + h * 512;
            #pragma unroll
            for (int c = 0; c < 8; ++c)
                gl2lds16(gr + c * 8, sb + c * 1024);
        }
        __syncthreads();
        #pragma unroll
        for (int sub = 0; sub < 2; ++sub) {
            const int co = (sub * 4 + quad) * 1024;
            bf16x8 ah[4], al[4], bh[4], bl[4];
            #pragma unroll
            for (int i = 0; i < 4; ++i) {
                const int m = wm * 64 + i * 16 + lm;
                ah[i] = *(const bf16x8*)&sA_h[co + m * 8];
                al[i] = *(const bf16x8*)&sA_l[co + m * 8];
            }
            #pragma unroll
            for (int j = 0; j < 4; ++j) {
                const int n = wn * 64 + j * 16 + lm;
                bh[j] = *(const bf16x8*)&sB_h[co + n * 8];
                bl[j] = *(const bf16x8*)&sB_l[co + n * 8];
            }
            #pragma unroll
            for (int i = 0; i < 4; ++i)
                #pragma unroll
                for (int j = 0; j < 4; ++j) {
                    acc[i][j] = __builtin_amdgcn_mfma_f32_16x16x32_bf16(ah[i], bh[j], acc[i][j], 0, 0, 0);
                    acc[i][j] = __builtin_amdgcn_mfma_f32_16x16x32_bf16(ah[i], bl[j], acc[i][j], 0, 0, 0);
                    acc[i][j] = __builtin_amdgcn_mfma_f32_16x16x32_bf16(al[i], bh[j], acc[i][j], 0, 0, 0);
                }
        }
        __syncthreads();
    }
    #pragma unroll
    for (int i = 0; i < 4; ++i) {
        const int mrow = m0 + wm * 64 + i * 16 + quad * 4;
        #pragma unroll
        for (int j = 0; j < 4; ++j) {
            float* cp = C + (size_t)mrow * N + n0 + wn * 64 + j * 16 + lm;
            #pragma unroll
            for (int r = 0; r < 4; ++r) cp[(size_t)r * N] = acc[i][j][r];
        }
    }
}

// ---------------------------------------------------------------------------
// reduce_k: dst[i] = sum_z parts[i + z*strideZ], float4 per thread.
// (dst may alias parts' z=0 slice — each thread owns its own i.)
// ---------------------------------------------------------------------------
__global__ __launch_bounds__(256) void reduce_k(float* __restrict__ dst,
                                                const float* __restrict__ parts,
                                                long strideZ, int nz, long n)
{
    const long i = ((long)blockIdx.x * 256 + threadIdx.x) * 4;
    if (i >= n) return;
    float4 s = *(const float4*)(parts + i);
    for (int z = 1; z < nz; ++z) {
        float4 v = *(const float4*)(parts + (size_t)z * strideZ + i);
        s.x += v.x; s.y += v.y; s.z += v.z; s.w += v.w;
    }
    *(float4*)(dst + i) = s;
}

// ---------------------------------------------------------------------------
// fp32 -> bf16 hi/lo conversion (optional row gather; optional second source
// summed in — fuses a split-K reduce into the conversion, bit-identical to
// reduce_k-then-conv). 4 floats/thread.
// ---------------------------------------------------------------------------
__global__ __launch_bounds__(256) void conv_hl(const float* __restrict__ src,
                                               const float* __restrict__ src2,
                                               const int* __restrict__ gidx,
                                               int kshift,
                                               unsigned short* __restrict__ h,
                                               unsigned short* __restrict__ l)
{
    const long e = ((long)blockIdx.x * 256 + threadIdx.x) * 4;
    long off;
    if (gidx) {
        const long row = e >> kshift;
        const long col = e - (row << kshift);
        off = ((size_t)gidx[row] << kshift) + col;
    } else {
        off = e;
    }
    float4 v = *(const float4*)(src + off);
    if (src2) {
        float4 v2 = *(const float4*)(src2 + off);
        v.x += v2.x; v.y += v2.y; v.z += v2.z; v.w += v2.w;
    }
    ushort4 hh, ll;
    split2(v.x, hh.x, ll.x); split2(v.y, hh.y, ll.y);
    split2(v.z, hh.z, ll.z); split2(v.w, hh.w, ll.w);
    *(ushort4*)(h + e) = hh;
    *(ushort4*)(l + e) = ll;
}

// ---------------------------------------------------------------------------
// gather_conv: fw[r] = right[act[r]]; also emits bf16 hi/lo of the row.
// Fuses gather_rows(fw) + conv_hl(fw) into one pass.
// ---------------------------------------------------------------------------
__global__ __launch_bounds__(512) void gather_conv(const float* __restrict__ R,
                                                   const int* __restrict__ ridx,
                                                   float* __restrict__ outp,
                                                   unsigned short* __restrict__ h,
                                                   unsigned short* __restrict__ l)
{
    const int r = blockIdx.x;
    const int c = threadIdx.x * 4;
    const size_t e = (size_t)r * NDIM + c;
    float4 v = *(const float4*)(R + (size_t)ridx[r] * NDIM + c);
    *(float4*)(outp + e) = v;
    ushort4 hh, ll;
    split2(v.x, hh.x, ll.x); split2(v.y, hh.y, ll.y);
    split2(v.z, hh.z, ll.z); split2(v.w, hh.w, ll.w);
    *(ushort4*)(h + e) = hh;
    *(ushort4*)(l + e) = ll;
}

// ---------------------------------------------------------------------------
// Transposing fp32 -> bf16 hi/lo: dst[k][m] = src[m][k]. 64x64 LDS tile.
// ---------------------------------------------------------------------------
__global__ __launch_bounds__(256) void tconv_hl(const float* __restrict__ src,
                                                int Msrc, int Ksrc,
                                                unsigned short* __restrict__ h,
                                                unsigned short* __restrict__ l)
{
    __shared__ float t[64][65];
    const int bi = blockIdx.x, bj = blockIdx.y;
    const int tx = threadIdx.x & 15, ty = threadIdx.x >> 4;
    #pragma unroll
    for (int r = 0; r < 4; ++r) {
        const int row = bi * 64 + ty + r * 16;
        float4 v = *(const float4*)(src + (size_t)row * Ksrc + bj * 64 + tx * 4);
        t[ty + r * 16][tx * 4 + 0] = v.x; t[ty + r * 16][tx * 4 + 1] = v.y;
        t[ty + r * 16][tx * 4 + 2] = v.z; t[ty + r * 16][tx * 4 + 3] = v.w;
    }
    __syncthreads();
    #pragma unroll
    for (int r = 0; r < 4; ++r) {
        const int drow = bj * 64 + ty + r * 16;
        ushort4 hh, ll;
        split2(t[tx * 4 + 0][ty + r * 16], hh.x, ll.x);
        split2(t[tx * 4 + 1][ty + r * 16], hh.y, ll.y);
        split2(t[tx * 4 + 2][ty + r * 16], hh.z, ll.z);
        split2(t[tx * 4 + 3][ty + r * 16], hh.w, ll.w);
        *(ushort4*)(h + (size_t)drow * Msrc + bi * 64 + tx * 4) = hh;
        *(ushort4*)(l + (size_t)drow * Msrc + bi * 64 + tx * 4) = ll;
    }
}

// ---------------------------------------------------------------------------
// GT[n,r] = Gfull[r,n] transposed+converted, Gfull fused on the fly.
// W1 comes as TWO split-K partials (W1a + W1b) — reduce fused in.
// ---------------------------------------------------------------------------
__global__ __launch_bounds__(256) void gt_build(const float* __restrict__ W1a,
                                                const float* __restrict__ W1b,
                                                const float* __restrict__ right,
                                                const int* __restrict__ inva,
                                                const float* __restrict__ dmrow,
                                                unsigned short* __restrict__ h,
                                                unsigned short* __restrict__ l)
{
    __shared__ float t[64][65];
    const int bi = blockIdx.x, bj = blockIdx.y;
    const int tx = threadIdx.x & 15, ty = threadIdx.x >> 4;
    #pragma unroll
    for (int rr = 0; rr < 4; ++rr) {
        const int r = bi * 64 + ty + rr * 16;
        const int ia = inva[r];
        float4 v;
        if (ia >= 0) {
            const size_t o = (size_t)ia * NDIM + bj * 64 + tx * 4;
            v = *(const float4*)(W1a + o);
            float4 v2 = *(const float4*)(W1b + o);
            v.x += v2.x; v.y += v2.y; v.z += v2.z; v.w += v2.w;
        } else {
            v = *(const float4*)(right + (size_t)r * NDIM + bj * 64 + tx * 4);
            const float s = dmrow[r];
            v.x *= s; v.y *= s; v.z *= s; v.w *= s;
        }
        t[ty + rr * 16][tx * 4 + 0] = v.x; t[ty + rr * 16][tx * 4 + 1] = v.y;
        t[ty + rr * 16][tx * 4 + 2] = v.z; t[ty + rr * 16][tx * 4 + 3] = v.w;
    }
    __syncthreads();
    #pragma unroll
    for (int rr = 0; rr < 4; ++rr) {
        const int drow = bj * 64 + ty + rr * 16;
        ushort4 hh, ll;
        split2(t[tx * 4 + 0][ty + rr * 16], hh.x, ll.x);
        split2(t[tx * 4 + 1][ty + rr * 16], hh.y, ll.y);
        split2(t[tx * 4 + 2][ty + rr * 16], hh.z, ll.z);
        split2(t[tx * 4 + 3][ty + rr * 16], hh.w, ll.w);
        *(ushort4*)(h + (size_t)drow * NDIM + bi * 64 + tx * 4) = hh;
        *(ushort4*)(l + (size_t)drow * NDIM + bi * 64 + tx * 4) = ll;
    }
}

// ---------------------------------------------------------------------------
// Small helpers
// ---------------------------------------------------------------------------
// diag_all[i] = dot(P[i] (+ P2[i]), R[i]) — P2 is the optional split-K
// partial, summed element-wise before the product (== reduce_k then diag).
__global__ __launch_bounds__(256) void diag_kernel(const float* __restrict__ P,
                                                   const float* __restrict__ P2,
                                                   const float* __restrict__ R,
                                                   float* __restrict__ diag_all)
{
    __shared__ float red[256];
    const int i = blockIdx.x;
    const float4* p4 = (const float4*)(P + (size_t)i * NDIM);
    const float4* q4 = P2 ? (const float4*)(P2 + (size_t)i * NDIM) : nullptr;
    const float4* r4 = (const float4*)(R + (size_t)i * NDIM);
    float s = 0.f;
    for (int kq = threadIdx.x; kq < NDIM / 4; kq += 256) {
        float4 a = p4[kq], b = r4[kq];
        if (q4) {
            float4 a2 = q4[kq];
            a.x += a2.x; a.y += a2.y; a.z += a2.z; a.w += a2.w;
        }
        s += a.x * b.x + a.y * b.y + a.z * b.z + a.w * b.w;
    }
    red[threadIdx.x] = s;
    __syncthreads();
    for (int off = 128; off > 0; off >>= 1) {
        if (threadIdx.x < off) red[threadIdx.x] += red[threadIdx.x + off];
        __syncthreads();
    }
    if (threadIdx.x == 0) diag_all[i] = red[0];
}

__global__ void prep2_kernel(const int* __restrict__ act, const int* __restrict__ inact,
                             const float* __restrict__ diag_all,
                             int* __restrict__ inva, float* __restrict__ dm,
                             float* __restrict__ dmrow)
{
    const int t = threadIdx.x;
    inva[t] = -1;
    inva[t + HALF] = -1;
    __syncthreads();
    inva[act[t]] = t;
    const int ir = inact[t];
    const float dv = diag_all[ir];
    dm[t] = dv;
    dmrow[ir] = dv;
}

__global__ __launch_bounds__(256) void build_D(const float* __restrict__ Daa,
                                               const float* __restrict__ diag_all,
                                               const int* __restrict__ inva,
                                               float* __restrict__ D)
{
    const int e = blockIdx.x * 256 + threadIdx.x;
    const int i = e >> 11, j = e & (NDIM - 1);
    const int ii = inva[i], jj = inva[j];
    float v = 0.f;
    if (ii >= 0 && jj >= 0) v = Daa[ii * HALF + jj];
    if (i == j) v = diag_all[i];
    D[e] = v;
}

__global__ __launch_bounds__(256) void mc_kernel(const float* __restrict__ dm,
                                                 float* __restrict__ mc)
{
    const int e = blockIdx.x * 256 + threadIdx.x;
    const int t = e >> 10, s = e & (HALF - 1);
    mc[e] = (t == s) ? dm[t] : 0.f;
}

__global__ __launch_bounds__(512) void gather_rows(const float* __restrict__ R,
                                                   const int* __restrict__ ridx,
                                                   float* __restrict__ outp)
{
    const int r = blockIdx.x;
    const int c = threadIdx.x * 4;
    *(float4*)(outp + (size_t)r * NDIM + c) =
        *(const float4*)(R + (size_t)ridx[r] * NDIM + c);
}

// ---------------------------------------------------------------------------
// fp32 fallback gemms (only if ws_size too small for bf16 scratch)
// ---------------------------------------------------------------------------
__global__ __launch_bounds__(256) void gemm_nt64(const float* __restrict__ A, int lda,
                                                 const int* __restrict__ ridxA,
                                                 const float* __restrict__ B, int ldb,
                                                 const int* __restrict__ ridxB,
                                                 float* __restrict__ C, int ldc, int Kk)
{
    __shared__ float As[16][68];
    __shared__ float Bs[16][68];
    const int tid = threadIdx.x;
    const int tx = tid & 15, ty = tid >> 4;
    const int m0 = blockIdx.x * 64, n0 = blockIdx.y * 64;
    const int li = tid >> 2;
    const int lk = (tid & 3) * 4;
    int rowA = m0 + li; if (ridxA) rowA = ridxA[rowA];
    int rowB = n0 + li; if (ridxB) rowB = ridxB[rowB];
    const float* pA = A + (size_t)rowA * lda + lk;
    const float* pB = B + (size_t)rowB * ldb + lk;
    float acc[4][4] = {};
    for (int k0 = 0; k0 < Kk; k0 += 16) {
        float4 a4 = *(const float4*)(pA + k0);
        float4 b4 = *(const float4*)(pB + k0);
        As[lk + 0][li] = a4.x; As[lk + 1][li] = a4.y; As[lk + 2][li] = a4.z; As[lk + 3][li] = a4.w;
        Bs[lk + 0][li] = b4.x; Bs[lk + 1][li] = b4.y; Bs[lk + 2][li] = b4.z; Bs[lk + 3][li] = b4.w;
        __syncthreads();
        #pragma unroll
        for (int kk = 0; kk < 16; ++kk) {
            float4 av = *(const float4*)&As[kk][ty * 4];
            float4 bv = *(const float4*)&Bs[kk][tx * 4];
            float a[4] = {av.x, av.y, av.z, av.w};
            float b[4] = {bv.x, bv.y, bv.z, bv.w};
            #pragma unroll
            for (int i = 0; i < 4; ++i)
                #pragma unroll
                for (int j = 0; j < 4; ++j) acc[i][j] += a[i] * b[j];
        }
        __syncthreads();
    }
    #pragma unroll
    for (int i = 0; i < 4; ++i) {
        float4 v = make_float4(acc[i][0], acc[i][1], acc[i][2], acc[i][3]);
        *(float4*)(C + (size_t)(m0 + ty * 4 + i) * ldc + n0 + tx * 4) = v;
    }
}

__global__ __launch_bounds__(256) void gemm_nn64(const float* __restrict__ A, int lda,
                                                 const float* __restrict__ B, int ldb,
                                                 float* __restrict__ C, int ldc, int Kk)
{
    __shared__ float As[16][68];
    __shared__ float Bs[16][68];
    const int tid = threadIdx.x;
    const int tx = tid & 15, ty = tid >> 4;
    const int m0 = blockIdx.x * 64, n0 = blockIdx.y * 64;
    const int li = tid >> 2;
    const int lk = (tid & 3) * 4;
    const int bk = tid >> 4;
    const int bn = (tid & 15) * 4;
    const float* pA = A + (size_t)(m0 + li) * lda + lk;
    float acc[4][4] = {};
    for (int k0 = 0; k0 < Kk; k0 += 16) {
        float4 a4 = *(const float4*)(pA + k0);
        float4 b4 = *(const float4*)(B + (size_t)(k0 + bk) * ldb + n0 + bn);
        As[lk + 0][li] = a4.x; As[lk + 1][li] = a4.y; As[lk + 2][li] = a4.z; As[lk + 3][li] = a4.w;
        *(float4*)&Bs[bk][bn] = b4;
        __syncthreads();
        #pragma unroll
        for (int kk = 0; kk < 16; ++kk) {
            float4 av = *(const float4*)&As[kk][ty * 4];
            float4 bv = *(const float4*)&Bs[kk][tx * 4];
            float a[4] = {av.x, av.y, av.z, av.w};
            float b[4] = {bv.x, bv.y, bv.z, bv.w};
            #pragma unroll
            for (int i = 0; i < 4; ++i)
                #pragma unroll
                for (int j = 0; j < 4; ++j) acc[i][j] += a[i] * b[j];
        }
        __syncthreads();
    }
    #pragma unroll
    for (int i = 0; i < 4; ++i) {
        float4 v = make_float4(acc[i][0], acc[i][1], acc[i][2], acc[i][3]);
        *(float4*)(C + (size_t)(m0 + ty * 4 + i) * ldc + n0 + tx * 4) = v;
    }
}

__global__ __launch_bounds__(256) void arec64(const float* __restrict__ fw,
                                              const float* __restrict__ mw,
                                              const float* __restrict__ W1,
                                              const float* __restrict__ dm,
                                              float* __restrict__ C)
{
    __shared__ float As[16][68];
    __shared__ float Bs[16][68];
    const int tid = threadIdx.x;
    const int tx = tid & 15, ty = tid >> 4;
    const int m0 = blockIdx.x * 64, n0 = blockIdx.y * 64;
    const int bk = tid >> 4;
    const int bn = (tid & 15) * 4;
    float acc[4][4] = {};
    for (int t0 = 0; t0 < NDIM; t0 += 16) {
        const int t = t0 + bk;
        const float* Hrow; const float* Grow; float gs;
        if (t < HALF) { Hrow = fw + (size_t)t * NDIM; Grow = W1 + (size_t)t * NDIM; gs = 1.f; }
        else          { Hrow = mw + (size_t)(t - HALF) * NDIM; Grow = Hrow; gs = dm[t - HALF]; }
        float4 a4 = *(const float4*)(Hrow + m0 + bn);
        float4 b4 = *(const float4*)(Grow + n0 + bn);
        b4.x *= gs; b4.y *= gs; b4.z *= gs; b4.w *= gs;
        *(float4*)&As[bk][bn] = a4;
        *(float4*)&Bs[bk][bn] = b4;
        __syncthreads();
        #pragma unroll
        for (int kk = 0; kk < 16; ++kk) {
            float4 av = *(const float4*)&As[kk][ty * 4];
            float4 bv = *(const float4*)&Bs[kk][tx * 4];
            float a[4] = {av.x, av.y, av.z, av.w};
            float b[4] = {bv.x, bv.y, bv.z, bv.w};
            #pragma unroll
            for (int i = 0; i < 4; ++i)
                #pragma unroll
                for (int j = 0; j < 4; ++j) acc[i][j] += a[i] * b[j];
        }
        __syncthreads();
    }
    #pragma unroll
    for (int i = 0; i < 4; ++i) {
        float4 v = make_float4(acc[i][0], acc[i][1], acc[i][2], acc[i][3]);
        *(float4*)(C + (size_t)(m0 + ty * 4 + i) * NDIM + n0 + tx * 4) = v;
    }
}

// ---------------------------------------------------------------------------
extern "C" void kernel_launch(void* const* d_in, const int* in_sizes, int n_in,
                              void* d_out, int out_size, void* d_ws, size_t ws_size,
                              hipStream_t stream)
{
    (void)in_sizes; (void)n_in; (void)out_size;
    const float* A     = (const float*)d_in[0];
    const float* O     = (const float*)d_in[1];
    const int*   idx   = (const int*)d_in[2];
    const int*   act   = (const int*)d_in[3];
    const int*   inact = (const int*)d_in[4];

    float* out = (float*)d_out;
    const size_t NN = (size_t)NDIM * NDIM;
    float* A_rec = out;                       // scratch for P(z0) until final gemm
    float* right = out + NN;
    float* D     = out + 2 * NN;              // scratch: split-K partials / W1
    float* mc    = out + 3 * NN;
    float* fc    = mc + (size_t)HALF * HALF;  // Daa
    float* mw    = fc + (size_t)HALF * HALF;
    float* fw    = mw + (size_t)HALF * NDIM;

    char*  w        = (char*)d_ws;
    float* diag_all = (float*)w;              // 2048 f
    float* dm       = (float*)(w + 8192);     // 1024 f
    int*   inva     = (int*)(w + 12288);      // 2048 i
    float* dmrow    = (float*)(w + 20480);    // 2048 f

    const size_t MB = 1024 * 1024;
    const size_t WS_NEEDED = 65536 + 32 * MB;

    if (ws_size >= WS_NEEDED) {
        char* r1 = w + 65536;                 // 16 MB: (Warr/Sarr) -> Rh/Rl -> RTh/RTl
        char* r2 = r1 + 16 * MB;              // 16 MB: Ah/Al -> Pa/F -> D/FT -> GT
        float* Warr = (float*)r1;             // 1 MB (consumed by scan3)
        int*   Sarr = (int*)(r1 + MB);        // 32 KB
        unsigned short* Rh  = (unsigned short*)r1;
        unsigned short* Rl  = (unsigned short*)(r1 + 8 * MB);
        unsigned short* RTh = Rh;
        unsigned short* RTl = Rl;
        unsigned short* Ah  = (unsigned short*)r2;
        unsigned short* Al  = (unsigned short*)(r2 + 8 * MB);
        unsigned short* Pah = (unsigned short*)r2;             // after P
        unsigned short* Pal = (unsigned short*)(r2 + 4 * MB);
        unsigned short* Fh  = (unsigned short*)(r2 + 8 * MB);
        unsigned short* Fl  = (unsigned short*)(r2 + 12 * MB);
        unsigned short* Dh  = (unsigned short*)r2;             // after Daa
        unsigned short* Dl  = (unsigned short*)(r2 + 2 * MB);
        unsigned short* FTh = (unsigned short*)(r2 + 4 * MB);
        unsigned short* FTl = (unsigned short*)(r2 + 8 * MB);
        unsigned short* GTh = (unsigned short*)r2;             // after W1
        unsigned short* GTl = (unsigned short*)(r2 + 8 * MB);

        // 1. pairwise level composition, then 256-level k-split scan
        compose_kernel<<<256, 64, 0, stream>>>(O, idx, Sarr, Warr);
        scan3_kernel<<<512, 64, 0, stream>>>(Warr, Sarr, right);
        // 2. mother wavelets (fw gather fused into step 7's gather_conv)
        gather_rows<<<1024, 512, 0, stream>>>(right, inact, mw);
        // 3. convert R and A to bf16 hi/lo (overwrites Warr/Sarr — consumed)
        conv_hl<<<4096, 256, 0, stream>>>(right, nullptr, nullptr, 11, Rh, Rl);
        conv_hl<<<4096, 256, 0, stream>>>(A, nullptr, nullptr, 11, Ah, Al);
        // 4. P = R @ A, split-K=2: z0 -> A_rec, z1 -> D slot (NOT reduced —
        //    consumers sum the partials inline)
        mfma_nt<<<dim3(16, 16, 2), 256, 0, stream>>>(Rh, Rl, Ah, Al, A_rec,
                                                     (long)2 * NN, NDIM, NDIM, NDIM, 2);
        // 5. diag (reads z0+z1) + prep
        diag_kernel<<<2048, 256, 0, stream>>>(A_rec, A_rec + 2 * NN, right, diag_all);
        prep2_kernel<<<1, 1024, 0, stream>>>(act, inact, diag_all, inva, dm, dmrow);
        // 7. Pa = (z0+z1)[act] in bf16; fw = right[act] + F in bf16 (fused)
        conv_hl<<<2048, 256, 0, stream>>>(A_rec, A_rec + 2 * NN, act, 11, Pah, Pal);
        gather_conv<<<1024, 512, 0, stream>>>(right, act, fw, Fh, Fl);
        // 8. Daa = Pa . F^T, split-K=4: partials in D slot (4 x 4 MB); reduce -> fc
        //    (fc is an output region — must materialize)
        mfma_nt<<<dim3(8, 8, 4), 256, 0, stream>>>(Pah, Pal, Fh, Fl, D,
                                                   (long)HALF * HALF, HALF, HALF, NDIM, 4);
        reduce_k<<<1024, 256, 0, stream>>>(fc, D, (long)HALF * HALF, 4, (long)HALF * HALF);
        // 9. Dh/Dl = conv(Daa); FT = fw^T
        conv_hl<<<1024, 256, 0, stream>>>(fc, nullptr, nullptr, 10, Dh, Dl);
        tconv_hl<<<dim3(16, 32), 256, 0, stream>>>(fw, HALF, NDIM, FTh, FTl);
        // 10. W1 = Daa @ fw, split-K=2: z0 -> D, z1 -> D+HALF*NDIM (NOT reduced —
        //     gt_build sums inline)
        mfma_nt<<<dim3(8, 16, 2), 256, 0, stream>>>(Dh, Dl, FTh, FTl, D,
                                                    (long)HALF * NDIM, HALF, NDIM, HALF, 2);
        // 11. RT = right^T
        tconv_hl<<<dim3(32, 32), 256, 0, stream>>>(right, NDIM, NDIM, RTh, RTl);
        // 12. GT from (W1z0+W1z1) / dm*right (consumes W1 partials in D slot)
        gt_build<<<dim3(32, 32), 256, 0, stream>>>(D, D + (size_t)HALF * NDIM,
                                                   right, inva, dmrow, GTh, GTl);
        // 13. A_rec = RT . GT^T, split-K=2: z0 -> A_rec, z1 -> D slot; reduce
        //     (A_rec is the output — must materialize)
        mfma_nt<<<dim3(16, 16, 2), 256, 0, stream>>>(RTh, RTl, GTh, GTl, A_rec,
                                                     (long)2 * NN, NDIM, NDIM, NDIM, 2);
        reduce_k<<<4096, 256, 0, stream>>>(A_rec, A_rec, (long)2 * NN, 2, (long)NN);
        // 14. D output (overwrites partial scratch)
        build_D<<<16384, 256, 0, stream>>>(fc, diag_all, inva, D);
        // 15. mother_coefficients = diag(dm)
        mc_kernel<<<4096, 256, 0, stream>>>(dm, mc);
    } else {
        // fp32 fallback (R1 structure)
        scan_kernel<<<256, 64, 0, stream>>>(O, idx, right);
        gather_rows<<<1024, 512, 0, stream>>>(right, act, fw);
        gather_rows<<<1024, 512, 0, stream>>>(right, inact, mw);
        gemm_nt64<<<dim3(32, 32), 256, 0, stream>>>(right, NDIM, nullptr, A, NDIM, nullptr,
                                                    A_rec, NDIM, NDIM);
        diag_kernel<<<2048, 256, 0, stream>>>(A_rec, nullptr, right, diag_all);
        prep2_kernel<<<1, 1024, 0, stream>>>(act, inact, diag_all, inva, dm, dmrow);
        gemm_nt64<<<dim3(16, 16), 256, 0, stream>>>(A_rec, NDIM, act, right, NDIM, act,
                                                    fc, HALF, NDIM);
        gemm_nn64<<<dim3(16, 32), 256, 0, stream>>>(fc, HALF, fw, NDIM, D, NDIM, HALF);
        arec64<<<dim3(32, 32), 256, 0, stream>>>(fw, mw, D, dm, A_rec);
        build_D<<<16384, 256, 0, stream>>>(fc, diag_all, inva, D);
        mc_kernel<<<4096, 256, 0, stream>>>(dm, mc);
    }
}

// Round 6
// 540.196 us; speedup vs baseline: 1.2946x; 1.0349x over previous
//
#include <hip/hip_runtime.h>

// Problem constants (N=2048, L=512, K=16, DROP=2, DIM=1024)
#define NDIM 2048
#define LLEV 512
#define KDIM 16
#define HALF 1024

typedef __attribute__((ext_vector_type(8))) short bf16x8;   // 8 bf16 = 4 VGPRs
typedef __attribute__((ext_vector_type(4))) float f32x4;

// ---------------------------------------------------------------------------
// bf16 split helpers: x ~= hi + lo, each RNE bf16 (~16-17 mantissa bits total)
// ---------------------------------------------------------------------------
__device__ inline unsigned short f2bf(float x) {
    unsigned u = __float_as_uint(x);
    u += 0x7fffu + ((u >> 16) & 1u);
    return (unsigned short)(u >> 16);
}
__device__ inline float bf2f(unsigned short b) {
    return __uint_as_float(((unsigned)b) << 16);
}
__device__ inline void split2(float x, unsigned short& h, unsigned short& l) {
    h = f2bf(x);
    l = f2bf(x - bf2f(h));
}

__device__ inline void gl2lds16(const void* g, void* l) {
    __builtin_amdgcn_global_load_lds(
        (const __attribute__((address_space(1))) void*)g,
        (__attribute__((address_space(3))) void*)l, 16, 0, 0);
}

// ---------------------------------------------------------------------------
// compose_kernel: pairwise level composition (validated R4/R5).
// 512 levels of 16 rows -> 256 composites of 32 rows.
// ---------------------------------------------------------------------------
__global__ __launch_bounds__(64) void compose_kernel(const float* __restrict__ O,
                                                     const int* __restrict__ idx,
                                                     int* __restrict__ Sarr,
                                                     float* __restrict__ Warr)
{
    __shared__ int s_S[32];
    __shared__ int s_pos[32];
    __shared__ float s_W[32][33];
    const int t = blockIdx.x;
    const int lane = threadIdx.x;
    const int* a = idx + (2 * t) * 16;
    const int* b = idx + (2 * t + 1) * 16;

    if (lane == 0) {
        int na = 0, i = 0, j = 0;
        while (i < 16 || j < 16) {
            int va = (i < 16) ? a[i] : 0x7fffffff;
            int vb = (j < 16) ? b[j] : 0x7fffffff;
            int v = va < vb ? va : vb;
            if (va == v) i++;
            if (vb == v) j++;
            s_S[na++] = v;
        }
        const int nm = na;
        int r = 0, p = 0;
        while (na < 32) {
            while (p < nm && s_S[p] < r) p++;
            if (p < nm && s_S[p] == r) { r++; continue; }
            s_S[na++] = r++;
        }
    }
    __syncthreads();
    if (lane < 32) {
        const int v = (lane < 16) ? a[lane] : b[lane - 16];
        int pp = 0;
        #pragma unroll
        for (int q = 0; q < 32; ++q) if (s_S[q] == v) pp = q;
        s_pos[lane] = pp;
        #pragma unroll
        for (int c = 0; c < 33; ++c) s_W[lane][c] = 0.f;
        s_W[lane][lane] = 1.f;
    }
    __syncthreads();
    const int j  = lane >> 2;
    const int cg = (lane & 3) * 8;
    #pragma unroll
    for (int step = 0; step < 2; ++step) {
        const float* Om = O + (size_t)(2 * t + step) * 256;
        float acc[8] = {};
        for (int k = 0; k < 16; ++k) {
            const float o = Om[j * 16 + k];
            const int p = s_pos[step * 16 + k];
            #pragma unroll
            for (int c = 0; c < 8; ++c) acc[c] += o * s_W[p][cg + c];
        }
        __syncthreads();
        const int pj = s_pos[step * 16 + j];
        #pragma unroll
        for (int c = 0; c < 8; ++c) s_W[pj][cg + c] = acc[c];
        __syncthreads();
    }
    if (lane < 32) Sarr[t * 32 + lane] = s_S[lane];
    {
        const int r = lane >> 1, h0 = (lane & 1) * 16;
        float* wp = Warr + (size_t)t * 1024 + r * 32 + h0;
        #pragma unroll
        for (int c = 0; c < 16; ++c) wp[c] = s_W[r][h0 + c];
    }
}

// ---------------------------------------------------------------------------
// scan3_fused: blocks 0..511 run the proven scan3 (123us, latency-bound,
// 5.5% occupancy); blocks 512+ run conv_hl(A) work in the scan's shadow
// (independent of scan output — only needs input A). 8192 conv blocks x
// 64 threads x 8 floats = 2048^2.
// ---------------------------------------------------------------------------
__global__ __launch_bounds__(64) void scan3_fused(const float* __restrict__ Warr,
                                                  const int* __restrict__ Sarr,
                                                  float* __restrict__ right,
                                                  const float* __restrict__ Asrc,
                                                  unsigned short* __restrict__ Ahd,
                                                  unsigned short* __restrict__ Ald)
{
    __shared__ float slab[NDIM * 4];
    const int lane = threadIdx.x;

    if (blockIdx.x >= 512) {
        const long e = ((long)(blockIdx.x - 512) * 64 + lane) * 8;
        float4 v0 = *(const float4*)(Asrc + e);
        float4 v1 = *(const float4*)(Asrc + e + 4);
        ushort4 h0, l0, h1, l1;
        split2(v0.x, h0.x, l0.x); split2(v0.y, h0.y, l0.y);
        split2(v0.z, h0.z, l0.z); split2(v0.w, h0.w, l0.w);
        split2(v1.x, h1.x, l1.x); split2(v1.y, h1.y, l1.y);
        split2(v1.z, h1.z, l1.z); split2(v1.w, h1.w, l1.w);
        *(ushort4*)(Ahd + e)     = h0;
        *(ushort4*)(Ahd + e + 4) = h1;
        *(ushort4*)(Ald + e)     = l0;
        *(ushort4*)(Ald + e + 4) = l1;
        return;
    }

    const int c0 = blockIdx.x * 4;
    const int rr = lane & 31;
    const int ks = lane >> 5;

    for (int r = lane; r < NDIM; r += 64)
        *(float4*)&slab[r * 4] = make_float4(0.f, 0.f, 0.f, 0.f);
    if (lane < 4) slab[(c0 + lane) * 4 + lane] = 1.0f;

    int rows[16]; float cf[16]; int wrow;
    {
        const int4* sp = (const int4*)(Sarr + ks * 16);
        #pragma unroll
        for (int q = 0; q < 4; ++q) *(int4*)&rows[q * 4] = sp[q];
        const float4* wp = (const float4*)(Warr + rr * 32 + ks * 16);
        #pragma unroll
        for (int q = 0; q < 4; ++q) *(float4*)&cf[q * 4] = wp[q];
        wrow = Sarr[rr];
    }

    for (int t = 0; t < 256; ++t) {
        int cr[16]; float cc[16];
        const int wr = wrow;
        #pragma unroll
        for (int q = 0; q < 16; ++q) { cr[q] = rows[q]; cc[q] = cf[q]; }
        if (t + 1 < 256) {
            const int4* sp = (const int4*)(Sarr + (t + 1) * 32 + ks * 16);
            #pragma unroll
            for (int q = 0; q < 4; ++q) *(int4*)&rows[q * 4] = sp[q];
            const float4* wp = (const float4*)(Warr + (size_t)(t + 1) * 1024 + rr * 32 + ks * 16);
            #pragma unroll
            for (int q = 0; q < 4; ++q) *(float4*)&cf[q * 4] = wp[q];
            wrow = Sarr[(t + 1) * 32 + rr];
        }
        float4 acc = make_float4(0.f, 0.f, 0.f, 0.f);
        #pragma unroll
        for (int j = 0; j < 16; ++j) {
            float4 v = *(const float4*)&slab[cr[j] * 4];
            acc.x += cc[j] * v.x; acc.y += cc[j] * v.y;
            acc.z += cc[j] * v.z; acc.w += cc[j] * v.w;
        }
        acc.x += __shfl_xor(acc.x, 32, 64);
        acc.y += __shfl_xor(acc.y, 32, 64);
        acc.z += __shfl_xor(acc.z, 32, 64);
        acc.w += __shfl_xor(acc.w, 32, 64);
        if (lane < 32)
            *(float4*)&slab[wr * 4] = acc;
    }

    #pragma unroll 4
    for (int i = 0; i < 32; ++i) {
        const int r = i * 64 + lane;
        *(float4*)(right + (size_t)r * NDIM + c0) = *(float4*)&slab[r * 4];
    }
}

// ---------------------------------------------------------------------------
// Old scan (fp32 fallback path only)
// ---------------------------------------------------------------------------
__global__ __launch_bounds__(64) void scan_kernel(const float* __restrict__ O,
                                                  const int* __restrict__ idx,
                                                  float* __restrict__ right)
{
    __shared__ float slab[NDIM * 8];
    const int lane = threadIdx.x;
    const int c0 = blockIdx.x * 8;
    const int k  = lane >> 2;
    const int c2 = (lane & 3) * 2;

    for (int r = lane; r < NDIM; r += 64) {
        *(float4*)&slab[r * 8]     = make_float4(0.f, 0.f, 0.f, 0.f);
        *(float4*)&slab[r * 8 + 4] = make_float4(0.f, 0.f, 0.f, 0.f);
    }
    if (lane < 8) slab[(c0 + lane) * 8 + lane] = 1.0f;

    int rows[16]; float a[16]; int wrow;
    #pragma unroll
    for (int j = 0; j < 16; ++j) rows[j] = idx[j];
    {
        const float4* p4 = (const float4*)(O + k * 16);
        #pragma unroll
        for (int q = 0; q < 4; ++q) *(float4*)&a[q * 4] = p4[q];
    }
    wrow = idx[k];

    for (int l = 0; l < LLEV; ++l) {
        int rr[16]; float aa[16];
        const int wr = wrow;
        #pragma unroll
        for (int j = 0; j < 16; ++j) { rr[j] = rows[j]; aa[j] = a[j]; }
        if (l + 1 < LLEV) {
            const int* ip = idx + (l + 1) * 16;
            #pragma unroll
            for (int j = 0; j < 16; ++j) rows[j] = ip[j];
            const float4* p4 = (const float4*)(O + (l + 1) * 256 + k * 16);
            #pragma unroll
            for (int q = 0; q < 4; ++q) *(float4*)&a[q * 4] = p4[q];
            wrow = ip[k];
        }
        float sx = 0.f, sy = 0.f;
        #pragma unroll
        for (int j = 0; j < 16; ++j) {
            float2 v = *(float2*)&slab[rr[j] * 8 + c2];
            sx += aa[j] * v.x;
            sy += aa[j] * v.y;
        }
        *(float2*)&slab[wr * 8 + c2] = make_float2(sx, sy);
    }

    for (int r0 = 0; r0 < NDIM; r0 += 32) {
        const int r = r0 + (lane >> 1);
        const int h = (lane & 1) * 4;
        *(float4*)(right + (size_t)r * NDIM + c0 + h) = *(float4*)&slab[r * 8 + h];
    }
}

// ---------------------------------------------------------------------------
// Split-bf16 MFMA NT gemm with SPLIT-K: blockIdx.z owns K-slice.
// 3-pass hi/lo, 128x128 tile.
// R5/R6: BK 64->32. Halves LDS 64KB->32KB so occupancy rises 2->3 blocks/CU
// (m132's measured occupancy cliff, inverted): the N=2048-shaped grids were
// barrier-drain-bound at 2 blocks/CU. Accumulation order over k-chunks and
// hh/hl/lh passes is UNCHANGED -> bit-identical results.
// ---------------------------------------------------------------------------
#define GBK 32
__global__ __launch_bounds__(256) void mfma_nt(const unsigned short* __restrict__ Ah,
                                               const unsigned short* __restrict__ Al,
                                               const unsigned short* __restrict__ Bh,
                                               const unsigned short* __restrict__ Bl,
                                               float* __restrict__ C,
                                               long strideZ,
                                               int M, int N, int K, int ksplit)
{
    __shared__ unsigned short sA_h[4 * 128 * 8];   // 8 KB each, 32 KB total
    __shared__ unsigned short sA_l[4 * 128 * 8];
    __shared__ unsigned short sB_h[4 * 128 * 8];
    __shared__ unsigned short sB_l[4 * 128 * 8];

    const int tid  = threadIdx.x;
    const int wave = tid >> 6, lane = tid & 63;
    const int lm   = lane & 15, quad = lane >> 4;
    const int wm   = wave & 1,  wn   = wave >> 1;
    const int m0   = blockIdx.x * 128, n0 = blockIdx.y * 128;
    const int Kz   = K / ksplit;
    const int kbeg = Kz * blockIdx.z;
    C += (size_t)blockIdx.z * strideZ;

    const unsigned short* gbase;
    unsigned short* sbase;
    if      (wave == 0) { gbase = Ah + (size_t)m0 * K; sbase = sA_h; }
    else if (wave == 1) { gbase = Al + (size_t)m0 * K; sbase = sA_l; }
    else if (wave == 2) { gbase = Bh + (size_t)n0 * K; sbase = sB_h; }
    else                { gbase = Bl + (size_t)n0 * K; sbase = sB_l; }

    f32x4 acc[4][4];
    #pragma unroll
    for (int i = 0; i < 4; ++i)
        #pragma unroll
        for (int j = 0; j < 4; ++j) acc[i][j] = (f32x4){0.f, 0.f, 0.f, 0.f};

    for (int k0 = kbeg; k0 < kbeg + Kz; k0 += GBK) {
        #pragma unroll
        for (int h = 0; h < 2; ++h) {
            const unsigned short* gr = gbase + (size_t)(h * 64 + lane) * K + k0;
            unsigned short* sb = sbase + h * 512;
            #pragma unroll
            for (int c = 0; c < 4; ++c)
                gl2lds16(gr + c * 8, sb + c * 1024);
        }
        __syncthreads();
        {
            const int co = quad * 1024;
            bf16x8 ah[4], al[4], bh[4], bl[4];
            #pragma unroll
            for (int i = 0; i < 4; ++i) {
                const int m = wm * 64 + i * 16 + lm;
                ah[i] = *(const bf16x8*)&sA_h[co + m * 8];
                al[i] = *(const bf16x8*)&sA_l[co + m * 8];
            }
            #pragma unroll
            for (int j = 0; j < 4; ++j) {
                const int n = wn * 64 + j * 16 + lm;
                bh[j] = *(const bf16x8*)&sB_h[co + n * 8];
                bl[j] = *(const bf16x8*)&sB_l[co + n * 8];
            }
            #pragma unroll
            for (int i = 0; i < 4; ++i)
                #pragma unroll
                for (int j = 0; j < 4; ++j) {
                    acc[i][j] = __builtin_amdgcn_mfma_f32_16x16x32_bf16(ah[i], bh[j], acc[i][j], 0, 0, 0);
                    acc[i][j] = __builtin_amdgcn_mfma_f32_16x16x32_bf16(ah[i], bl[j], acc[i][j], 0, 0, 0);
                    acc[i][j] = __builtin_amdgcn_mfma_f32_16x16x32_bf16(al[i], bh[j], acc[i][j], 0, 0, 0);
                }
        }
        __syncthreads();
    }
    #pragma unroll
    for (int i = 0; i < 4; ++i) {
        const int mrow = m0 + wm * 64 + i * 16 + quad * 4;
        #pragma unroll
        for (int j = 0; j < 4; ++j) {
            float* cp = C + (size_t)mrow * N + n0 + wn * 64 + j * 16 + lm;
            #pragma unroll
            for (int r = 0; r < 4; ++r) cp[(size_t)r * N] = acc[i][j][r];
        }
    }
}

// ---------------------------------------------------------------------------
// reduce_k: dst[i] = sum_z parts[i + z*strideZ], float4 per thread.
// (dst may alias parts' z=0 slice — each thread owns its own i.)
// ---------------------------------------------------------------------------
__global__ __launch_bounds__(256) void reduce_k(float* __restrict__ dst,
                                                const float* __restrict__ parts,
                                                long strideZ, int nz, long n)
{
    const long i = ((long)blockIdx.x * 256 + threadIdx.x) * 4;
    if (i >= n) return;
    float4 s = *(const float4*)(parts + i);
    for (int z = 1; z < nz; ++z) {
        float4 v = *(const float4*)(parts + (size_t)z * strideZ + i);
        s.x += v.x; s.y += v.y; s.z += v.z; s.w += v.w;
    }
    *(float4*)(dst + i) = s;
}

// ---------------------------------------------------------------------------
// fp32 -> bf16 hi/lo conversion (optional row gather; optional second source
// summed in — fuses a split-K reduce into the conversion, bit-identical to
// reduce_k-then-conv). 4 floats/thread.
// ---------------------------------------------------------------------------
__global__ __launch_bounds__(256) void conv_hl(const float* __restrict__ src,
                                               const float* __restrict__ src2,
                                               const int* __restrict__ gidx,
                                               int kshift,
                                               unsigned short* __restrict__ h,
                                               unsigned short* __restrict__ l)
{
    const long e = ((long)blockIdx.x * 256 + threadIdx.x) * 4;
    long off;
    if (gidx) {
        const long row = e >> kshift;
        const long col = e - (row << kshift);
        off = ((size_t)gidx[row] << kshift) + col;
    } else {
        off = e;
    }
    float4 v = *(const float4*)(src + off);
    if (src2) {
        float4 v2 = *(const float4*)(src2 + off);
        v.x += v2.x; v.y += v2.y; v.z += v2.z; v.w += v2.w;
    }
    ushort4 hh, ll;
    split2(v.x, hh.x, ll.x); split2(v.y, hh.y, ll.y);
    split2(v.z, hh.z, ll.z); split2(v.w, hh.w, ll.w);
    *(ushort4*)(h + e) = hh;
    *(ushort4*)(l + e) = ll;
}

// ---------------------------------------------------------------------------
// gather_conv: fw[r] = right[act[r]]; also emits bf16 hi/lo of the row.
// Fuses gather_rows(fw) + conv_hl(fw) into one pass.
// ---------------------------------------------------------------------------
__global__ __launch_bounds__(512) void gather_conv(const float* __restrict__ R,
                                                   const int* __restrict__ ridx,
                                                   float* __restrict__ outp,
                                                   unsigned short* __restrict__ h,
                                                   unsigned short* __restrict__ l)
{
    const int r = blockIdx.x;
    const int c = threadIdx.x * 4;
    const size_t e = (size_t)r * NDIM + c;
    float4 v = *(const float4*)(R + (size_t)ridx[r] * NDIM + c);
    *(float4*)(outp + e) = v;
    ushort4 hh, ll;
    split2(v.x, hh.x, ll.x); split2(v.y, hh.y, ll.y);
    split2(v.z, hh.z, ll.z); split2(v.w, hh.w, ll.w);
    *(ushort4*)(h + e) = hh;
    *(ushort4*)(l + e) = ll;
}

// ---------------------------------------------------------------------------
// Transposing fp32 -> bf16 hi/lo: dst[k][m] = src[m][k]. 64x64 LDS tile.
// ---------------------------------------------------------------------------
__global__ __launch_bounds__(256) void tconv_hl(const float* __restrict__ src,
                                                int Msrc, int Ksrc,
                                                unsigned short* __restrict__ h,
                                                unsigned short* __restrict__ l)
{
    __shared__ float t[64][65];
    const int bi = blockIdx.x, bj = blockIdx.y;
    const int tx = threadIdx.x & 15, ty = threadIdx.x >> 4;
    #pragma unroll
    for (int r = 0; r < 4; ++r) {
        const int row = bi * 64 + ty + r * 16;
        float4 v = *(const float4*)(src + (size_t)row * Ksrc + bj * 64 + tx * 4);
        t[ty + r * 16][tx * 4 + 0] = v.x; t[ty + r * 16][tx * 4 + 1] = v.y;
        t[ty + r * 16][tx * 4 + 2] = v.z; t[ty + r * 16][tx * 4 + 3] = v.w;
    }
    __syncthreads();
    #pragma unroll
    for (int r = 0; r < 4; ++r) {
        const int drow = bj * 64 + ty + r * 16;
        ushort4 hh, ll;
        split2(t[tx * 4 + 0][ty + r * 16], hh.x, ll.x);
        split2(t[tx * 4 + 1][ty + r * 16], hh.y, ll.y);
        split2(t[tx * 4 + 2][ty + r * 16], hh.z, ll.z);
        split2(t[tx * 4 + 3][ty + r * 16], hh.w, ll.w);
        *(ushort4*)(h + (size_t)drow * Msrc + bi * 64 + tx * 4) = hh;
        *(ushort4*)(l + (size_t)drow * Msrc + bi * 64 + tx * 4) = ll;
    }
}

// ---------------------------------------------------------------------------
// GT[n,r] = Gfull[r,n] transposed+converted, Gfull fused on the fly.
// W1 comes as TWO split-K partials (W1a + W1b) — reduce fused in.
// ---------------------------------------------------------------------------
__global__ __launch_bounds__(256) void gt_build(const float* __restrict__ W1a,
                                                const float* __restrict__ W1b,
                                                const float* __restrict__ right,
                                                const int* __restrict__ inva,
                                                const float* __restrict__ dmrow,
                                                unsigned short* __restrict__ h,
                                                unsigned short* __restrict__ l)
{
    __shared__ float t[64][65];
    const int bi = blockIdx.x, bj = blockIdx.y;
    const int tx = threadIdx.x & 15, ty = threadIdx.x >> 4;
    #pragma unroll
    for (int rr = 0; rr < 4; ++rr) {
        const int r = bi * 64 + ty + rr * 16;
        const int ia = inva[r];
        float4 v;
        if (ia >= 0) {
            const size_t o = (size_t)ia * NDIM + bj * 64 + tx * 4;
            v = *(const float4*)(W1a + o);
            float4 v2 = *(const float4*)(W1b + o);
            v.x += v2.x; v.y += v2.y; v.z += v2.z; v.w += v2.w;
        } else {
            v = *(const float4*)(right + (size_t)r * NDIM + bj * 64 + tx * 4);
            const float s = dmrow[r];
            v.x *= s; v.y *= s; v.z *= s; v.w *= s;
        }
        t[ty + rr * 16][tx * 4 + 0] = v.x; t[ty + rr * 16][tx * 4 + 1] = v.y;
        t[ty + rr * 16][tx * 4 + 2] = v.z; t[ty + rr * 16][tx * 4 + 3] = v.w;
    }
    __syncthreads();
    #pragma unroll
    for (int rr = 0; rr < 4; ++rr) {
        const int drow = bj * 64 + ty + rr * 16;
        ushort4 hh, ll;
        split2(t[tx * 4 + 0][ty + rr * 16], hh.x, ll.x);
        split2(t[tx * 4 + 1][ty + rr * 16], hh.y, ll.y);
        split2(t[tx * 4 + 2][ty + rr * 16], hh.z, ll.z);
        split2(t[tx * 4 + 3][ty + rr * 16], hh.w, ll.w);
        *(ushort4*)(h + (size_t)drow * NDIM + bi * 64 + tx * 4) = hh;
        *(ushort4*)(l + (size_t)drow * NDIM + bi * 64 + tx * 4) = ll;
    }
}

// ---------------------------------------------------------------------------
// Small helpers
// ---------------------------------------------------------------------------
// diag_all[i] = dot(P[i] (+ P2[i]), R[i]) — P2 is the optional split-K
// partial, summed element-wise before the product (== reduce_k then diag).
__global__ __launch_bounds__(256) void diag_kernel(const float* __restrict__ P,
                                                   const float* __restrict__ P2,
                                                   const float* __restrict__ R,
                                                   float* __restrict__ diag_all)
{
    __shared__ float red[256];
    const int i = blockIdx.x;
    const float4* p4 = (const float4*)(P + (size_t)i * NDIM);
    const float4* q4 = P2 ? (const float4*)(P2 + (size_t)i * NDIM) : nullptr;
    const float4* r4 = (const float4*)(R + (size_t)i * NDIM);
    float s = 0.f;
    for (int kq = threadIdx.x; kq < NDIM / 4; kq += 256) {
        float4 a = p4[kq], b = r4[kq];
        if (q4) {
            float4 a2 = q4[kq];
            a.x += a2.x; a.y += a2.y; a.z += a2.z; a.w += a2.w;
        }
        s += a.x * b.x + a.y * b.y + a.z * b.z + a.w * b.w;
    }
    red[threadIdx.x] = s;
    __syncthreads();
    for (int off = 128; off > 0; off >>= 1) {
        if (threadIdx.x < off) red[threadIdx.x] += red[threadIdx.x + off];
        __syncthreads();
    }
    if (threadIdx.x == 0) diag_all[i] = red[0];
}

__global__ void prep2_kernel(const int* __restrict__ act, const int* __restrict__ inact,
                             const float* __restrict__ diag_all,
                             int* __restrict__ inva, float* __restrict__ dm,
                             float* __restrict__ dmrow)
{
    const int t = threadIdx.x;
    inva[t] = -1;
    inva[t + HALF] = -1;
    __syncthreads();
    inva[act[t]] = t;
    const int ir = inact[t];
    const float dv = diag_all[ir];
    dm[t] = dv;
    dmrow[ir] = dv;
}

__global__ __launch_bounds__(256) void build_D(const float* __restrict__ Daa,
                                               const float* __restrict__ diag_all,
                                               const int* __restrict__ inva,
                                               float* __restrict__ D)
{
    const int e = blockIdx.x * 256 + threadIdx.x;
    const int i = e >> 11, j = e & (NDIM - 1);
    const int ii = inva[i], jj = inva[j];
    float v = 0.f;
    if (ii >= 0 && jj >= 0) v = Daa[ii * HALF + jj];
    if (i == j) v = diag_all[i];
    D[e] = v;
}

__global__ __launch_bounds__(256) void mc_kernel(const float* __restrict__ dm,
                                                 float* __restrict__ mc)
{
    const int e = blockIdx.x * 256 + threadIdx.x;
    const int t = e >> 10, s = e & (HALF - 1);
    mc[e] = (t == s) ? dm[t] : 0.f;
}

__global__ __launch_bounds__(512) void gather_rows(const float* __restrict__ R,
                                                   const int* __restrict__ ridx,
                                                   float* __restrict__ outp)
{
    const int r = blockIdx.x;
    const int c = threadIdx.x * 4;
    *(float4*)(outp + (size_t)r * NDIM + c) =
        *(const float4*)(R + (size_t)ridx[r] * NDIM + c);
}

// ---------------------------------------------------------------------------
// fp32 fallback gemms (only if ws_size too small for bf16 scratch)
// ---------------------------------------------------------------------------
__global__ __launch_bounds__(256) void gemm_nt64(const float* __restrict__ A, int lda,
                                                 const int* __restrict__ ridxA,
                                                 const float* __restrict__ B, int ldb,
                                                 const int* __restrict__ ridxB,
                                                 float* __restrict__ C, int ldc, int Kk)
{
    __shared__ float As[16][68];
    __shared__ float Bs[16][68];
    const int tid = threadIdx.x;
    const int tx = tid & 15, ty = tid >> 4;
    const int m0 = blockIdx.x * 64, n0 = blockIdx.y * 64;
    const int li = tid >> 2;
    const int lk = (tid & 3) * 4;
    int rowA = m0 + li; if (ridxA) rowA = ridxA[rowA];
    int rowB = n0 + li; if (ridxB) rowB = ridxB[rowB];
    const float* pA = A + (size_t)rowA * lda + lk;
    const float* pB = B + (size_t)rowB * ldb + lk;
    float acc[4][4] = {};
    for (int k0 = 0; k0 < Kk; k0 += 16) {
        float4 a4 = *(const float4*)(pA + k0);
        float4 b4 = *(const float4*)(pB + k0);
        As[lk + 0][li] = a4.x; As[lk + 1][li] = a4.y; As[lk + 2][li] = a4.z; As[lk + 3][li] = a4.w;
        Bs[lk + 0][li] = b4.x; Bs[lk + 1][li] = b4.y; Bs[lk + 2][li] = b4.z; Bs[lk + 3][li] = b4.w;
        __syncthreads();
        #pragma unroll
        for (int kk = 0; kk < 16; ++kk) {
            float4 av = *(const float4*)&As[kk][ty * 4];
            float4 bv = *(const float4*)&Bs[kk][tx * 4];
            float a[4] = {av.x, av.y, av.z, av.w};
            float b[4] = {bv.x, bv.y, bv.z, bv.w};
            #pragma unroll
            for (int i = 0; i < 4; ++i)
                #pragma unroll
                for (int j = 0; j < 4; ++j) acc[i][j] += a[i] * b[j];
        }
        __syncthreads();
    }
    #pragma unroll
    for (int i = 0; i < 4; ++i) {
        float4 v = make_float4(acc[i][0], acc[i][1], acc[i][2], acc[i][3]);
        *(float4*)(C + (size_t)(m0 + ty * 4 + i) * ldc + n0 + tx * 4) = v;
    }
}

__global__ __launch_bounds__(256) void gemm_nn64(const float* __restrict__ A, int lda,
                                                 const float* __restrict__ B, int ldb,
                                                 float* __restrict__ C, int ldc, int Kk)
{
    __shared__ float As[16][68];
    __shared__ float Bs[16][68];
    const int tid = threadIdx.x;
    const int tx = tid & 15, ty = tid >> 4;
    const int m0 = blockIdx.x * 64, n0 = blockIdx.y * 64;
    const int li = tid >> 2;
    const int lk = (tid & 3) * 4;
    const int bk = tid >> 4;
    const int bn = (tid & 15) * 4;
    const float* pA = A + (size_t)(m0 + li) * lda + lk;
    float acc[4][4] = {};
    for (int k0 = 0; k0 < Kk; k0 += 16) {
        float4 a4 = *(const float4*)(pA + k0);
        float4 b4 = *(const float4*)(B + (size_t)(k0 + bk) * ldb + n0 + bn);
        As[lk + 0][li] = a4.x; As[lk + 1][li] = a4.y; As[lk + 2][li] = a4.z; As[lk + 3][li] = a4.w;
        *(float4*)&Bs[bk][bn] = b4;
        __syncthreads();
        #pragma unroll
        for (int kk = 0; kk < 16; ++kk) {
            float4 av = *(const float4*)&As[kk][ty * 4];
            float4 bv = *(const float4*)&Bs[kk][tx * 4];
            float a[4] = {av.x, av.y, av.z, av.w};
            float b[4] = {bv.x, bv.y, bv.z, bv.w};
            #pragma unroll
            for (int i = 0; i < 4; ++i)
                #pragma unroll
                for (int j = 0; j < 4; ++j) acc[i][j] += a[i] * b[j];
        }
        __syncthreads();
    }
    #pragma unroll
    for (int i = 0; i < 4; ++i) {
        float4 v = make_float4(acc[i][0], acc[i][1], acc[i][2], acc[i][3]);
        *(float4*)(C + (size_t)(m0 + ty * 4 + i) * ldc + n0 + tx * 4) = v;
    }
}

__global__ __launch_bounds__(256) void arec64(const float* __restrict__ fw,
                                              const float* __restrict__ mw,
                                              const float* __restrict__ W1,
                                              const float* __restrict__ dm,
                                              float* __restrict__ C)
{
    __shared__ float As[16][68];
    __shared__ float Bs[16][68];
    const int tid = threadIdx.x;
    const int tx = tid & 15, ty = tid >> 4;
    const int m0 = blockIdx.x * 64, n0 = blockIdx.y * 64;
    const int bk = tid >> 4;
    const int bn = (tid & 15) * 4;
    float acc[4][4] = {};
    for (int t0 = 0; t0 < NDIM; t0 += 16) {
        const int t = t0 + bk;
        const float* Hrow; const float* Grow; float gs;
        if (t < HALF) { Hrow = fw + (size_t)t * NDIM; Grow = W1 + (size_t)t * NDIM; gs = 1.f; }
        else          { Hrow = mw + (size_t)(t - HALF) * NDIM; Grow = Hrow; gs = dm[t - HALF]; }
        float4 a4 = *(const float4*)(Hrow + m0 + bn);
        float4 b4 = *(const float4*)(Grow + n0 + bn);
        b4.x *= gs; b4.y *= gs; b4.z *= gs; b4.w *= gs;
        *(float4*)&As[bk][bn] = a4;
        *(float4*)&Bs[bk][bn] = b4;
        __syncthreads();
        #pragma unroll
        for (int kk = 0; kk < 16; ++kk) {
            float4 av = *(const float4*)&As[kk][ty * 4];
            float4 bv = *(const float4*)&Bs[kk][tx * 4];
            float a[4] = {av.x, av.y, av.z, av.w};
            float b[4] = {bv.x, bv.y, bv.z, bv.w};
            #pragma unroll
            for (int i = 0; i < 4; ++i)
                #pragma unroll
                for (int j = 0; j < 4; ++j) acc[i][j] += a[i] * b[j];
        }
        __syncthreads();
    }
    #pragma unroll
    for (int i = 0; i < 4; ++i) {
        float4 v = make_float4(acc[i][0], acc[i][1], acc[i][2], acc[i][3]);
        *(float4*)(C + (size_t)(m0 + ty * 4 + i) * NDIM + n0 + tx * 4) = v;
    }
}

// ---------------------------------------------------------------------------
extern "C" void kernel_launch(void* const* d_in, const int* in_sizes, int n_in,
                              void* d_out, int out_size, void* d_ws, size_t ws_size,
                              hipStream_t stream)
{
    (void)in_sizes; (void)n_in; (void)out_size;
    const float* A     = (const float*)d_in[0];
    const float* O     = (const float*)d_in[1];
    const int*   idx   = (const int*)d_in[2];
    const int*   act   = (const int*)d_in[3];
    const int*   inact = (const int*)d_in[4];

    float* out = (float*)d_out;
    const size_t NN = (size_t)NDIM * NDIM;
    float* A_rec = out;                       // scratch for P(z0) until final gemm
    float* right = out + NN;
    float* D     = out + 2 * NN;              // scratch: split-K partials / W1
    float* mc    = out + 3 * NN;
    float* fc    = mc + (size_t)HALF * HALF;  // Daa
    float* mw    = fc + (size_t)HALF * HALF;
    float* fw    = mw + (size_t)HALF * NDIM;

    char*  w        = (char*)d_ws;
    float* diag_all = (float*)w;              // 2048 f
    float* dm       = (float*)(w + 8192);     // 1024 f
    int*   inva     = (int*)(w + 12288);      // 2048 i
    float* dmrow    = (float*)(w + 20480);    // 2048 f

    const size_t MB = 1024 * 1024;
    const size_t WS_NEEDED = 65536 + 32 * MB;

    if (ws_size >= WS_NEEDED) {
        char* r1 = w + 65536;                 // 16 MB: (Warr/Sarr) -> Rh/Rl -> RTh/RTl
        char* r2 = r1 + 16 * MB;              // 16 MB: Ah/Al -> Pa/F -> D/FT -> GT
        float* Warr = (float*)r1;             // 1 MB (consumed by scan3)
        int*   Sarr = (int*)(r1 + MB);        // 32 KB
        unsigned short* Rh  = (unsigned short*)r1;
        unsigned short* Rl  = (unsigned short*)(r1 + 8 * MB);
        unsigned short* RTh = Rh;
        unsigned short* RTl = Rl;
        unsigned short* Ah  = (unsigned short*)r2;
        unsigned short* Al  = (unsigned short*)(r2 + 8 * MB);
        unsigned short* Pah = (unsigned short*)r2;             // after P
        unsigned short* Pal = (unsigned short*)(r2 + 4 * MB);
        unsigned short* Fh  = (unsigned short*)(r2 + 8 * MB);
        unsigned short* Fl  = (unsigned short*)(r2 + 12 * MB);
        unsigned short* Dh  = (unsigned short*)r2;             // after Daa
        unsigned short* Dl  = (unsigned short*)(r2 + 2 * MB);
        unsigned short* FTh = (unsigned short*)(r2 + 4 * MB);
        unsigned short* FTl = (unsigned short*)(r2 + 8 * MB);
        unsigned short* GTh = (unsigned short*)r2;             // after W1
        unsigned short* GTl = (unsigned short*)(r2 + 8 * MB);

        // 1. pairwise level composition, then 256-level k-split scan with
        //    conv_hl(A) folded into the scan's idle shadow (blocks 512+)
        compose_kernel<<<256, 64, 0, stream>>>(O, idx, Sarr, Warr);
        scan3_fused<<<512 + 8192, 64, 0, stream>>>(Warr, Sarr, right, A, Ah, Al);
        // 2. mother wavelets (fw gather fused into step 7's gather_conv)
        gather_rows<<<1024, 512, 0, stream>>>(right, inact, mw);
        // 3. convert R to bf16 hi/lo (overwrites Warr/Sarr — consumed)
        conv_hl<<<4096, 256, 0, stream>>>(right, nullptr, nullptr, 11, Rh, Rl);
        // 4. P = R @ A, split-K=2: z0 -> A_rec, z1 -> D slot (NOT reduced —
        //    consumers sum the partials inline)
        mfma_nt<<<dim3(16, 16, 2), 256, 0, stream>>>(Rh, Rl, Ah, Al, A_rec,
                                                     (long)2 * NN, NDIM, NDIM, NDIM, 2);
        // 5. diag (reads z0+z1) + prep
        diag_kernel<<<2048, 256, 0, stream>>>(A_rec, A_rec + 2 * NN, right, diag_all);
        prep2_kernel<<<1, 1024, 0, stream>>>(act, inact, diag_all, inva, dm, dmrow);
        // 7. Pa = (z0+z1)[act] in bf16; fw = right[act] + F in bf16 (fused)
        conv_hl<<<2048, 256, 0, stream>>>(A_rec, A_rec + 2 * NN, act, 11, Pah, Pal);
        gather_conv<<<1024, 512, 0, stream>>>(right, act, fw, Fh, Fl);
        // 8. Daa = Pa . F^T, split-K=4: partials in D slot (4 x 4 MB); reduce -> fc
        //    (fc is an output region — must materialize)
        mfma_nt<<<dim3(8, 8, 4), 256, 0, stream>>>(Pah, Pal, Fh, Fl, D,
                                                   (long)HALF * HALF, HALF, HALF, NDIM, 4);
        reduce_k<<<1024, 256, 0, stream>>>(fc, D, (long)HALF * HALF, 4, (long)HALF * HALF);
        // 9. Dh/Dl = conv(Daa); FT = fw^T
        conv_hl<<<1024, 256, 0, stream>>>(fc, nullptr, nullptr, 10, Dh, Dl);
        tconv_hl<<<dim3(16, 32), 256, 0, stream>>>(fw, HALF, NDIM, FTh, FTl);
        // 10. W1 = Daa @ fw, split-K=2: z0 -> D, z1 -> D+HALF*NDIM (NOT reduced —
        //     gt_build sums inline)
        mfma_nt<<<dim3(8, 16, 2), 256, 0, stream>>>(Dh, Dl, FTh, FTl, D,
                                                    (long)HALF * NDIM, HALF, NDIM, HALF, 2);
        // 11. RT = right^T
        tconv_hl<<<dim3(32, 32), 256, 0, stream>>>(right, NDIM, NDIM, RTh, RTl);
        // 12. GT from (W1z0+W1z1) / dm*right (consumes W1 partials in D slot)
        gt_build<<<dim3(32, 32), 256, 0, stream>>>(D, D + (size_t)HALF * NDIM,
                                                   right, inva, dmrow, GTh, GTl);
        // 13. A_rec = RT . GT^T, split-K=2: z0 -> A_rec, z1 -> D slot; reduce
        //     (A_rec is the output — must materialize)
        mfma_nt<<<dim3(16, 16, 2), 256, 0, stream>>>(RTh, RTl, GTh, GTl, A_rec,
                                                     (long)2 * NN, NDIM, NDIM, NDIM, 2);
        reduce_k<<<4096, 256, 0, stream>>>(A_rec, A_rec, (long)2 * NN, 2, (long)NN);
        // 14. D output (overwrites partial scratch)
        build_D<<<16384, 256, 0, stream>>>(fc, diag_all, inva, D);
        // 15. mother_coefficients = diag(dm)
        mc_kernel<<<4096, 256, 0, stream>>>(dm, mc);
    } else {
        // fp32 fallback (R1 structure)
        scan_kernel<<<256, 64, 0, stream>>>(O, idx, right);
        gather_rows<<<1024, 512, 0, stream>>>(right, act, fw);
        gather_rows<<<1024, 512, 0, stream>>>(right, inact, mw);
        gemm_nt64<<<dim3(32, 32), 256, 0, stream>>>(right, NDIM, nullptr, A, NDIM, nullptr,
                                                    A_rec, NDIM, NDIM);
        diag_kernel<<<2048, 256, 0, stream>>>(A_rec, nullptr, right, diag_all);
        prep2_kernel<<<1, 1024, 0, stream>>>(act, inact, diag_all, inva, dm, dmrow);
        gemm_nt64<<<dim3(16, 16), 256, 0, stream>>>(A_rec, NDIM, act, right, NDIM, act,
                                                    fc, HALF, NDIM);
        gemm_nn64<<<dim3(16, 32), 256, 0, stream>>>(fc, HALF, fw, NDIM, D, NDIM, HALF);
        arec64<<<dim3(32, 32), 256, 0, stream>>>(fw, mw, D, dm, A_rec);
        build_D<<<16384, 256, 0, stream>>>(fc, diag_all, inva, D);
        mc_kernel<<<4096, 256, 0, stream>>>(dm, mc);
    }
}

// Round 8
// 526.592 us; speedup vs baseline: 1.3280x; 1.0258x over previous
//
#include <hip/hip_runtime.h>

// Problem constants (N=2048, L=512, K=16, DROP=2, DIM=1024)
#define NDIM 2048
#define LLEV 512
#define KDIM 16
#define HALF 1024

typedef __attribute__((ext_vector_type(8))) short bf16x8;   // 8 bf16 = 4 VGPRs
typedef __attribute__((ext_vector_type(4))) float f32x4;

// ---------------------------------------------------------------------------
// bf16 split helpers: x ~= hi + lo, each RNE bf16 (~16-17 mantissa bits total)
// ---------------------------------------------------------------------------
__device__ inline unsigned short f2bf(float x) {
    unsigned u = __float_as_uint(x);
    u += 0x7fffu + ((u >> 16) & 1u);
    return (unsigned short)(u >> 16);
}
__device__ inline float bf2f(unsigned short b) {
    return __uint_as_float(((unsigned)b) << 16);
}
__device__ inline void split2(float x, unsigned short& h, unsigned short& l) {
    h = f2bf(x);
    l = f2bf(x - bf2f(h));
}

__device__ inline void gl2lds16(const void* g, void* l) {
    __builtin_amdgcn_global_load_lds(
        (const __attribute__((address_space(1))) void*)g,
        (__attribute__((address_space(3))) void*)l, 16, 0, 0);
}

// ---------------------------------------------------------------------------
// compose_kernel: pairwise level composition (validated R4/R5).
// 512 levels of 16 rows -> 256 composites of 32 rows.
// ---------------------------------------------------------------------------
__global__ __launch_bounds__(64) void compose_kernel(const float* __restrict__ O,
                                                     const int* __restrict__ idx,
                                                     int* __restrict__ Sarr,
                                                     float* __restrict__ Warr)
{
    __shared__ int s_S[32];
    __shared__ int s_pos[32];
    __shared__ float s_W[32][33];
    const int t = blockIdx.x;
    const int lane = threadIdx.x;
    const int* a = idx + (2 * t) * 16;
    const int* b = idx + (2 * t + 1) * 16;

    if (lane == 0) {
        int na = 0, i = 0, j = 0;
        while (i < 16 || j < 16) {
            int va = (i < 16) ? a[i] : 0x7fffffff;
            int vb = (j < 16) ? b[j] : 0x7fffffff;
            int v = va < vb ? va : vb;
            if (va == v) i++;
            if (vb == v) j++;
            s_S[na++] = v;
        }
        const int nm = na;
        int r = 0, p = 0;
        while (na < 32) {
            while (p < nm && s_S[p] < r) p++;
            if (p < nm && s_S[p] == r) { r++; continue; }
            s_S[na++] = r++;
        }
    }
    __syncthreads();
    if (lane < 32) {
        const int v = (lane < 16) ? a[lane] : b[lane - 16];
        int pp = 0;
        #pragma unroll
        for (int q = 0; q < 32; ++q) if (s_S[q] == v) pp = q;
        s_pos[lane] = pp;
        #pragma unroll
        for (int c = 0; c < 33; ++c) s_W[lane][c] = 0.f;
        s_W[lane][lane] = 1.f;
    }
    __syncthreads();
    const int j  = lane >> 2;
    const int cg = (lane & 3) * 8;
    #pragma unroll
    for (int step = 0; step < 2; ++step) {
        const float* Om = O + (size_t)(2 * t + step) * 256;
        float acc[8] = {};
        for (int k = 0; k < 16; ++k) {
            const float o = Om[j * 16 + k];
            const int p = s_pos[step * 16 + k];
            #pragma unroll
            for (int c = 0; c < 8; ++c) acc[c] += o * s_W[p][cg + c];
        }
        __syncthreads();
        const int pj = s_pos[step * 16 + j];
        #pragma unroll
        for (int c = 0; c < 8; ++c) s_W[pj][cg + c] = acc[c];
        __syncthreads();
    }
    if (lane < 32) Sarr[t * 32 + lane] = s_S[lane];
    {
        const int r = lane >> 1, h0 = (lane & 1) * 16;
        float* wp = Warr + (size_t)t * 1024 + r * 32 + h0;
        #pragma unroll
        for (int c = 0; c < 16; ++c) wp[c] = s_W[r][h0 + c];
    }
}

// ---------------------------------------------------------------------------
// scan3_fused: blocks 0..511 run the proven scan3 (latency-bound, chain of
// 256 steps); blocks 512+ run conv_hl(A) work in the scan's shadow.
// ---------------------------------------------------------------------------
__global__ __launch_bounds__(64) void scan3_fused(const float* __restrict__ Warr,
                                                  const int* __restrict__ Sarr,
                                                  float* __restrict__ right,
                                                  const float* __restrict__ Asrc,
                                                  unsigned short* __restrict__ Ahd,
                                                  unsigned short* __restrict__ Ald)
{
    __shared__ float slab[NDIM * 4];
    const int lane = threadIdx.x;

    if (blockIdx.x >= 512) {
        const long e = ((long)(blockIdx.x - 512) * 64 + lane) * 8;
        float4 v0 = *(const float4*)(Asrc + e);
        float4 v1 = *(const float4*)(Asrc + e + 4);
        ushort4 h0, l0, h1, l1;
        split2(v0.x, h0.x, l0.x); split2(v0.y, h0.y, l0.y);
        split2(v0.z, h0.z, l0.z); split2(v0.w, h0.w, l0.w);
        split2(v1.x, h1.x, l1.x); split2(v1.y, h1.y, l1.y);
        split2(v1.z, h1.z, l1.z); split2(v1.w, h1.w, l1.w);
        *(ushort4*)(Ahd + e)     = h0;
        *(ushort4*)(Ahd + e + 4) = h1;
        *(ushort4*)(Ald + e)     = l0;
        *(ushort4*)(Ald + e + 4) = l1;
        return;
    }

    const int c0 = blockIdx.x * 4;
    const int rr = lane & 31;
    const int ks = lane >> 5;

    for (int r = lane; r < NDIM; r += 64)
        *(float4*)&slab[r * 4] = make_float4(0.f, 0.f, 0.f, 0.f);
    if (lane < 4) slab[(c0 + lane) * 4 + lane] = 1.0f;

    int rows[16]; float cf[16]; int wrow;
    {
        const int4* sp = (const int4*)(Sarr + ks * 16);
        #pragma unroll
        for (int q = 0; q < 4; ++q) *(int4*)&rows[q * 4] = sp[q];
        const float4* wp = (const float4*)(Warr + rr * 32 + ks * 16);
        #pragma unroll
        for (int q = 0; q < 4; ++q) *(float4*)&cf[q * 4] = wp[q];
        wrow = Sarr[rr];
    }

    for (int t = 0; t < 256; ++t) {
        int cr[16]; float cc[16];
        const int wr = wrow;
        #pragma unroll
        for (int q = 0; q < 16; ++q) { cr[q] = rows[q]; cc[q] = cf[q]; }
        if (t + 1 < 256) {
            const int4* sp = (const int4*)(Sarr + (t + 1) * 32 + ks * 16);
            #pragma unroll
            for (int q = 0; q < 4; ++q) *(int4*)&rows[q * 4] = sp[q];
            const float4* wp = (const float4*)(Warr + (size_t)(t + 1) * 1024 + rr * 32 + ks * 16);
            #pragma unroll
            for (int q = 0; q < 4; ++q) *(float4*)&cf[q * 4] = wp[q];
            wrow = Sarr[(t + 1) * 32 + rr];
        }
        float4 acc = make_float4(0.f, 0.f, 0.f, 0.f);
        #pragma unroll
        for (int j = 0; j < 16; ++j) {
            float4 v = *(const float4*)&slab[cr[j] * 4];
            acc.x += cc[j] * v.x; acc.y += cc[j] * v.y;
            acc.z += cc[j] * v.z; acc.w += cc[j] * v.w;
        }
        acc.x += __shfl_xor(acc.x, 32, 64);
        acc.y += __shfl_xor(acc.y, 32, 64);
        acc.z += __shfl_xor(acc.z, 32, 64);
        acc.w += __shfl_xor(acc.w, 32, 64);
        if (lane < 32)
            *(float4*)&slab[wr * 4] = acc;
    }

    #pragma unroll 4
    for (int i = 0; i < 32; ++i) {
        const int r = i * 64 + lane;
        *(float4*)(right + (size_t)r * NDIM + c0) = *(float4*)&slab[r * 4];
    }
}

// ---------------------------------------------------------------------------
// post_scan: conv_hl(right -> Rh/Rl) [blocks 0..4095] merged with
// mw = right[inact] gather [blocks 4096..6143, half-row each].
// ---------------------------------------------------------------------------
__global__ __launch_bounds__(256) void post_scan(const float* __restrict__ right,
                                                 const int* __restrict__ inact,
                                                 unsigned short* __restrict__ Rh,
                                                 unsigned short* __restrict__ Rl,
                                                 float* __restrict__ mw)
{
    const int b = blockIdx.x;
    const int tid = threadIdx.x;
    if (b < 4096) {
        const long e = ((long)b * 256 + tid) * 4;
        float4 v = *(const float4*)(right + e);
        ushort4 hh, ll;
        split2(v.x, hh.x, ll.x); split2(v.y, hh.y, ll.y);
        split2(v.z, hh.z, ll.z); split2(v.w, hh.w, ll.w);
        *(ushort4*)(Rh + e) = hh;
        *(ushort4*)(Rl + e) = ll;
    } else {
        const int rb = b - 4096;
        const int r = rb >> 1;
        const int c = (rb & 1) * 1024 + tid * 4;
        *(float4*)(mw + (size_t)r * NDIM + c) =
            *(const float4*)(right + (size_t)inact[r] * NDIM + c);
    }
}

// ---------------------------------------------------------------------------
// Split-bf16 MFMA NT gemm with SPLIT-K (generic). 3-pass hi/lo, 128x128 tile,
// BK=32 (32KB LDS). Validated R6.
// ---------------------------------------------------------------------------
#define GBK 32
__global__ __launch_bounds__(256) void mfma_nt(const unsigned short* __restrict__ Ah,
                                               const unsigned short* __restrict__ Al,
                                               const unsigned short* __restrict__ Bh,
                                               const unsigned short* __restrict__ Bl,
                                               float* __restrict__ C,
                                               long strideZ,
                                               int M, int N, int K, int ksplit)
{
    __shared__ unsigned short sA_h[4 * 128 * 8];   // 8 KB each, 32 KB total
    __shared__ unsigned short sA_l[4 * 128 * 8];
    __shared__ unsigned short sB_h[4 * 128 * 8];
    __shared__ unsigned short sB_l[4 * 128 * 8];

    const int tid  = threadIdx.x;
    const int wave = tid >> 6, lane = tid & 63;
    const int lm   = lane & 15, quad = lane >> 4;
    const int wm   = wave & 1,  wn   = wave >> 1;
    const int m0   = blockIdx.x * 128, n0 = blockIdx.y * 128;
    const int Kz   = K / ksplit;
    const int kbeg = Kz * blockIdx.z;
    C += (size_t)blockIdx.z * strideZ;

    const unsigned short* gbase;
    unsigned short* sbase;
    if      (wave == 0) { gbase = Ah + (size_t)m0 * K; sbase = sA_h; }
    else if (wave == 1) { gbase = Al + (size_t)m0 * K; sbase = sA_l; }
    else if (wave == 2) { gbase = Bh + (size_t)n0 * K; sbase = sB_h; }
    else                { gbase = Bl + (size_t)n0 * K; sbase = sB_l; }

    f32x4 acc[4][4];
    #pragma unroll
    for (int i = 0; i < 4; ++i)
        #pragma unroll
        for (int j = 0; j < 4; ++j) acc[i][j] = (f32x4){0.f, 0.f, 0.f, 0.f};

    for (int k0 = kbeg; k0 < kbeg + Kz; k0 += GBK) {
        #pragma unroll
        for (int h = 0; h < 2; ++h) {
            const unsigned short* gr = gbase + (size_t)(h * 64 + lane) * K + k0;
            unsigned short* sb = sbase + h * 512;
            #pragma unroll
            for (int c = 0; c < 4; ++c)
                gl2lds16(gr + c * 8, sb + c * 1024);
        }
        __syncthreads();
        {
            const int co = quad * 1024;
            bf16x8 ah[4], al[4], bh[4], bl[4];
            #pragma unroll
            for (int i = 0; i < 4; ++i) {
                const int m = wm * 64 + i * 16 + lm;
                ah[i] = *(const bf16x8*)&sA_h[co + m * 8];
                al[i] = *(const bf16x8*)&sA_l[co + m * 8];
            }
            #pragma unroll
            for (int j = 0; j < 4; ++j) {
                const int n = wn * 64 + j * 16 + lm;
                bh[j] = *(const bf16x8*)&sB_h[co + n * 8];
                bl[j] = *(const bf16x8*)&sB_l[co + n * 8];
            }
            #pragma unroll
            for (int i = 0; i < 4; ++i)
                #pragma unroll
                for (int j = 0; j < 4; ++j) {
                    acc[i][j] = __builtin_amdgcn_mfma_f32_16x16x32_bf16(ah[i], bh[j], acc[i][j], 0, 0, 0);
                    acc[i][j] = __builtin_amdgcn_mfma_f32_16x16x32_bf16(ah[i], bl[j], acc[i][j], 0, 0, 0);
                    acc[i][j] = __builtin_amdgcn_mfma_f32_16x16x32_bf16(al[i], bh[j], acc[i][j], 0, 0, 0);
                }
        }
        __syncthreads();
    }
    #pragma unroll
    for (int i = 0; i < 4; ++i) {
        const int mrow = m0 + wm * 64 + i * 16 + quad * 4;
        #pragma unroll
        for (int j = 0; j < 4; ++j) {
            float* cp = C + (size_t)mrow * N + n0 + wn * 64 + j * 16 + lm;
            #pragma unroll
            for (int r = 0; r < 4; ++r) cp[(size_t)r * N] = acc[i][j][r];
        }
    }
}

// ---------------------------------------------------------------------------
// mfma_daa_fused: the Daa GEMM (Pa.F^T, M=N=HALF, K=NDIM, split-K=4) runs
// only 256 blocks = 1 block/CU -> half the machine idles. Blocks 256+ run
// the RT = right^T tconv (1024 blocks) in its shadow. RT's home (r1) is dead
// after the P GEMM; the Daa GEMM reads only r2 -> no aliasing.
// ---------------------------------------------------------------------------
__global__ __launch_bounds__(256) void mfma_daa_fused(const unsigned short* __restrict__ Ah,
                                                      const unsigned short* __restrict__ Al,
                                                      const unsigned short* __restrict__ Bh,
                                                      const unsigned short* __restrict__ Bl,
                                                      float* __restrict__ C,
                                                      const float* __restrict__ right,
                                                      unsigned short* __restrict__ RTh,
                                                      unsigned short* __restrict__ RTl)
{
    __shared__ __align__(16) char smem[32768];
    const int tid = threadIdx.x;

    if (blockIdx.x >= 256) {
        // tconv: RT[k][m] = right[m][k], 64x64 tile, LDS-transposed.
        float* t = (float*)smem;   // [64][65]
        const int rb = blockIdx.x - 256;
        const int bi = rb & 31, bj = rb >> 5;
        const int tx = tid & 15, ty = tid >> 4;
        #pragma unroll
        for (int r = 0; r < 4; ++r) {
            const int row = bi * 64 + ty + r * 16;
            float4 v = *(const float4*)(right + (size_t)row * NDIM + bj * 64 + tx * 4);
            t[(ty + r * 16) * 65 + tx * 4 + 0] = v.x;
            t[(ty + r * 16) * 65 + tx * 4 + 1] = v.y;
            t[(ty + r * 16) * 65 + tx * 4 + 2] = v.z;
            t[(ty + r * 16) * 65 + tx * 4 + 3] = v.w;
        }
        __syncthreads();
        #pragma unroll
        for (int r = 0; r < 4; ++r) {
            const int drow = bj * 64 + ty + r * 16;
            ushort4 hh, ll;
            split2(t[(tx * 4 + 0) * 65 + ty + r * 16], hh.x, ll.x);
            split2(t[(tx * 4 + 1) * 65 + ty + r * 16], hh.y, ll.y);
            split2(t[(tx * 4 + 2) * 65 + ty + r * 16], hh.z, ll.z);
            split2(t[(tx * 4 + 3) * 65 + ty + r * 16], hh.w, ll.w);
            *(ushort4*)(RTh + (size_t)drow * NDIM + bi * 64 + tx * 4) = hh;
            *(ushort4*)(RTl + (size_t)drow * NDIM + bi * 64 + tx * 4) = ll;
        }
        return;
    }

    // GEMM path: M=N=HALF, K=NDIM, ksplit=4, strideZ=HALF*HALF.
    unsigned short* sA_h = (unsigned short*)smem;
    unsigned short* sA_l = sA_h + 4096;
    unsigned short* sB_h = sA_h + 8192;
    unsigned short* sB_l = sA_h + 12288;

    const int b = blockIdx.x;
    const int bx = b & 7, by = (b >> 3) & 7, bz = b >> 6;
    const int wave = tid >> 6, lane = tid & 63;
    const int lm   = lane & 15, quad = lane >> 4;
    const int wm   = wave & 1,  wn   = wave >> 1;
    const int m0   = bx * 128, n0 = by * 128;
    const int Kz   = NDIM / 4;
    const int kbeg = Kz * bz;
    float* Cz = C + (size_t)bz * ((long)HALF * HALF);

    const unsigned short* gbase;
    unsigned short* sbase;
    if      (wave == 0) { gbase = Ah + (size_t)m0 * NDIM; sbase = sA_h; }
    else if (wave == 1) { gbase = Al + (size_t)m0 * NDIM; sbase = sA_l; }
    else if (wave == 2) { gbase = Bh + (size_t)n0 * NDIM; sbase = sB_h; }
    else                { gbase = Bl + (size_t)n0 * NDIM; sbase = sB_l; }

    f32x4 acc[4][4];
    #pragma unroll
    for (int i = 0; i < 4; ++i)
        #pragma unroll
        for (int j = 0; j < 4; ++j) acc[i][j] = (f32x4){0.f, 0.f, 0.f, 0.f};

    for (int k0 = kbeg; k0 < kbeg + Kz; k0 += GBK) {
        #pragma unroll
        for (int h = 0; h < 2; ++h) {
            const unsigned short* gr = gbase + (size_t)(h * 64 + lane) * NDIM + k0;
            unsigned short* sb = sbase + h * 512;
            #pragma unroll
            for (int c = 0; c < 4; ++c)
                gl2lds16(gr + c * 8, sb + c * 1024);
        }
        __syncthreads();
        {
            const int co = quad * 1024;
            bf16x8 ah[4], al[4], bh[4], bl[4];
            #pragma unroll
            for (int i = 0; i < 4; ++i) {
                const int m = wm * 64 + i * 16 + lm;
                ah[i] = *(const bf16x8*)&sA_h[co + m * 8];
                al[i] = *(const bf16x8*)&sA_l[co + m * 8];
            }
            #pragma unroll
            for (int j = 0; j < 4; ++j) {
                const int n = wn * 64 + j * 16 + lm;
                bh[j] = *(const bf16x8*)&sB_h[co + n * 8];
                bl[j] = *(const bf16x8*)&sB_l[co + n * 8];
            }
            #pragma unroll
            for (int i = 0; i < 4; ++i)
                #pragma unroll
                for (int j = 0; j < 4; ++j) {
                    acc[i][j] = __builtin_amdgcn_mfma_f32_16x16x32_bf16(ah[i], bh[j], acc[i][j], 0, 0, 0);
                    acc[i][j] = __builtin_amdgcn_mfma_f32_16x16x32_bf16(ah[i], bl[j], acc[i][j], 0, 0, 0);
                    acc[i][j] = __builtin_amdgcn_mfma_f32_16x16x32_bf16(al[i], bh[j], acc[i][j], 0, 0, 0);
                }
        }
        __syncthreads();
    }
    #pragma unroll
    for (int i = 0; i < 4; ++i) {
        const int mrow = m0 + wm * 64 + i * 16 + quad * 4;
        #pragma unroll
        for (int j = 0; j < 4; ++j) {
            float* cp = Cz + (size_t)mrow * HALF + n0 + wn * 64 + j * 16 + lm;
            #pragma unroll
            for (int r = 0; r < 4; ++r) cp[(size_t)r * HALF] = acc[i][j][r];
        }
    }
}

// ---------------------------------------------------------------------------
// reduce_k: dst[i] = sum_z parts[i + z*strideZ], float4 per thread.
// ---------------------------------------------------------------------------
__global__ __launch_bounds__(256) void reduce_k(float* __restrict__ dst,
                                                const float* __restrict__ parts,
                                                long strideZ, int nz, long n)
{
    const long i = ((long)blockIdx.x * 256 + threadIdx.x) * 4;
    if (i >= n) return;
    float4 s = *(const float4*)(parts + i);
    for (int z = 1; z < nz; ++z) {
        float4 v = *(const float4*)(parts + (size_t)z * strideZ + i);
        s.x += v.x; s.y += v.y; s.z += v.z; s.w += v.w;
    }
    *(float4*)(dst + i) = s;
}

// ---------------------------------------------------------------------------
// step7_kernel: conv Pa = (Pz0+Pz1)[act] -> bf16 [blocks 0..2047] merged
// with fw = right[act] gather + bf16 conv [blocks 2048..4095, half-row each].
// R7 post-mortem: grid was 6144 — the extra 2048 gather blocks read
// act[1024..2047] OOB and wrote 8MB past the output buffer (core dump).
// Correct grid: 2048 (Pa: HALF*NDIM/1024) + 2048 (fw: HALF rows x 2) = 4096.
// ---------------------------------------------------------------------------
__global__ __launch_bounds__(256) void step7_kernel(const float* __restrict__ P0,
                                                    const float* __restrict__ P1,
                                                    const int* __restrict__ act,
                                                    const float* __restrict__ right,
                                                    float* __restrict__ fw,
                                                    unsigned short* __restrict__ Pah,
                                                    unsigned short* __restrict__ Pal,
                                                    unsigned short* __restrict__ Fh,
                                                    unsigned short* __restrict__ Fl)
{
    const int b = blockIdx.x;
    const int tid = threadIdx.x;
    if (b < 2048) {
        const long e = ((long)b * 256 + tid) * 4;
        const long row = e >> 11;
        const long col = e & (NDIM - 1);
        const long off = ((size_t)act[row] << 11) + col;
        float4 v = *(const float4*)(P0 + off);
        float4 v2 = *(const float4*)(P1 + off);
        v.x += v2.x; v.y += v2.y; v.z += v2.z; v.w += v2.w;
        ushort4 hh, ll;
        split2(v.x, hh.x, ll.x); split2(v.y, hh.y, ll.y);
        split2(v.z, hh.z, ll.z); split2(v.w, hh.w, ll.w);
        *(ushort4*)(Pah + e) = hh;
        *(ushort4*)(Pal + e) = ll;
    } else {
        const int rb = b - 2048;
        const int r = rb >> 1;
        const int c = (rb & 1) * 1024 + tid * 4;
        const size_t e = (size_t)r * NDIM + c;
        float4 v = *(const float4*)(right + (size_t)act[r] * NDIM + c);
        *(float4*)(fw + e) = v;
        ushort4 hh, ll;
        split2(v.x, hh.x, ll.x); split2(v.y, hh.y, ll.y);
        split2(v.z, hh.z, ll.z); split2(v.w, hh.w, ll.w);
        *(ushort4*)(Fh + e) = hh;
        *(ushort4*)(Fl + e) = ll;
    }
}

// ---------------------------------------------------------------------------
// step9_kernel: conv Daa (fc -> Dh/Dl) [blocks 0..1023] merged with
// FT = fw^T tconv [blocks 1024..1535].
// ---------------------------------------------------------------------------
__global__ __launch_bounds__(256) void step9_kernel(const float* __restrict__ fc,
                                                    const float* __restrict__ fw,
                                                    unsigned short* __restrict__ Dh,
                                                    unsigned short* __restrict__ Dl,
                                                    unsigned short* __restrict__ FTh,
                                                    unsigned short* __restrict__ FTl)
{
    __shared__ float t[64][65];
    const int b = blockIdx.x;
    const int tid = threadIdx.x;
    if (b < 1024) {
        const long e = ((long)b * 256 + tid) * 4;
        float4 v = *(const float4*)(fc + e);
        ushort4 hh, ll;
        split2(v.x, hh.x, ll.x); split2(v.y, hh.y, ll.y);
        split2(v.z, hh.z, ll.z); split2(v.w, hh.w, ll.w);
        *(ushort4*)(Dh + e) = hh;
        *(ushort4*)(Dl + e) = ll;
        return;
    }
    const int rb = b - 1024;            // tconv fw: Msrc=HALF, Ksrc=NDIM, grid 16x32
    const int bi = rb & 15, bj = rb >> 4;
    const int tx = tid & 15, ty = tid >> 4;
    #pragma unroll
    for (int r = 0; r < 4; ++r) {
        const int row = bi * 64 + ty + r * 16;
        float4 v = *(const float4*)(fw + (size_t)row * NDIM + bj * 64 + tx * 4);
        t[ty + r * 16][tx * 4 + 0] = v.x; t[ty + r * 16][tx * 4 + 1] = v.y;
        t[ty + r * 16][tx * 4 + 2] = v.z; t[ty + r * 16][tx * 4 + 3] = v.w;
    }
    __syncthreads();
    #pragma unroll
    for (int r = 0; r < 4; ++r) {
        const int drow = bj * 64 + ty + r * 16;
        ushort4 hh, ll;
        split2(t[tx * 4 + 0][ty + r * 16], hh.x, ll.x);
        split2(t[tx * 4 + 1][ty + r * 16], hh.y, ll.y);
        split2(t[tx * 4 + 2][ty + r * 16], hh.z, ll.z);
        split2(t[tx * 4 + 3][ty + r * 16], hh.w, ll.w);
        *(ushort4*)(FTh + (size_t)drow * HALF + bi * 64 + tx * 4) = hh;
        *(ushort4*)(FTl + (size_t)drow * HALF + bi * 64 + tx * 4) = ll;
    }
}

// ---------------------------------------------------------------------------
// GT[n,r] = Gfull[r,n] transposed+converted, Gfull fused on the fly.
// W1 comes as TWO split-K partials (W1a + W1b) — reduce fused in.
// ---------------------------------------------------------------------------
__global__ __launch_bounds__(256) void gt_build(const float* __restrict__ W1a,
                                                const float* __restrict__ W1b,
                                                const float* __restrict__ right,
                                                const int* __restrict__ inva,
                                                const float* __restrict__ dmrow,
                                                unsigned short* __restrict__ h,
                                                unsigned short* __restrict__ l)
{
    __shared__ float t[64][65];
    const int bi = blockIdx.x, bj = blockIdx.y;
    const int tx = threadIdx.x & 15, ty = threadIdx.x >> 4;
    #pragma unroll
    for (int rr = 0; rr < 4; ++rr) {
        const int r = bi * 64 + ty + rr * 16;
        const int ia = inva[r];
        float4 v;
        if (ia >= 0) {
            const size_t o = (size_t)ia * NDIM + bj * 64 + tx * 4;
            v = *(const float4*)(W1a + o);
            float4 v2 = *(const float4*)(W1b + o);
            v.x += v2.x; v.y += v2.y; v.z += v2.z; v.w += v2.w;
        } else {
            v = *(const float4*)(right + (size_t)r * NDIM + bj * 64 + tx * 4);
            const float s = dmrow[r];
            v.x *= s; v.y *= s; v.z *= s; v.w *= s;
        }
        t[ty + rr * 16][tx * 4 + 0] = v.x; t[ty + rr * 16][tx * 4 + 1] = v.y;
        t[ty + rr * 16][tx * 4 + 2] = v.z; t[ty + rr * 16][tx * 4 + 3] = v.w;
    }
    __syncthreads();
    #pragma unroll
    for (int rr = 0; rr < 4; ++rr) {
        const int drow = bj * 64 + ty + rr * 16;
        ushort4 hh, ll;
        split2(t[tx * 4 + 0][ty + rr * 16], hh.x, ll.x);
        split2(t[tx * 4 + 1][ty + rr * 16], hh.y, ll.y);
        split2(t[tx * 4 + 2][ty + rr * 16], hh.z, ll.z);
        split2(t[tx * 4 + 3][ty + rr * 16], hh.w, ll.w);
        *(ushort4*)(h + (size_t)drow * NDIM + bi * 64 + tx * 4) = hh;
        *(ushort4*)(l + (size_t)drow * NDIM + bi * 64 + tx * 4) = ll;
    }
}

// ---------------------------------------------------------------------------
// Small helpers
// ---------------------------------------------------------------------------
__global__ __launch_bounds__(256) void diag_kernel(const float* __restrict__ P,
                                                   const float* __restrict__ P2,
                                                   const float* __restrict__ R,
                                                   float* __restrict__ diag_all)
{
    __shared__ float red[256];
    const int i = blockIdx.x;
    const float4* p4 = (const float4*)(P + (size_t)i * NDIM);
    const float4* q4 = P2 ? (const float4*)(P2 + (size_t)i * NDIM) : nullptr;
    const float4* r4 = (const float4*)(R + (size_t)i * NDIM);
    float s = 0.f;
    for (int kq = threadIdx.x; kq < NDIM / 4; kq += 256) {
        float4 a = p4[kq], b = r4[kq];
        if (q4) {
            float4 a2 = q4[kq];
            a.x += a2.x; a.y += a2.y; a.z += a2.z; a.w += a2.w;
        }
        s += a.x * b.x + a.y * b.y + a.z * b.z + a.w * b.w;
    }
    red[threadIdx.x] = s;
    __syncthreads();
    for (int off = 128; off > 0; off >>= 1) {
        if (threadIdx.x < off) red[threadIdx.x] += red[threadIdx.x + off];
        __syncthreads();
    }
    if (threadIdx.x == 0) diag_all[i] = red[0];
}

__global__ void prep2_kernel(const int* __restrict__ act, const int* __restrict__ inact,
                             const float* __restrict__ diag_all,
                             int* __restrict__ inva, float* __restrict__ dm,
                             float* __restrict__ dmrow)
{
    const int t = threadIdx.x;
    inva[t] = -1;
    inva[t + HALF] = -1;
    __syncthreads();
    inva[act[t]] = t;
    const int ir = inact[t];
    const float dv = diag_all[ir];
    dm[t] = dv;
    dmrow[ir] = dv;
}

// tail_kernel: build_D [blocks 0..16383] + mc = diag(dm) [blocks 16384..20479].
__global__ __launch_bounds__(256) void tail_kernel(const float* __restrict__ Daa,
                                                   const float* __restrict__ diag_all,
                                                   const int* __restrict__ inva,
                                                   const float* __restrict__ dm,
                                                   float* __restrict__ D,
                                                   float* __restrict__ mc)
{
    const int b = blockIdx.x;
    if (b < 16384) {
        const int e = b * 256 + threadIdx.x;
        const int i = e >> 11, j = e & (NDIM - 1);
        const int ii = inva[i], jj = inva[j];
        float v = 0.f;
        if (ii >= 0 && jj >= 0) v = Daa[ii * HALF + jj];
        if (i == j) v = diag_all[i];
        D[e] = v;
    } else {
        const int e = (b - 16384) * 256 + threadIdx.x;
        const int t = e >> 10, s = e & (HALF - 1);
        mc[e] = (t == s) ? dm[t] : 0.f;
    }
}

__global__ __launch_bounds__(512) void gather_rows(const float* __restrict__ R,
                                                   const int* __restrict__ ridx,
                                                   float* __restrict__ outp)
{
    const int r = blockIdx.x;
    const int c = threadIdx.x * 4;
    *(float4*)(outp + (size_t)r * NDIM + c) =
        *(const float4*)(R + (size_t)ridx[r] * NDIM + c);
}

// ---------------------------------------------------------------------------
// Old scan + fp32 fallback gemms (fallback path only)
// ---------------------------------------------------------------------------
__global__ __launch_bounds__(64) void scan_kernel(const float* __restrict__ O,
                                                  const int* __restrict__ idx,
                                                  float* __restrict__ right)
{
    __shared__ float slab[NDIM * 8];
    const int lane = threadIdx.x;
    const int c0 = blockIdx.x * 8;
    const int k  = lane >> 2;
    const int c2 = (lane & 3) * 2;

    for (int r = lane; r < NDIM; r += 64) {
        *(float4*)&slab[r * 8]     = make_float4(0.f, 0.f, 0.f, 0.f);
        *(float4*)&slab[r * 8 + 4] = make_float4(0.f, 0.f, 0.f, 0.f);
    }
    if (lane < 8) slab[(c0 + lane) * 8 + lane] = 1.0f;

    int rows[16]; float a[16]; int wrow;
    #pragma unroll
    for (int j = 0; j < 16; ++j) rows[j] = idx[j];
    {
        const float4* p4 = (const float4*)(O + k * 16);
        #pragma unroll
        for (int q = 0; q < 4; ++q) *(float4*)&a[q * 4] = p4[q];
    }
    wrow = idx[k];

    for (int l = 0; l < LLEV; ++l) {
        int rr[16]; float aa[16];
        const int wr = wrow;
        #pragma unroll
        for (int j = 0; j < 16; ++j) { rr[j] = rows[j]; aa[j] = a[j]; }
        if (l + 1 < LLEV) {
            const int* ip = idx + (l + 1) * 16;
            #pragma unroll
            for (int j = 0; j < 16; ++j) rows[j] = ip[j];
            const float4* p4 = (const float4*)(O + (l + 1) * 256 + k * 16);
            #pragma unroll
            for (int q = 0; q < 4; ++q) *(float4*)&a[q * 4] = p4[q];
            wrow = ip[k];
        }
        float sx = 0.f, sy = 0.f;
        #pragma unroll
        for (int j = 0; j < 16; ++j) {
            float2 v = *(float2*)&slab[rr[j] * 8 + c2];
            sx += aa[j] * v.x;
            sy += aa[j] * v.y;
        }
        *(float2*)&slab[wr * 8 + c2] = make_float2(sx, sy);
    }

    for (int r0 = 0; r0 < NDIM; r0 += 32) {
        const int r = r0 + (lane >> 1);
        const int h = (lane & 1) * 4;
        *(float4*)(right + (size_t)r * NDIM + c0 + h) = *(float4*)&slab[r * 8 + h];
    }
}

__global__ __launch_bounds__(256) void gemm_nt64(const float* __restrict__ A, int lda,
                                                 const int* __restrict__ ridxA,
                                                 const float* __restrict__ B, int ldb,
                                                 const int* __restrict__ ridxB,
                                                 float* __restrict__ C, int ldc, int Kk)
{
    __shared__ float As[16][68];
    __shared__ float Bs[16][68];
    const int tid = threadIdx.x;
    const int tx = tid & 15, ty = tid >> 4;
    const int m0 = blockIdx.x * 64, n0 = blockIdx.y * 64;
    const int li = tid >> 2;
    const int lk = (tid & 3) * 4;
    int rowA = m0 + li; if (ridxA) rowA = ridxA[rowA];
    int rowB = n0 + li; if (ridxB) rowB = ridxB[rowB];
    const float* pA = A + (size_t)rowA * lda + lk;
    const float* pB = B + (size_t)rowB * ldb + lk;
    float acc[4][4] = {};
    for (int k0 = 0; k0 < Kk; k0 += 16) {
        float4 a4 = *(const float4*)(pA + k0);
        float4 b4 = *(const float4*)(pB + k0);
        As[lk + 0][li] = a4.x; As[lk + 1][li] = a4.y; As[lk + 2][li] = a4.z; As[lk + 3][li] = a4.w;
        Bs[lk + 0][li] = b4.x; Bs[lk + 1][li] = b4.y; Bs[lk + 2][li] = b4.z; Bs[lk + 3][li] = b4.w;
        __syncthreads();
        #pragma unroll
        for (int kk = 0; kk < 16; ++kk) {
            float4 av = *(const float4*)&As[kk][ty * 4];
            float4 bv = *(const float4*)&Bs[kk][tx * 4];
            float a[4] = {av.x, av.y, av.z, av.w};
            float b[4] = {bv.x, bv.y, bv.z, bv.w};
            #pragma unroll
            for (int i = 0; i < 4; ++i)
                #pragma unroll
                for (int j = 0; j < 4; ++j) acc[i][j] += a[i] * b[j];
        }
        __syncthreads();
    }
    #pragma unroll
    for (int i = 0; i < 4; ++i) {
        float4 v = make_float4(acc[i][0], acc[i][1], acc[i][2], acc[i][3]);
        *(float4*)(C + (size_t)(m0 + ty * 4 + i) * ldc + n0 + tx * 4) = v;
    }
}

__global__ __launch_bounds__(256) void gemm_nn64(const float* __restrict__ A, int lda,
                                                 const float* __restrict__ B, int ldb,
                                                 float* __restrict__ C, int ldc, int Kk)
{
    __shared__ float As[16][68];
    __shared__ float Bs[16][68];
    const int tid = threadIdx.x;
    const int tx = tid & 15, ty = tid >> 4;
    const int m0 = blockIdx.x * 64, n0 = blockIdx.y * 64;
    const int li = tid >> 2;
    const int lk = (tid & 3) * 4;
    const int bk = tid >> 4;
    const int bn = (tid & 15) * 4;
    const float* pA = A + (size_t)(m0 + li) * lda + lk;
    float acc[4][4] = {};
    for (int k0 = 0; k0 < Kk; k0 += 16) {
        float4 a4 = *(const float4*)(pA + k0);
        float4 b4 = *(const float4*)(B + (size_t)(k0 + bk) * ldb + n0 + bn);
        As[lk + 0][li] = a4.x; As[lk + 1][li] = a4.y; As[lk + 2][li] = a4.z; As[lk + 3][li] = a4.w;
        *(float4*)&Bs[bk][bn] = b4;
        __syncthreads();
        #pragma unroll
        for (int kk = 0; kk < 16; ++kk) {
            float4 av = *(const float4*)&As[kk][ty * 4];
            float4 bv = *(const float4*)&Bs[kk][tx * 4];
            float a[4] = {av.x, av.y, av.z, av.w};
            float b[4] = {bv.x, bv.y, bv.z, bv.w};
            #pragma unroll
            for (int i = 0; i < 4; ++i)
                #pragma unroll
                for (int j = 0; j < 4; ++j) acc[i][j] += a[i] * b[j];
        }
        __syncthreads();
    }
    #pragma unroll
    for (int i = 0; i < 4; ++i) {
        float4 v = make_float4(acc[i][0], acc[i][1], acc[i][2], acc[i][3]);
        *(float4*)(C + (size_t)(m0 + ty * 4 + i) * ldc + n0 + tx * 4) = v;
    }
}

__global__ __launch_bounds__(256) void arec64(const float* __restrict__ fw,
                                              const float* __restrict__ mw,
                                              const float* __restrict__ W1,
                                              const float* __restrict__ dm,
                                              float* __restrict__ C)
{
    __shared__ float As[16][68];
    __shared__ float Bs[16][68];
    const int tid = threadIdx.x;
    const int tx = tid & 15, ty = tid >> 4;
    const int m0 = blockIdx.x * 64, n0 = blockIdx.y * 64;
    const int bk = tid >> 4;
    const int bn = (tid & 15) * 4;
    float acc[4][4] = {};
    for (int t0 = 0; t0 < NDIM; t0 += 16) {
        const int t = t0 + bk;
        const float* Hrow; const float* Grow; float gs;
        if (t < HALF) { Hrow = fw + (size_t)t * NDIM; Grow = W1 + (size_t)t * NDIM; gs = 1.f; }
        else          { Hrow = mw + (size_t)(t - HALF) * NDIM; Grow = Hrow; gs = dm[t - HALF]; }
        float4 a4 = *(const float4*)(Hrow + m0 + bn);
        float4 b4 = *(const float4*)(Grow + n0 + bn);
        b4.x *= gs; b4.y *= gs; b4.z *= gs; b4.w *= gs;
        *(float4*)&As[bk][bn] = a4;
        *(float4*)&Bs[bk][bn] = b4;
        __syncthreads();
        #pragma unroll
        for (int kk = 0; kk < 16; ++kk) {
            float4 av = *(const float4*)&As[kk][ty * 4];
            float4 bv = *(const float4*)&Bs[kk][tx * 4];
            float a[4] = {av.x, av.y, av.z, av.w};
            float b[4] = {bv.x, bv.y, bv.z, bv.w};
            #pragma unroll
            for (int i = 0; i < 4; ++i)
                #pragma unroll
                for (int j = 0; j < 4; ++j) acc[i][j] += a[i] * b[j];
        }
        __syncthreads();
    }
    #pragma unroll
    for (int i = 0; i < 4; ++i) {
        float4 v = make_float4(acc[i][0], acc[i][1], acc[i][2], acc[i][3]);
        *(float4*)(C + (size_t)(m0 + ty * 4 + i) * NDIM + n0 + tx * 4) = v;
    }
}

// build_D (fallback path)
__global__ __launch_bounds__(256) void build_D(const float* __restrict__ Daa,
                                               const float* __restrict__ diag_all,
                                               const int* __restrict__ inva,
                                               float* __restrict__ D)
{
    const int e = blockIdx.x * 256 + threadIdx.x;
    const int i = e >> 11, j = e & (NDIM - 1);
    const int ii = inva[i], jj = inva[j];
    float v = 0.f;
    if (ii >= 0 && jj >= 0) v = Daa[ii * HALF + jj];
    if (i == j) v = diag_all[i];
    D[e] = v;
}

__global__ __launch_bounds__(256) void mc_kernel(const float* __restrict__ dm,
                                                 float* __restrict__ mc)
{
    const int e = blockIdx.x * 256 + threadIdx.x;
    const int t = e >> 10, s = e & (HALF - 1);
    mc[e] = (t == s) ? dm[t] : 0.f;
}

// ---------------------------------------------------------------------------
extern "C" void kernel_launch(void* const* d_in, const int* in_sizes, int n_in,
                              void* d_out, int out_size, void* d_ws, size_t ws_size,
                              hipStream_t stream)
{
    (void)in_sizes; (void)n_in; (void)out_size;
    const float* A     = (const float*)d_in[0];
    const float* O     = (const float*)d_in[1];
    const int*   idx   = (const int*)d_in[2];
    const int*   act   = (const int*)d_in[3];
    const int*   inact = (const int*)d_in[4];

    float* out = (float*)d_out;
    const size_t NN = (size_t)NDIM * NDIM;
    float* A_rec = out;                       // scratch for P(z0) until final gemm
    float* right = out + NN;
    float* D     = out + 2 * NN;              // scratch: split-K partials / W1
    float* mc    = out + 3 * NN;
    float* fc    = mc + (size_t)HALF * HALF;  // Daa
    float* mw    = fc + (size_t)HALF * HALF;
    float* fw    = mw + (size_t)HALF * NDIM;

    char*  w        = (char*)d_ws;
    float* diag_all = (float*)w;              // 2048 f
    float* dm       = (float*)(w + 8192);     // 1024 f
    int*   inva     = (int*)(w + 12288);      // 2048 i
    float* dmrow    = (float*)(w + 20480);    // 2048 f

    const size_t MB = 1024 * 1024;
    const size_t WS_NEEDED = 65536 + 32 * MB;

    if (ws_size >= WS_NEEDED) {
        char* r1 = w + 65536;                 // 16 MB: (Warr/Sarr) -> Rh/Rl -> RTh/RTl
        char* r2 = r1 + 16 * MB;              // 16 MB: Ah/Al -> Pa/F -> D/FT -> GT
        float* Warr = (float*)r1;             // 1 MB (consumed by scan3)
        int*   Sarr = (int*)(r1 + MB);        // 32 KB
        unsigned short* Rh  = (unsigned short*)r1;
        unsigned short* Rl  = (unsigned short*)(r1 + 8 * MB);
        unsigned short* RTh = Rh;
        unsigned short* RTl = Rl;
        unsigned short* Ah  = (unsigned short*)r2;
        unsigned short* Al  = (unsigned short*)(r2 + 8 * MB);
        unsigned short* Pah = (unsigned short*)r2;             // after P
        unsigned short* Pal = (unsigned short*)(r2 + 4 * MB);
        unsigned short* Fh  = (unsigned short*)(r2 + 8 * MB);
        unsigned short* Fl  = (unsigned short*)(r2 + 12 * MB);
        unsigned short* Dh  = (unsigned short*)r2;             // after Daa
        unsigned short* Dl  = (unsigned short*)(r2 + 2 * MB);
        unsigned short* FTh = (unsigned short*)(r2 + 4 * MB);
        unsigned short* FTl = (unsigned short*)(r2 + 8 * MB);
        unsigned short* GTh = (unsigned short*)r2;             // after W1
        unsigned short* GTl = (unsigned short*)(r2 + 8 * MB);

        // 1. compose; scan with conv_hl(A) in its shadow
        compose_kernel<<<256, 64, 0, stream>>>(O, idx, Sarr, Warr);
        scan3_fused<<<512 + 8192, 64, 0, stream>>>(Warr, Sarr, right, A, Ah, Al);
        // 2. conv right->Rh/Rl + gather mw (merged)
        post_scan<<<6144, 256, 0, stream>>>(right, inact, Rh, Rl, mw);
        // 3. P = R @ A, split-K=2: z0 -> A_rec, z1 -> D slot (partials summed
        //    inline by consumers)
        mfma_nt<<<dim3(16, 16, 2), 256, 0, stream>>>(Rh, Rl, Ah, Al, A_rec,
                                                     (long)2 * NN, NDIM, NDIM, NDIM, 2);
        // 4. diag (sums z0+z1) + prep
        diag_kernel<<<2048, 256, 0, stream>>>(A_rec, A_rec + 2 * NN, right, diag_all);
        prep2_kernel<<<1, 1024, 0, stream>>>(act, inact, diag_all, inva, dm, dmrow);
        // 5. Pa = (z0+z1)[act] bf16 + fw gather/conv (merged; grid 4096 — R7 fix)
        step7_kernel<<<4096, 256, 0, stream>>>(A_rec, A_rec + 2 * NN, act, right,
                                               fw, Pah, Pal, Fh, Fl);
        // 6. Daa GEMM (1 block/CU) with RT = right^T tconv riding its shadow
        mfma_daa_fused<<<256 + 1024, 256, 0, stream>>>(Pah, Pal, Fh, Fl, D,
                                                       right, RTh, RTl);
        reduce_k<<<1024, 256, 0, stream>>>(fc, D, (long)HALF * HALF, 4, (long)HALF * HALF);
        // 7. conv Daa -> Dh/Dl + FT = fw^T (merged)
        step9_kernel<<<1536, 256, 0, stream>>>(fc, fw, Dh, Dl, FTh, FTl);
        // 8. W1 = Daa @ fw, split-K=2 (partials summed inline by gt_build)
        mfma_nt<<<dim3(8, 16, 2), 256, 0, stream>>>(Dh, Dl, FTh, FTl, D,
                                                    (long)HALF * NDIM, HALF, NDIM, HALF, 2);
        // 9. GT from (W1z0+W1z1) / dm*right
        gt_build<<<dim3(32, 32), 256, 0, stream>>>(D, D + (size_t)HALF * NDIM,
                                                   right, inva, dmrow, GTh, GTl);
        // 10. A_rec = RT . GT^T, split-K=2; reduce (output must materialize)
        mfma_nt<<<dim3(16, 16, 2), 256, 0, stream>>>(RTh, RTl, GTh, GTl, A_rec,
                                                     (long)2 * NN, NDIM, NDIM, NDIM, 2);
        reduce_k<<<4096, 256, 0, stream>>>(A_rec, A_rec, (long)2 * NN, 2, (long)NN);
        // 11. D output + mc (merged; D write only after reduce consumed z1)
        tail_kernel<<<20480, 256, 0, stream>>>(fc, diag_all, inva, dm, D, mc);
    } else {
        // fp32 fallback (R1 structure)
        scan_kernel<<<256, 64, 0, stream>>>(O, idx, right);
        gather_rows<<<1024, 512, 0, stream>>>(right, act, fw);
        gather_rows<<<1024, 512, 0, stream>>>(right, inact, mw);
        gemm_nt64<<<dim3(32, 32), 256, 0, stream>>>(right, NDIM, nullptr, A, NDIM, nullptr,
                                                    A_rec, NDIM, NDIM);
        diag_kernel<<<2048, 256, 0, stream>>>(A_rec, nullptr, right, diag_all);
        prep2_kernel<<<1, 1024, 0, stream>>>(act, inact, diag_all, inva, dm, dmrow);
        gemm_nt64<<<dim3(16, 16), 256, 0, stream>>>(A_rec, NDIM, act, right, NDIM, act,
                                                    fc, HALF, NDIM);
        gemm_nn64<<<dim3(16, 32), 256, 0, stream>>>(fc, HALF, fw, NDIM, D, NDIM, HALF);
        arec64<<<dim3(32, 32), 256, 0, stream>>>(fw, mw, D, dm, A_rec);
        build_D<<<16384, 256, 0, stream>>>(fc, diag_all, inva, D);
        mc_kernel<<<4096, 256, 0, stream>>>(dm, mc);
    }
}

// Round 9
// 520.430 us; speedup vs baseline: 1.3437x; 1.0118x over previous
//
#include <hip/hip_runtime.h>

// Problem constants (N=2048, L=512, K=16, DROP=2, DIM=1024)
#define NDIM 2048
#define LLEV 512
#define KDIM 16
#define HALF 1024

typedef __attribute__((ext_vector_type(8))) short bf16x8;   // 8 bf16 = 4 VGPRs
typedef __attribute__((ext_vector_type(4))) float f32x4;

// ---------------------------------------------------------------------------
// bf16 split helpers: x ~= hi + lo, each RNE bf16 (~16-17 mantissa bits total)
// ---------------------------------------------------------------------------
__device__ inline unsigned short f2bf(float x) {
    unsigned u = __float_as_uint(x);
    u += 0x7fffu + ((u >> 16) & 1u);
    return (unsigned short)(u >> 16);
}
__device__ inline float bf2f(unsigned short b) {
    return __uint_as_float(((unsigned)b) << 16);
}
__device__ inline void split2(float x, unsigned short& h, unsigned short& l) {
    h = f2bf(x);
    l = f2bf(x - bf2f(h));
}

__device__ inline void gl2lds16(const void* g, void* l) {
    __builtin_amdgcn_global_load_lds(
        (const __attribute__((address_space(1))) void*)g,
        (__attribute__((address_space(3))) void*)l, 16, 0, 0);
}

// ---------------------------------------------------------------------------
// compose_kernel: pairwise level composition (validated R4/R5).
// 512 levels of 16 rows -> 256 composites of 32 rows.
// ---------------------------------------------------------------------------
__global__ __launch_bounds__(64) void compose_kernel(const float* __restrict__ O,
                                                     const int* __restrict__ idx,
                                                     int* __restrict__ Sarr,
                                                     float* __restrict__ Warr)
{
    __shared__ int s_S[32];
    __shared__ int s_pos[32];
    __shared__ float s_W[32][33];
    const int t = blockIdx.x;
    const int lane = threadIdx.x;
    const int* a = idx + (2 * t) * 16;
    const int* b = idx + (2 * t + 1) * 16;

    if (lane == 0) {
        int na = 0, i = 0, j = 0;
        while (i < 16 || j < 16) {
            int va = (i < 16) ? a[i] : 0x7fffffff;
            int vb = (j < 16) ? b[j] : 0x7fffffff;
            int v = va < vb ? va : vb;
            if (va == v) i++;
            if (vb == v) j++;
            s_S[na++] = v;
        }
        const int nm = na;
        int r = 0, p = 0;
        while (na < 32) {
            while (p < nm && s_S[p] < r) p++;
            if (p < nm && s_S[p] == r) { r++; continue; }
            s_S[na++] = r++;
        }
    }
    __syncthreads();
    if (lane < 32) {
        const int v = (lane < 16) ? a[lane] : b[lane - 16];
        int pp = 0;
        #pragma unroll
        for (int q = 0; q < 32; ++q) if (s_S[q] == v) pp = q;
        s_pos[lane] = pp;
        #pragma unroll
        for (int c = 0; c < 33; ++c) s_W[lane][c] = 0.f;
        s_W[lane][lane] = 1.f;
    }
    __syncthreads();
    const int j  = lane >> 2;
    const int cg = (lane & 3) * 8;
    #pragma unroll
    for (int step = 0; step < 2; ++step) {
        const float* Om = O + (size_t)(2 * t + step) * 256;
        float acc[8] = {};
        for (int k = 0; k < 16; ++k) {
            const float o = Om[j * 16 + k];
            const int p = s_pos[step * 16 + k];
            #pragma unroll
            for (int c = 0; c < 8; ++c) acc[c] += o * s_W[p][cg + c];
        }
        __syncthreads();
        const int pj = s_pos[step * 16 + j];
        #pragma unroll
        for (int c = 0; c < 8; ++c) s_W[pj][cg + c] = acc[c];
        __syncthreads();
    }
    if (lane < 32) Sarr[t * 32 + lane] = s_S[lane];
    {
        const int r = lane >> 1, h0 = (lane & 1) * 16;
        float* wp = Warr + (size_t)t * 1024 + r * 32 + h0;
        #pragma unroll
        for (int c = 0; c < 16; ++c) wp[c] = s_W[r][h0 + c];
    }
}

// ---------------------------------------------------------------------------
// scan3_fused: blocks 0..511 run the proven scan3 (latency-bound, chain of
// 256 steps); blocks 512+ run conv_hl(A) work in the scan's shadow.
// ---------------------------------------------------------------------------
__global__ __launch_bounds__(64) void scan3_fused(const float* __restrict__ Warr,
                                                  const int* __restrict__ Sarr,
                                                  float* __restrict__ right,
                                                  const float* __restrict__ Asrc,
                                                  unsigned short* __restrict__ Ahd,
                                                  unsigned short* __restrict__ Ald)
{
    __shared__ float slab[NDIM * 4];
    const int lane = threadIdx.x;

    if (blockIdx.x >= 512) {
        const long e = ((long)(blockIdx.x - 512) * 64 + lane) * 8;
        float4 v0 = *(const float4*)(Asrc + e);
        float4 v1 = *(const float4*)(Asrc + e + 4);
        ushort4 h0, l0, h1, l1;
        split2(v0.x, h0.x, l0.x); split2(v0.y, h0.y, l0.y);
        split2(v0.z, h0.z, l0.z); split2(v0.w, h0.w, l0.w);
        split2(v1.x, h1.x, l1.x); split2(v1.y, h1.y, l1.y);
        split2(v1.z, h1.z, l1.z); split2(v1.w, h1.w, l1.w);
        *(ushort4*)(Ahd + e)     = h0;
        *(ushort4*)(Ahd + e + 4) = h1;
        *(ushort4*)(Ald + e)     = l0;
        *(ushort4*)(Ald + e + 4) = l1;
        return;
    }

    const int c0 = blockIdx.x * 4;
    const int rr = lane & 31;
    const int ks = lane >> 5;

    for (int r = lane; r < NDIM; r += 64)
        *(float4*)&slab[r * 4] = make_float4(0.f, 0.f, 0.f, 0.f);
    if (lane < 4) slab[(c0 + lane) * 4 + lane] = 1.0f;

    int rows[16]; float cf[16]; int wrow;
    {
        const int4* sp = (const int4*)(Sarr + ks * 16);
        #pragma unroll
        for (int q = 0; q < 4; ++q) *(int4*)&rows[q * 4] = sp[q];
        const float4* wp = (const float4*)(Warr + rr * 32 + ks * 16);
        #pragma unroll
        for (int q = 0; q < 4; ++q) *(float4*)&cf[q * 4] = wp[q];
        wrow = Sarr[rr];
    }

    for (int t = 0; t < 256; ++t) {
        int cr[16]; float cc[16];
        const int wr = wrow;
        #pragma unroll
        for (int q = 0; q < 16; ++q) { cr[q] = rows[q]; cc[q] = cf[q]; }
        if (t + 1 < 256) {
            const int4* sp = (const int4*)(Sarr + (t + 1) * 32 + ks * 16);
            #pragma unroll
            for (int q = 0; q < 4; ++q) *(int4*)&rows[q * 4] = sp[q];
            const float4* wp = (const float4*)(Warr + (size_t)(t + 1) * 1024 + rr * 32 + ks * 16);
            #pragma unroll
            for (int q = 0; q < 4; ++q) *(float4*)&cf[q * 4] = wp[q];
            wrow = Sarr[(t + 1) * 32 + rr];
        }
        float4 acc = make_float4(0.f, 0.f, 0.f, 0.f);
        #pragma unroll
        for (int j = 0; j < 16; ++j) {
            float4 v = *(const float4*)&slab[cr[j] * 4];
            acc.x += cc[j] * v.x; acc.y += cc[j] * v.y;
            acc.z += cc[j] * v.z; acc.w += cc[j] * v.w;
        }
        acc.x += __shfl_xor(acc.x, 32, 64);
        acc.y += __shfl_xor(acc.y, 32, 64);
        acc.z += __shfl_xor(acc.z, 32, 64);
        acc.w += __shfl_xor(acc.w, 32, 64);
        if (lane < 32)
            *(float4*)&slab[wr * 4] = acc;
    }

    #pragma unroll 4
    for (int i = 0; i < 32; ++i) {
        const int r = i * 64 + lane;
        *(float4*)(right + (size_t)r * NDIM + c0) = *(float4*)&slab[r * 4];
    }
}

// ---------------------------------------------------------------------------
// post_scan: conv_hl(right -> Rh/Rl) [blocks 0..4095] merged with
// mw = right[inact] gather [blocks 4096..6143, half-row each].
// ---------------------------------------------------------------------------
__global__ __launch_bounds__(256) void post_scan(const float* __restrict__ right,
                                                 const int* __restrict__ inact,
                                                 unsigned short* __restrict__ Rh,
                                                 unsigned short* __restrict__ Rl,
                                                 float* __restrict__ mw)
{
    const int b = blockIdx.x;
    const int tid = threadIdx.x;
    if (b < 4096) {
        const long e = ((long)b * 256 + tid) * 4;
        float4 v = *(const float4*)(right + e);
        ushort4 hh, ll;
        split2(v.x, hh.x, ll.x); split2(v.y, hh.y, ll.y);
        split2(v.z, hh.z, ll.z); split2(v.w, hh.w, ll.w);
        *(ushort4*)(Rh + e) = hh;
        *(ushort4*)(Rl + e) = ll;
    } else {
        const int rb = b - 4096;
        const int r = rb >> 1;
        const int c = (rb & 1) * 1024 + tid * 4;
        *(float4*)(mw + (size_t)r * NDIM + c) =
            *(const float4*)(right + (size_t)inact[r] * NDIM + c);
    }
}

// ---------------------------------------------------------------------------
// Split-bf16 MFMA NT gemm with SPLIT-K (generic). 3-pass hi/lo, 128x128 tile,
// BK=32 (32KB LDS). Validated R6.
// ---------------------------------------------------------------------------
#define GBK 32
__global__ __launch_bounds__(256) void mfma_nt(const unsigned short* __restrict__ Ah,
                                               const unsigned short* __restrict__ Al,
                                               const unsigned short* __restrict__ Bh,
                                               const unsigned short* __restrict__ Bl,
                                               float* __restrict__ C,
                                               long strideZ,
                                               int M, int N, int K, int ksplit)
{
    __shared__ unsigned short sA_h[4 * 128 * 8];   // 8 KB each, 32 KB total
    __shared__ unsigned short sA_l[4 * 128 * 8];
    __shared__ unsigned short sB_h[4 * 128 * 8];
    __shared__ unsigned short sB_l[4 * 128 * 8];

    const int tid  = threadIdx.x;
    const int wave = tid >> 6, lane = tid & 63;
    const int lm   = lane & 15, quad = lane >> 4;
    const int wm   = wave & 1,  wn   = wave >> 1;
    const int m0   = blockIdx.x * 128, n0 = blockIdx.y * 128;
    const int Kz   = K / ksplit;
    const int kbeg = Kz * blockIdx.z;
    C += (size_t)blockIdx.z * strideZ;

    const unsigned short* gbase;
    unsigned short* sbase;
    if      (wave == 0) { gbase = Ah + (size_t)m0 * K; sbase = sA_h; }
    else if (wave == 1) { gbase = Al + (size_t)m0 * K; sbase = sA_l; }
    else if (wave == 2) { gbase = Bh + (size_t)n0 * K; sbase = sB_h; }
    else                { gbase = Bl + (size_t)n0 * K; sbase = sB_l; }

    f32x4 acc[4][4];
    #pragma unroll
    for (int i = 0; i < 4; ++i)
        #pragma unroll
        for (int j = 0; j < 4; ++j) acc[i][j] = (f32x4){0.f, 0.f, 0.f, 0.f};

    for (int k0 = kbeg; k0 < kbeg + Kz; k0 += GBK) {
        #pragma unroll
        for (int h = 0; h < 2; ++h) {
            const unsigned short* gr = gbase + (size_t)(h * 64 + lane) * K + k0;
            unsigned short* sb = sbase + h * 512;
            #pragma unroll
            for (int c = 0; c < 4; ++c)
                gl2lds16(gr + c * 8, sb + c * 1024);
        }
        __syncthreads();
        {
            const int co = quad * 1024;
            bf16x8 ah[4], al[4], bh[4], bl[4];
            #pragma unroll
            for (int i = 0; i < 4; ++i) {
                const int m = wm * 64 + i * 16 + lm;
                ah[i] = *(const bf16x8*)&sA_h[co + m * 8];
                al[i] = *(const bf16x8*)&sA_l[co + m * 8];
            }
            #pragma unroll
            for (int j = 0; j < 4; ++j) {
                const int n = wn * 64 + j * 16 + lm;
                bh[j] = *(const bf16x8*)&sB_h[co + n * 8];
                bl[j] = *(const bf16x8*)&sB_l[co + n * 8];
            }
            #pragma unroll
            for (int i = 0; i < 4; ++i)
                #pragma unroll
                for (int j = 0; j < 4; ++j) {
                    acc[i][j] = __builtin_amdgcn_mfma_f32_16x16x32_bf16(ah[i], bh[j], acc[i][j], 0, 0, 0);
                    acc[i][j] = __builtin_amdgcn_mfma_f32_16x16x32_bf16(ah[i], bl[j], acc[i][j], 0, 0, 0);
                    acc[i][j] = __builtin_amdgcn_mfma_f32_16x16x32_bf16(al[i], bh[j], acc[i][j], 0, 0, 0);
                }
        }
        __syncthreads();
    }
    #pragma unroll
    for (int i = 0; i < 4; ++i) {
        const int mrow = m0 + wm * 64 + i * 16 + quad * 4;
        #pragma unroll
        for (int j = 0; j < 4; ++j) {
            float* cp = C + (size_t)mrow * N + n0 + wn * 64 + j * 16 + lm;
            #pragma unroll
            for (int r = 0; r < 4; ++r) cp[(size_t)r * N] = acc[i][j][r];
        }
    }
}

// ---------------------------------------------------------------------------
// mfma_daa_fused: the Daa GEMM (Pa.F^T, M=N=HALF, K=NDIM, split-K=4) runs
// only 256 blocks = 1 block/CU -> half the machine idles. Blocks 256+ run
// the RT = right^T tconv (1024 blocks) in its shadow.
// ---------------------------------------------------------------------------
__global__ __launch_bounds__(256) void mfma_daa_fused(const unsigned short* __restrict__ Ah,
                                                      const unsigned short* __restrict__ Al,
                                                      const unsigned short* __restrict__ Bh,
                                                      const unsigned short* __restrict__ Bl,
                                                      float* __restrict__ C,
                                                      const float* __restrict__ right,
                                                      unsigned short* __restrict__ RTh,
                                                      unsigned short* __restrict__ RTl)
{
    __shared__ __align__(16) char smem[32768];
    const int tid = threadIdx.x;

    if (blockIdx.x >= 256) {
        // tconv: RT[k][m] = right[m][k], 64x64 tile, LDS-transposed.
        float* t = (float*)smem;   // [64][65]
        const int rb = blockIdx.x - 256;
        const int bi = rb & 31, bj = rb >> 5;
        const int tx = tid & 15, ty = tid >> 4;
        #pragma unroll
        for (int r = 0; r < 4; ++r) {
            const int row = bi * 64 + ty + r * 16;
            float4 v = *(const float4*)(right + (size_t)row * NDIM + bj * 64 + tx * 4);
            t[(ty + r * 16) * 65 + tx * 4 + 0] = v.x;
            t[(ty + r * 16) * 65 + tx * 4 + 1] = v.y;
            t[(ty + r * 16) * 65 + tx * 4 + 2] = v.z;
            t[(ty + r * 16) * 65 + tx * 4 + 3] = v.w;
        }
        __syncthreads();
        #pragma unroll
        for (int r = 0; r < 4; ++r) {
            const int drow = bj * 64 + ty + r * 16;
            ushort4 hh, ll;
            split2(t[(tx * 4 + 0) * 65 + ty + r * 16], hh.x, ll.x);
            split2(t[(tx * 4 + 1) * 65 + ty + r * 16], hh.y, ll.y);
            split2(t[(tx * 4 + 2) * 65 + ty + r * 16], hh.z, ll.z);
            split2(t[(tx * 4 + 3) * 65 + ty + r * 16], hh.w, ll.w);
            *(ushort4*)(RTh + (size_t)drow * NDIM + bi * 64 + tx * 4) = hh;
            *(ushort4*)(RTl + (size_t)drow * NDIM + bi * 64 + tx * 4) = ll;
        }
        return;
    }

    // GEMM path: M=N=HALF, K=NDIM, ksplit=4, strideZ=HALF*HALF.
    unsigned short* sA_h = (unsigned short*)smem;
    unsigned short* sA_l = sA_h + 4096;
    unsigned short* sB_h = sA_h + 8192;
    unsigned short* sB_l = sA_h + 12288;

    const int b = blockIdx.x;
    const int bx = b & 7, by = (b >> 3) & 7, bz = b >> 6;
    const int wave = tid >> 6, lane = tid & 63;
    const int lm   = lane & 15, quad = lane >> 4;
    const int wm   = wave & 1,  wn   = wave >> 1;
    const int m0   = bx * 128, n0 = by * 128;
    const int Kz   = NDIM / 4;
    const int kbeg = Kz * bz;
    float* Cz = C + (size_t)bz * ((long)HALF * HALF);

    const unsigned short* gbase;
    unsigned short* sbase;
    if      (wave == 0) { gbase = Ah + (size_t)m0 * NDIM; sbase = sA_h; }
    else if (wave == 1) { gbase = Al + (size_t)m0 * NDIM; sbase = sA_l; }
    else if (wave == 2) { gbase = Bh + (size_t)n0 * NDIM; sbase = sB_h; }
    else                { gbase = Bl + (size_t)n0 * NDIM; sbase = sB_l; }

    f32x4 acc[4][4];
    #pragma unroll
    for (int i = 0; i < 4; ++i)
        #pragma unroll
        for (int j = 0; j < 4; ++j) acc[i][j] = (f32x4){0.f, 0.f, 0.f, 0.f};

    for (int k0 = kbeg; k0 < kbeg + Kz; k0 += GBK) {
        #pragma unroll
        for (int h = 0; h < 2; ++h) {
            const unsigned short* gr = gbase + (size_t)(h * 64 + lane) * NDIM + k0;
            unsigned short* sb = sbase + h * 512;
            #pragma unroll
            for (int c = 0; c < 4; ++c)
                gl2lds16(gr + c * 8, sb + c * 1024);
        }
        __syncthreads();
        {
            const int co = quad * 1024;
            bf16x8 ah[4], al[4], bh[4], bl[4];
            #pragma unroll
            for (int i = 0; i < 4; ++i) {
                const int m = wm * 64 + i * 16 + lm;
                ah[i] = *(const bf16x8*)&sA_h[co + m * 8];
                al[i] = *(const bf16x8*)&sA_l[co + m * 8];
            }
            #pragma unroll
            for (int j = 0; j < 4; ++j) {
                const int n = wn * 64 + j * 16 + lm;
                bh[j] = *(const bf16x8*)&sB_h[co + n * 8];
                bl[j] = *(const bf16x8*)&sB_l[co + n * 8];
            }
            #pragma unroll
            for (int i = 0; i < 4; ++i)
                #pragma unroll
                for (int j = 0; j < 4; ++j) {
                    acc[i][j] = __builtin_amdgcn_mfma_f32_16x16x32_bf16(ah[i], bh[j], acc[i][j], 0, 0, 0);
                    acc[i][j] = __builtin_amdgcn_mfma_f32_16x16x32_bf16(ah[i], bl[j], acc[i][j], 0, 0, 0);
                    acc[i][j] = __builtin_amdgcn_mfma_f32_16x16x32_bf16(al[i], bh[j], acc[i][j], 0, 0, 0);
                }
        }
        __syncthreads();
    }
    #pragma unroll
    for (int i = 0; i < 4; ++i) {
        const int mrow = m0 + wm * 64 + i * 16 + quad * 4;
        #pragma unroll
        for (int j = 0; j < 4; ++j) {
            float* cp = Cz + (size_t)mrow * HALF + n0 + wn * 64 + j * 16 + lm;
            #pragma unroll
            for (int r = 0; r < 4; ++r) cp[(size_t)r * HALF] = acc[i][j][r];
        }
    }
}

// ---------------------------------------------------------------------------
// reduce_k: dst[i] = sum_z parts[i + z*strideZ], float4 per thread.
// ---------------------------------------------------------------------------
__global__ __launch_bounds__(256) void reduce_k(float* __restrict__ dst,
                                                const float* __restrict__ parts,
                                                long strideZ, int nz, long n)
{
    const long i = ((long)blockIdx.x * 256 + threadIdx.x) * 4;
    if (i >= n) return;
    float4 s = *(const float4*)(parts + i);
    for (int z = 1; z < nz; ++z) {
        float4 v = *(const float4*)(parts + (size_t)z * strideZ + i);
        s.x += v.x; s.y += v.y; s.z += v.z; s.w += v.w;
    }
    *(float4*)(dst + i) = s;
}

// ---------------------------------------------------------------------------
// diag_step7: merged diag + step7 (R9). step7's outputs are independent of
// diag's (diag_all), and step7 reads only {P partials, right, act} — no dep.
//   blocks 0..2047:    diag_all[i] = dot(Pz0[i]+Pz1[i], right[i])
//   blocks 2048..4095: Pa = (Pz0+Pz1)[act] -> bf16 hi/lo
//   blocks 4096..6143: fw = right[act] (f32 + bf16 hi/lo), half-row each
// ---------------------------------------------------------------------------
__global__ __launch_bounds__(256) void diag_step7(const float* __restrict__ P0,
                                                  const float* __restrict__ P1,
                                                  const float* __restrict__ right,
                                                  const int* __restrict__ act,
                                                  float* __restrict__ diag_all,
                                                  float* __restrict__ fw,
                                                  unsigned short* __restrict__ Pah,
                                                  unsigned short* __restrict__ Pal,
                                                  unsigned short* __restrict__ Fh,
                                                  unsigned short* __restrict__ Fl)
{
    __shared__ float red[256];
    const int b = blockIdx.x;
    const int tid = threadIdx.x;

    if (b < 2048) {
        const int i = b;
        const float4* p4 = (const float4*)(P0 + (size_t)i * NDIM);
        const float4* q4 = (const float4*)(P1 + (size_t)i * NDIM);
        const float4* r4 = (const float4*)(right + (size_t)i * NDIM);
        float s = 0.f;
        for (int kq = tid; kq < NDIM / 4; kq += 256) {
            float4 a = p4[kq], b2 = r4[kq], a2 = q4[kq];
            a.x += a2.x; a.y += a2.y; a.z += a2.z; a.w += a2.w;
            s += a.x * b2.x + a.y * b2.y + a.z * b2.z + a.w * b2.w;
        }
        red[tid] = s;
        __syncthreads();
        for (int off = 128; off > 0; off >>= 1) {
            if (tid < off) red[tid] += red[tid + off];
            __syncthreads();
        }
        if (tid == 0) diag_all[i] = red[0];
        return;
    }
    if (b < 4096) {
        const int bb = b - 2048;
        const long e = ((long)bb * 256 + tid) * 4;
        const long row = e >> 11;
        const long col = e & (NDIM - 1);
        const long off = ((size_t)act[row] << 11) + col;
        float4 v = *(const float4*)(P0 + off);
        float4 v2 = *(const float4*)(P1 + off);
        v.x += v2.x; v.y += v2.y; v.z += v2.z; v.w += v2.w;
        ushort4 hh, ll;
        split2(v.x, hh.x, ll.x); split2(v.y, hh.y, ll.y);
        split2(v.z, hh.z, ll.z); split2(v.w, hh.w, ll.w);
        *(ushort4*)(Pah + e) = hh;
        *(ushort4*)(Pal + e) = ll;
        return;
    }
    {
        const int rb = b - 4096;          // 0..2047 -> r 0..1023
        const int r = rb >> 1;
        const int c = (rb & 1) * 1024 + tid * 4;
        const size_t e = (size_t)r * NDIM + c;
        float4 v = *(const float4*)(right + (size_t)act[r] * NDIM + c);
        *(float4*)(fw + e) = v;
        ushort4 hh, ll;
        split2(v.x, hh.x, ll.x); split2(v.y, hh.y, ll.y);
        split2(v.z, hh.z, ll.z); split2(v.w, hh.w, ll.w);
        *(ushort4*)(Fh + e) = hh;
        *(ushort4*)(Fl + e) = ll;
    }
}

// ---------------------------------------------------------------------------
// mid_kernel (R9): replaces reduce_k(fc) + step9 + prep2.
//   blocks 0..1023:   fc = sum of 4 Daa split-K partials; Dh/Dl = bf16(fc)
//                     (conversion fused on the summed registers — no re-read)
//   blocks 1024..1535: FT = fw^T tconv (grid 16x32)
//   block 1536:        prep2 (inva/dm/dmrow), 256 threads, single-block sync
// ---------------------------------------------------------------------------
__global__ __launch_bounds__(256) void mid_kernel(const float* __restrict__ parts,
                                                  const float* __restrict__ fw,
                                                  const int* __restrict__ act,
                                                  const int* __restrict__ inact,
                                                  const float* __restrict__ diag_all,
                                                  float* __restrict__ fc,
                                                  unsigned short* __restrict__ Dh,
                                                  unsigned short* __restrict__ Dl,
                                                  unsigned short* __restrict__ FTh,
                                                  unsigned short* __restrict__ FTl,
                                                  int* __restrict__ inva,
                                                  float* __restrict__ dm,
                                                  float* __restrict__ dmrow)
{
    __shared__ float t[64][65];
    const int b = blockIdx.x;
    const int tid = threadIdx.x;
    const long NH = (long)HALF * HALF;

    if (b < 1024) {
        const long i = ((long)b * 256 + tid) * 4;
        float4 s = *(const float4*)(parts + i);
        #pragma unroll
        for (int z = 1; z < 4; ++z) {
            float4 v = *(const float4*)(parts + (size_t)z * NH + i);
            s.x += v.x; s.y += v.y; s.z += v.z; s.w += v.w;
        }
        *(float4*)(fc + i) = s;
        ushort4 hh, ll;
        split2(s.x, hh.x, ll.x); split2(s.y, hh.y, ll.y);
        split2(s.z, hh.z, ll.z); split2(s.w, hh.w, ll.w);
        *(ushort4*)(Dh + i) = hh;
        *(ushort4*)(Dl + i) = ll;
        return;
    }
    if (b < 1536) {
        const int rb = b - 1024;          // tconv fw: Msrc=HALF, Ksrc=NDIM, 16x32
        const int bi = rb & 15, bj = rb >> 4;
        const int tx = tid & 15, ty = tid >> 4;
        #pragma unroll
        for (int r = 0; r < 4; ++r) {
            const int row = bi * 64 + ty + r * 16;
            float4 v = *(const float4*)(fw + (size_t)row * NDIM + bj * 64 + tx * 4);
            t[ty + r * 16][tx * 4 + 0] = v.x; t[ty + r * 16][tx * 4 + 1] = v.y;
            t[ty + r * 16][tx * 4 + 2] = v.z; t[ty + r * 16][tx * 4 + 3] = v.w;
        }
        __syncthreads();
        #pragma unroll
        for (int r = 0; r < 4; ++r) {
            const int drow = bj * 64 + ty + r * 16;
            ushort4 hh, ll;
            split2(t[tx * 4 + 0][ty + r * 16], hh.x, ll.x);
            split2(t[tx * 4 + 1][ty + r * 16], hh.y, ll.y);
            split2(t[tx * 4 + 2][ty + r * 16], hh.z, ll.z);
            split2(t[tx * 4 + 3][ty + r * 16], hh.w, ll.w);
            *(ushort4*)(FTh + (size_t)drow * HALF + bi * 64 + tx * 4) = hh;
            *(ushort4*)(FTl + (size_t)drow * HALF + bi * 64 + tx * 4) = ll;
        }
        return;
    }
    {
        // prep2 with 256 threads (was 1024): same single-block semantics.
        for (int k = tid; k < 2048; k += 256) inva[k] = -1;
        __syncthreads();
        for (int k = tid; k < 1024; k += 256) {
            inva[act[k]] = k;
            const int ir = inact[k];
            const float dv = diag_all[ir];
            dm[k] = dv;
            dmrow[ir] = dv;
        }
    }
}

// ---------------------------------------------------------------------------
// GT[n,r] = Gfull[r,n] transposed+converted, Gfull fused on the fly.
// W1 comes as TWO split-K partials (W1a + W1b) — reduce fused in.
// ---------------------------------------------------------------------------
__global__ __launch_bounds__(256) void gt_build(const float* __restrict__ W1a,
                                                const float* __restrict__ W1b,
                                                const float* __restrict__ right,
                                                const int* __restrict__ inva,
                                                const float* __restrict__ dmrow,
                                                unsigned short* __restrict__ h,
                                                unsigned short* __restrict__ l)
{
    __shared__ float t[64][65];
    const int bi = blockIdx.x, bj = blockIdx.y;
    const int tx = threadIdx.x & 15, ty = threadIdx.x >> 4;
    #pragma unroll
    for (int rr = 0; rr < 4; ++rr) {
        const int r = bi * 64 + ty + rr * 16;
        const int ia = inva[r];
        float4 v;
        if (ia >= 0) {
            const size_t o = (size_t)ia * NDIM + bj * 64 + tx * 4;
            v = *(const float4*)(W1a + o);
            float4 v2 = *(const float4*)(W1b + o);
            v.x += v2.x; v.y += v2.y; v.z += v2.z; v.w += v2.w;
        } else {
            v = *(const float4*)(right + (size_t)r * NDIM + bj * 64 + tx * 4);
            const float s = dmrow[r];
            v.x *= s; v.y *= s; v.z *= s; v.w *= s;
        }
        t[ty + rr * 16][tx * 4 + 0] = v.x; t[ty + rr * 16][tx * 4 + 1] = v.y;
        t[ty + rr * 16][tx * 4 + 2] = v.z; t[ty + rr * 16][tx * 4 + 3] = v.w;
    }
    __syncthreads();
    #pragma unroll
    for (int rr = 0; rr < 4; ++rr) {
        const int drow = bj * 64 + ty + rr * 16;
        ushort4 hh, ll;
        split2(t[tx * 4 + 0][ty + rr * 16], hh.x, ll.x);
        split2(t[tx * 4 + 1][ty + rr * 16], hh.y, ll.y);
        split2(t[tx * 4 + 2][ty + rr * 16], hh.z, ll.z);
        split2(t[tx * 4 + 3][ty + rr * 16], hh.w, ll.w);
        *(ushort4*)(h + (size_t)drow * NDIM + bi * 64 + tx * 4) = hh;
        *(ushort4*)(l + (size_t)drow * NDIM + bi * 64 + tx * 4) = ll;
    }
}

// tail_kernel: build_D [blocks 0..16383] + mc = diag(dm) [blocks 16384..20479].
__global__ __launch_bounds__(256) void tail_kernel(const float* __restrict__ Daa,
                                                   const float* __restrict__ diag_all,
                                                   const int* __restrict__ inva,
                                                   const float* __restrict__ dm,
                                                   float* __restrict__ D,
                                                   float* __restrict__ mc)
{
    const int b = blockIdx.x;
    if (b < 16384) {
        const int e = b * 256 + threadIdx.x;
        const int i = e >> 11, j = e & (NDIM - 1);
        const int ii = inva[i], jj = inva[j];
        float v = 0.f;
        if (ii >= 0 && jj >= 0) v = Daa[ii * HALF + jj];
        if (i == j) v = diag_all[i];
        D[e] = v;
    } else {
        const int e = (b - 16384) * 256 + threadIdx.x;
        const int t = e >> 10, s = e & (HALF - 1);
        mc[e] = (t == s) ? dm[t] : 0.f;
    }
}

// ---------------------------------------------------------------------------
// Fallback-path helpers (fp32 path only)
// ---------------------------------------------------------------------------
__global__ __launch_bounds__(256) void diag_kernel(const float* __restrict__ P,
                                                   const float* __restrict__ P2,
                                                   const float* __restrict__ R,
                                                   float* __restrict__ diag_all)
{
    __shared__ float red[256];
    const int i = blockIdx.x;
    const float4* p4 = (const float4*)(P + (size_t)i * NDIM);
    const float4* q4 = P2 ? (const float4*)(P2 + (size_t)i * NDIM) : nullptr;
    const float4* r4 = (const float4*)(R + (size_t)i * NDIM);
    float s = 0.f;
    for (int kq = threadIdx.x; kq < NDIM / 4; kq += 256) {
        float4 a = p4[kq], b = r4[kq];
        if (q4) {
            float4 a2 = q4[kq];
            a.x += a2.x; a.y += a2.y; a.z += a2.z; a.w += a2.w;
        }
        s += a.x * b.x + a.y * b.y + a.z * b.z + a.w * b.w;
    }
    red[threadIdx.x] = s;
    __syncthreads();
    for (int off = 128; off > 0; off >>= 1) {
        if (threadIdx.x < off) red[threadIdx.x] += red[threadIdx.x + off];
        __syncthreads();
    }
    if (threadIdx.x == 0) diag_all[i] = red[0];
}

__global__ void prep2_kernel(const int* __restrict__ act, const int* __restrict__ inact,
                             const float* __restrict__ diag_all,
                             int* __restrict__ inva, float* __restrict__ dm,
                             float* __restrict__ dmrow)
{
    const int t = threadIdx.x;
    inva[t] = -1;
    inva[t + HALF] = -1;
    __syncthreads();
    inva[act[t]] = t;
    const int ir = inact[t];
    const float dv = diag_all[ir];
    dm[t] = dv;
    dmrow[ir] = dv;
}

__global__ __launch_bounds__(512) void gather_rows(const float* __restrict__ R,
                                                   const int* __restrict__ ridx,
                                                   float* __restrict__ outp)
{
    const int r = blockIdx.x;
    const int c = threadIdx.x * 4;
    *(float4*)(outp + (size_t)r * NDIM + c) =
        *(const float4*)(R + (size_t)ridx[r] * NDIM + c);
}

__global__ __launch_bounds__(64) void scan_kernel(const float* __restrict__ O,
                                                  const int* __restrict__ idx,
                                                  float* __restrict__ right)
{
    __shared__ float slab[NDIM * 8];
    const int lane = threadIdx.x;
    const int c0 = blockIdx.x * 8;
    const int k  = lane >> 2;
    const int c2 = (lane & 3) * 2;

    for (int r = lane; r < NDIM; r += 64) {
        *(float4*)&slab[r * 8]     = make_float4(0.f, 0.f, 0.f, 0.f);
        *(float4*)&slab[r * 8 + 4] = make_float4(0.f, 0.f, 0.f, 0.f);
    }
    if (lane < 8) slab[(c0 + lane) * 8 + lane] = 1.0f;

    int rows[16]; float a[16]; int wrow;
    #pragma unroll
    for (int j = 0; j < 16; ++j) rows[j] = idx[j];
    {
        const float4* p4 = (const float4*)(O + k * 16);
        #pragma unroll
        for (int q = 0; q < 4; ++q) *(float4*)&a[q * 4] = p4[q];
    }
    wrow = idx[k];

    for (int l = 0; l < LLEV; ++l) {
        int rr[16]; float aa[16];
        const int wr = wrow;
        #pragma unroll
        for (int j = 0; j < 16; ++j) { rr[j] = rows[j]; aa[j] = a[j]; }
        if (l + 1 < LLEV) {
            const int* ip = idx + (l + 1) * 16;
            #pragma unroll
            for (int j = 0; j < 16; ++j) rows[j] = ip[j];
            const float4* p4 = (const float4*)(O + (l + 1) * 256 + k * 16);
            #pragma unroll
            for (int q = 0; q < 4; ++q) *(float4*)&a[q * 4] = p4[q];
            wrow = ip[k];
        }
        float sx = 0.f, sy = 0.f;
        #pragma unroll
        for (int j = 0; j < 16; ++j) {
            float2 v = *(float2*)&slab[rr[j] * 8 + c2];
            sx += aa[j] * v.x;
            sy += aa[j] * v.y;
        }
        *(float2*)&slab[wr * 8 + c2] = make_float2(sx, sy);
    }

    for (int r0 = 0; r0 < NDIM; r0 += 32) {
        const int r = r0 + (lane >> 1);
        const int h = (lane & 1) * 4;
        *(float4*)(right + (size_t)r * NDIM + c0 + h) = *(float4*)&slab[r * 8 + h];
    }
}

__global__ __launch_bounds__(256) void gemm_nt64(const float* __restrict__ A, int lda,
                                                 const int* __restrict__ ridxA,
                                                 const float* __restrict__ B, int ldb,
                                                 const int* __restrict__ ridxB,
                                                 float* __restrict__ C, int ldc, int Kk)
{
    __shared__ float As[16][68];
    __shared__ float Bs[16][68];
    const int tid = threadIdx.x;
    const int tx = tid & 15, ty = tid >> 4;
    const int m0 = blockIdx.x * 64, n0 = blockIdx.y * 64;
    const int li = tid >> 2;
    const int lk = (tid & 3) * 4;
    int rowA = m0 + li; if (ridxA) rowA = ridxA[rowA];
    int rowB = n0 + li; if (ridxB) rowB = ridxB[rowB];
    const float* pA = A + (size_t)rowA * lda + lk;
    const float* pB = B + (size_t)rowB * ldb + lk;
    float acc[4][4] = {};
    for (int k0 = 0; k0 < Kk; k0 += 16) {
        float4 a4 = *(const float4*)(pA + k0);
        float4 b4 = *(const float4*)(pB + k0);
        As[lk + 0][li] = a4.x; As[lk + 1][li] = a4.y; As[lk + 2][li] = a4.z; As[lk + 3][li] = a4.w;
        Bs[lk + 0][li] = b4.x; Bs[lk + 1][li] = b4.y; Bs[lk + 2][li] = b4.z; Bs[lk + 3][li] = b4.w;
        __syncthreads();
        #pragma unroll
        for (int kk = 0; kk < 16; ++kk) {
            float4 av = *(const float4*)&As[kk][ty * 4];
            float4 bv = *(const float4*)&Bs[kk][tx * 4];
            float a[4] = {av.x, av.y, av.z, av.w};
            float b[4] = {bv.x, bv.y, bv.z, bv.w};
            #pragma unroll
            for (int i = 0; i < 4; ++i)
                #pragma unroll
                for (int j = 0; j < 4; ++j) acc[i][j] += a[i] * b[j];
        }
        __syncthreads();
    }
    #pragma unroll
    for (int i = 0; i < 4; ++i) {
        float4 v = make_float4(acc[i][0], acc[i][1], acc[i][2], acc[i][3]);
        *(float4*)(C + (size_t)(m0 + ty * 4 + i) * ldc + n0 + tx * 4) = v;
    }
}

__global__ __launch_bounds__(256) void gemm_nn64(const float* __restrict__ A, int lda,
                                                 const float* __restrict__ B, int ldb,
                                                 float* __restrict__ C, int ldc, int Kk)
{
    __shared__ float As[16][68];
    __shared__ float Bs[16][68];
    const int tid = threadIdx.x;
    const int tx = tid & 15, ty = tid >> 4;
    const int m0 = blockIdx.x * 64, n0 = blockIdx.y * 64;
    const int li = tid >> 2;
    const int lk = (tid & 3) * 4;
    const int bk = tid >> 4;
    const int bn = (tid & 15) * 4;
    const float* pA = A + (size_t)(m0 + li) * lda + lk;
    float acc[4][4] = {};
    for (int k0 = 0; k0 < Kk; k0 += 16) {
        float4 a4 = *(const float4*)(pA + k0);
        float4 b4 = *(const float4*)(B + (size_t)(k0 + bk) * ldb + n0 + bn);
        As[lk + 0][li] = a4.x; As[lk + 1][li] = a4.y; As[lk + 2][li] = a4.z; As[lk + 3][li] = a4.w;
        *(float4*)&Bs[bk][bn] = b4;
        __syncthreads();
        #pragma unroll
        for (int kk = 0; kk < 16; ++kk) {
            float4 av = *(const float4*)&As[kk][ty * 4];
            float4 bv = *(const float4*)&Bs[kk][tx * 4];
            float a[4] = {av.x, av.y, av.z, av.w};
            float b[4] = {bv.x, bv.y, bv.z, bv.w};
            #pragma unroll
            for (int i = 0; i < 4; ++i)
                #pragma unroll
                for (int j = 0; j < 4; ++j) acc[i][j] += a[i] * b[j];
        }
        __syncthreads();
    }
    #pragma unroll
    for (int i = 0; i < 4; ++i) {
        float4 v = make_float4(acc[i][0], acc[i][1], acc[i][2], acc[i][3]);
        *(float4*)(C + (size_t)(m0 + ty * 4 + i) * ldc + n0 + tx * 4) = v;
    }
}

__global__ __launch_bounds__(256) void arec64(const float* __restrict__ fw,
                                              const float* __restrict__ mw,
                                              const float* __restrict__ W1,
                                              const float* __restrict__ dm,
                                              float* __restrict__ C)
{
    __shared__ float As[16][68];
    __shared__ float Bs[16][68];
    const int tid = threadIdx.x;
    const int tx = tid & 15, ty = tid >> 4;
    const int m0 = blockIdx.x * 64, n0 = blockIdx.y * 64;
    const int bk = tid >> 4;
    const int bn = (tid & 15) * 4;
    float acc[4][4] = {};
    for (int t0 = 0; t0 < NDIM; t0 += 16) {
        const int t = t0 + bk;
        const float* Hrow; const float* Grow; float gs;
        if (t < HALF) { Hrow = fw + (size_t)t * NDIM; Grow = W1 + (size_t)t * NDIM; gs = 1.f; }
        else          { Hrow = mw + (size_t)(t - HALF) * NDIM; Grow = Hrow; gs = dm[t - HALF]; }
        float4 a4 = *(const float4*)(Hrow + m0 + bn);
        float4 b4 = *(const float4*)(Grow + n0 + bn);
        b4.x *= gs; b4.y *= gs; b4.z *= gs; b4.w *= gs;
        *(float4*)&As[bk][bn] = a4;
        *(float4*)&Bs[bk][bn] = b4;
        __syncthreads();
        #pragma unroll
        for (int kk = 0; kk < 16; ++kk) {
            float4 av = *(const float4*)&As[kk][ty * 4];
            float4 bv = *(const float4*)&Bs[kk][tx * 4];
            float a[4] = {av.x, av.y, av.z, av.w};
            float b[4] = {bv.x, bv.y, bv.z, bv.w};
            #pragma unroll
            for (int i = 0; i < 4; ++i)
                #pragma unroll
                for (int j = 0; j < 4; ++j) acc[i][j] += a[i] * b[j];
        }
        __syncthreads();
    }
    #pragma unroll
    for (int i = 0; i < 4; ++i) {
        float4 v = make_float4(acc[i][0], acc[i][1], acc[i][2], acc[i][3]);
        *(float4*)(C + (size_t)(m0 + ty * 4 + i) * NDIM + n0 + tx * 4) = v;
    }
}

__global__ __launch_bounds__(256) void build_D(const float* __restrict__ Daa,
                                               const float* __restrict__ diag_all,
                                               const int* __restrict__ inva,
                                               float* __restrict__ D)
{
    const int e = blockIdx.x * 256 + threadIdx.x;
    const int i = e >> 11, j = e & (NDIM - 1);
    const int ii = inva[i], jj = inva[j];
    float v = 0.f;
    if (ii >= 0 && jj >= 0) v = Daa[ii * HALF + jj];
    if (i == j) v = diag_all[i];
    D[e] = v;
}

__global__ __launch_bounds__(256) void mc_kernel(const float* __restrict__ dm,
                                                 float* __restrict__ mc)
{
    const int e = blockIdx.x * 256 + threadIdx.x;
    const int t = e >> 10, s = e & (HALF - 1);
    mc[e] = (t == s) ? dm[t] : 0.f;
}

// ---------------------------------------------------------------------------
extern "C" void kernel_launch(void* const* d_in, const int* in_sizes, int n_in,
                              void* d_out, int out_size, void* d_ws, size_t ws_size,
                              hipStream_t stream)
{
    (void)in_sizes; (void)n_in; (void)out_size;
    const float* A     = (const float*)d_in[0];
    const float* O     = (const float*)d_in[1];
    const int*   idx   = (const int*)d_in[2];
    const int*   act   = (const int*)d_in[3];
    const int*   inact = (const int*)d_in[4];

    float* out = (float*)d_out;
    const size_t NN = (size_t)NDIM * NDIM;
    float* A_rec = out;                       // scratch for P(z0) until final gemm
    float* right = out + NN;
    float* D     = out + 2 * NN;              // scratch: split-K partials / W1
    float* mc    = out + 3 * NN;
    float* fc    = mc + (size_t)HALF * HALF;  // Daa
    float* mw    = fc + (size_t)HALF * HALF;
    float* fw    = mw + (size_t)HALF * NDIM;

    char*  w        = (char*)d_ws;
    float* diag_all = (float*)w;              // 2048 f
    float* dm       = (float*)(w + 8192);     // 1024 f
    int*   inva     = (int*)(w + 12288);      // 2048 i
    float* dmrow    = (float*)(w + 20480);    // 2048 f

    const size_t MB = 1024 * 1024;
    const size_t WS_NEEDED = 65536 + 32 * MB;

    if (ws_size >= WS_NEEDED) {
        char* r1 = w + 65536;                 // 16 MB: (Warr/Sarr) -> Rh/Rl -> RTh/RTl
        char* r2 = r1 + 16 * MB;              // 16 MB: Ah/Al -> Pa/F -> D/FT -> GT
        float* Warr = (float*)r1;             // 1 MB (consumed by scan3)
        int*   Sarr = (int*)(r1 + MB);        // 32 KB
        unsigned short* Rh  = (unsigned short*)r1;
        unsigned short* Rl  = (unsigned short*)(r1 + 8 * MB);
        unsigned short* RTh = Rh;
        unsigned short* RTl = Rl;
        unsigned short* Ah  = (unsigned short*)r2;
        unsigned short* Al  = (unsigned short*)(r2 + 8 * MB);
        unsigned short* Pah = (unsigned short*)r2;             // after P
        unsigned short* Pal = (unsigned short*)(r2 + 4 * MB);
        unsigned short* Fh  = (unsigned short*)(r2 + 8 * MB);
        unsigned short* Fl  = (unsigned short*)(r2 + 12 * MB);
        unsigned short* Dh  = (unsigned short*)r2;             // after Daa
        unsigned short* Dl  = (unsigned short*)(r2 + 2 * MB);
        unsigned short* FTh = (unsigned short*)(r2 + 4 * MB);
        unsigned short* FTl = (unsigned short*)(r2 + 8 * MB);
        unsigned short* GTh = (unsigned short*)r2;             // after W1
        unsigned short* GTl = (unsigned short*)(r2 + 8 * MB);

        // 1. compose; scan with conv_hl(A) in its shadow
        compose_kernel<<<256, 64, 0, stream>>>(O, idx, Sarr, Warr);
        scan3_fused<<<512 + 8192, 64, 0, stream>>>(Warr, Sarr, right, A, Ah, Al);
        // 2. conv right->Rh/Rl + gather mw (merged)
        post_scan<<<6144, 256, 0, stream>>>(right, inact, Rh, Rl, mw);
        // 3. P = R @ A, split-K=2: z0 -> A_rec, z1 -> D slot
        mfma_nt<<<dim3(16, 16, 2), 256, 0, stream>>>(Rh, Rl, Ah, Al, A_rec,
                                                     (long)2 * NN, NDIM, NDIM, NDIM, 2);
        // 4. diag + Pa conv + fw gather/conv (merged — step7 is independent
        //    of diag's output; prep2 moved into mid_kernel)
        diag_step7<<<6144, 256, 0, stream>>>(A_rec, A_rec + 2 * NN, right, act,
                                             diag_all, fw, Pah, Pal, Fh, Fl);
        // 5. Daa GEMM (1 block/CU) with RT = right^T tconv riding its shadow
        mfma_daa_fused<<<256 + 1024, 256, 0, stream>>>(Pah, Pal, Fh, Fl, D,
                                                       right, RTh, RTl);
        // 6. fc = sum partials (+bf16 conv fused) + FT tconv + prep2 (merged)
        mid_kernel<<<1537, 256, 0, stream>>>(D, fw, act, inact, diag_all,
                                             fc, Dh, Dl, FTh, FTl,
                                             inva, dm, dmrow);
        // 7. W1 = Daa @ fw, split-K=2 (partials summed inline by gt_build)
        mfma_nt<<<dim3(8, 16, 2), 256, 0, stream>>>(Dh, Dl, FTh, FTl, D,
                                                    (long)HALF * NDIM, HALF, NDIM, HALF, 2);
        // 8. GT from (W1z0+W1z1) / dm*right
        gt_build<<<dim3(32, 32), 256, 0, stream>>>(D, D + (size_t)HALF * NDIM,
                                                   right, inva, dmrow, GTh, GTl);
        // 9. A_rec = RT . GT^T, split-K=2; reduce (output must materialize;
        //    cannot merge reduce with tail — tail writes D region which holds
        //    the z1 partial the reduce still reads)
        mfma_nt<<<dim3(16, 16, 2), 256, 0, stream>>>(RTh, RTl, GTh, GTl, A_rec,
                                                     (long)2 * NN, NDIM, NDIM, NDIM, 2);
        reduce_k<<<4096, 256, 0, stream>>>(A_rec, A_rec, (long)2 * NN, 2, (long)NN);
        // 10. D output + mc (merged)
        tail_kernel<<<20480, 256, 0, stream>>>(fc, diag_all, inva, dm, D, mc);
    } else {
        // fp32 fallback (R1 structure)
        scan_kernel<<<256, 64, 0, stream>>>(O, idx, right);
        gather_rows<<<1024, 512, 0, stream>>>(right, act, fw);
        gather_rows<<<1024, 512, 0, stream>>>(right, inact, mw);
        gemm_nt64<<<dim3(32, 32), 256, 0, stream>>>(right, NDIM, nullptr, A, NDIM, nullptr,
                                                    A_rec, NDIM, NDIM);
        diag_kernel<<<2048, 256, 0, stream>>>(A_rec, nullptr, right, diag_all);
        prep2_kernel<<<1, 1024, 0, stream>>>(act, inact, diag_all, inva, dm, dmrow);
        gemm_nt64<<<dim3(16, 16), 256, 0, stream>>>(A_rec, NDIM, act, right, NDIM, act,
                                                    fc, HALF, NDIM);
        gemm_nn64<<<dim3(16, 32), 256, 0, stream>>>(fc, HALF, fw, NDIM, D, NDIM, HALF);
        arec64<<<dim3(32, 32), 256, 0, stream>>>(fw, mw, D, dm, A_rec);
        build_D<<<16384, 256, 0, stream>>>(fc, diag_all, inva, D);
        mc_kernel<<<4096, 256, 0, stream>>>(dm, mc);
    }
}